// Round 3
// baseline (1061.403 us; speedup 1.0000x reference)
//
#include <hip/hip_runtime.h>
#include <hip/hip_bf16.h>

#define N_NODES 32768
#define N_GRAPHS 8
#define NPG 4096
#define DEG 8
#define N_EDGES (N_NODES*DEG)
#define TW 25
#define NL 6
#define L_PDE 16.0f
#define TMAXC 4.0f
#define DTC 0.04f
#define EPSC 1e-5f

typedef __bf16 bf16x8 __attribute__((ext_vector_type(8)));
typedef float f32x4 __attribute__((ext_vector_type(4)));
typedef unsigned short u16;
typedef unsigned int u32;

__device__ __forceinline__ float bf2f(u16 h){
  union { float f; u32 u; } v; v.u = ((u32)h) << 16; return v.f;
}
__device__ __forceinline__ u16 f2bf(float f){
  union { float f; u32 u; } v; v.f = f;
  u32 r = v.u + 0x7FFFu + ((v.u >> 16) & 1u);
  return (u16)(r >> 16);
}
__device__ __forceinline__ float swishf(float x){
  return x / (1.0f + __expf(-x));
}

// ---------------------------------------------------------------------------
// Weight prep: repack W[K][N] (f32, k-major) into frag-major bf16:
// flat = ((nf*KSTEPS + ks)*64 + lane)*8 + e  maps (c = nf*16 + lane&15,
// k = ks*32 + (lane>>4)*8 + e). Pad rows k>=Ksrc are zero (so X pad can be garbage).
// ---------------------------------------------------------------------------
__global__ void prep_std(const float* __restrict__ src, u16* __restrict__ dst,
                         int Ksrc, int KPAD, int NOUT)
{
  int l = blockIdx.y;
  int per = KPAD * NOUT;
  int i = blockIdx.x * 256 + threadIdx.x;
  if (i >= per) return;
  int KSTEPS = KPAD / 32;
  int e = i & 7;
  int lane = (i >> 3) & 63;
  int ks = (i >> 9) % KSTEPS;
  int nf = i / (KSTEPS * 512);
  int c = nf * 16 + (lane & 15);
  int k = ks * 32 + (lane >> 4) * 8 + e;
  float v = (k < Ksrc) ? src[(size_t)l * Ksrc * NOUT + (size_t)k * NOUT + c] : 0.f;
  dst[(size_t)l * per + i] = f2bf(v);
}

// AB factorization weights: cols 0..127 = A (rows 0..127=h_dst, 128..177=+u,
// 178=+px, 179=+pt), cols 128..255 = B (rows 0..127=h_src, 128..177=-u, 178=-px, 179=0)
__global__ void prep_AB(const float* __restrict__ W, const float* __restrict__ bsrc,
                        u16* __restrict__ dst, float* __restrict__ bdst)
{
  int l = blockIdx.y;
  const int KSTEPS = 6;
  int i = blockIdx.x * 256 + threadIdx.x;       // < 192*256 = 49152
  int e = i & 7, lane = (i >> 3) & 63, ks = (i >> 9) % KSTEPS, nf = i / (KSTEPS * 512);
  int c = nf * 16 + (lane & 15);
  int k = ks * 32 + (lane >> 4) * 8 + e;
  const float* Wl = W + (size_t)l * 308 * 128;
  float v = 0.f;
  if (c < 128) {
    int rowi = -1;
    if (k < 128) rowi = k;
    else if (k < 178) rowi = 256 + (k - 128);
    else if (k == 178) rowi = 306;
    else if (k == 179) rowi = 307;
    if (rowi >= 0) v = Wl[rowi * 128 + c];
  } else {
    int cc = c - 128; float sgn = 1.f; int rowi = -1;
    if (k < 128) rowi = 128 + k;
    else if (k < 178) { rowi = 256 + (k - 128); sgn = -1.f; }
    else if (k == 178) { rowi = 306; sgn = -1.f; }
    if (rowi >= 0) v = sgn * Wl[rowi * 128 + cc];
  }
  dst[(size_t)l * 192 * 256 + i] = f2bf(v);
  if (i < 256) bdst[l * 256 + i] = (i < 128) ? bsrc[l * 128 + i] : 0.f;
}

// Static feature columns: X0[N][64] = [u(50), px, pt, 0..]; Xab cols 128..191 same;
// Xupd col 256 = pt.
__global__ __launch_bounds__(256) void build_static(
    const float* __restrict__ u, const float* __restrict__ pos,
    u16* __restrict__ X0, u16* __restrict__ Xab, u16* __restrict__ Xupd)
{
  int idx = blockIdx.x * 256 + threadIdx.x;   // N*64
  int n = idx >> 6, j = idx & 63;
  float px = pos[n * 2 + 1] * (1.f / L_PDE);
  float pt = pos[n * 2 + 0] * (1.f / TMAXC);
  float v;
  if (j < 50) v = u[n * 50 + j];
  else if (j == 50) v = px;
  else if (j == 51) v = pt;
  else v = 0.f;
  u16 b = f2bf(v);
  X0[n * 64 + j] = b;
  Xab[n * 192 + 128 + j] = b;
  if (j == 0) Xupd[n * 320 + 256] = f2bf(pt);
}

// ---------------------------------------------------------------------------
// Generic MFMA GEMM: out[64-row tile] = act(X @ Wfrag + bias). 4 waves, each
// owns 16 rows x NOUT cols. X staged in LDS with (row&7)<<4 XOR swizzle
// (row stride KPAD*2 B is a multiple of 128 for all instantiations).
// W read frag-major from global (L2-resident, coalesced loads).
// Optional outF: f32 side copy of the activated output (residual seed).
// ---------------------------------------------------------------------------
template<int KPAD, int NOUT, int ACT>
__global__ __launch_bounds__(256) void gemm_act(
    const u16* __restrict__ X, int ldx,
    const u16* __restrict__ Wf, const float* __restrict__ bias,
    u16* __restrict__ out, int ldo,
    u16* __restrict__ out2, int ldo2,
    float* __restrict__ outF)
{
  constexpr int KSTEPS = KPAD / 32;
  constexpr int NF = NOUT / 16;
  constexpr int LDO_S = NOUT + 8;
  constexpr int SMEM_US = 64 * (KPAD > LDO_S ? KPAD : LDO_S);
  __shared__ u16 sm[SMEM_US];
  int tid = threadIdx.x, lane = tid & 63, wid = tid >> 6;
  int n0 = blockIdx.x * 64;

  for (int c = tid; c < 64 * KPAD / 8; c += 256) {
    int r = c / (KPAD / 8), kc = c % (KPAD / 8);
    uint4 v = *(const uint4*)(X + (size_t)(n0 + r) * ldx + kc * 8);
    int byte = r * (KPAD * 2) + kc * 16; byte ^= ((r & 7) << 4);
    *(uint4*)((char*)sm + byte) = v;
  }
  __syncthreads();

  f32x4 acc[NF];
  f32x4 zero = {0.f, 0.f, 0.f, 0.f};
  #pragma unroll
  for (int i = 0; i < NF; ++i) acc[i] = zero;
  int row = wid * 16 + (lane & 15);
  int kb = lane >> 4;
  #pragma unroll
  for (int ks = 0; ks < KSTEPS; ++ks) {
    int ab = row * (KPAD * 2) + ks * 64 + kb * 16; ab ^= ((row & 7) << 4);
    bf16x8 a = *(const bf16x8*)((const char*)sm + ab);
    #pragma unroll
    for (int nf = 0; nf < NF; ++nf) {
      bf16x8 b = *(const bf16x8*)(Wf + ((nf * KSTEPS + ks) * 64 + lane) * 8);
      acc[nf] = __builtin_amdgcn_mfma_f32_16x16x32_bf16(a, b, acc[nf], 0, 0, 0);
    }
  }
  __syncthreads();
  #pragma unroll
  for (int nf = 0; nf < NF; ++nf) {
    int col = nf * 16 + (lane & 15);
    float bv = bias[col];
    #pragma unroll
    for (int j = 0; j < 4; ++j) {
      int r = wid * 16 + (lane >> 4) * 4 + j;
      float v = acc[nf][j] + bv;
      if (ACT == 1) v = swishf(v);
      sm[r * LDO_S + col] = f2bf(v);
      if (outF) outF[(size_t)(n0 + r) * NOUT + col] = v;
    }
  }
  __syncthreads();
  for (int c = tid; c < 64 * NOUT / 8; c += 256) {
    int r = c / (NOUT / 8), kc = c % (NOUT / 8);
    uint4 v = *(const uint4*)(sm + r * LDO_S + kc * 8);
    *(uint4*)(out + (size_t)(n0 + r) * ldo + kc * 8) = v;
    if (out2) *(uint4*)(out2 + (size_t)(n0 + r) * ldo2 + kc * 8) = v;
  }
}

// ---------------------------------------------------------------------------
// Edge message + mean-aggregate. 64 edges (=8 nodes, dst = e>>3) per block.
// m = swish(A[dst]+B[src]) built in LDS; m2 = swish(m@Wm2+b); agg = mean over
// the 8 consecutive edges of each node (static degree), written to Xupd[.,128:256].
// ---------------------------------------------------------------------------
__global__ __launch_bounds__(256) void msg_kernel(
    const u16* __restrict__ AB, const int* __restrict__ srcIdx,
    const u16* __restrict__ Wf, const float* __restrict__ bm2,
    u16* __restrict__ Xupd)
{
  __shared__ u16 Ms[64 * 128];
  __shared__ float aggS[8][132];
  int tid = threadIdx.x, lane = tid & 63, wid = tid >> 6;
  int e0 = blockIdx.x * 64;
  for (int c = tid; c < 1024; c += 256) {
    int i = c >> 4, kc = c & 15;
    int e = e0 + i;
    int nd = e >> 3;
    int ns = srcIdx[e];
    union { uint4 v; u16 s[8]; } va, vb, vo;
    va.v = *(const uint4*)(AB + (size_t)nd * 256 + kc * 8);
    vb.v = *(const uint4*)(AB + (size_t)ns * 256 + 128 + kc * 8);
    #pragma unroll
    for (int j = 0; j < 8; ++j) vo.s[j] = f2bf(swishf(bf2f(va.s[j]) + bf2f(vb.s[j])));
    int byte = i * 256 + kc * 16; byte ^= ((i & 7) << 4);
    *(uint4*)((char*)Ms + byte) = vo.v;
  }
  __syncthreads();
  f32x4 acc[8];
  f32x4 zero = {0.f, 0.f, 0.f, 0.f};
  #pragma unroll
  for (int i = 0; i < 8; ++i) acc[i] = zero;
  int row = wid * 16 + (lane & 15), kb = lane >> 4;
  #pragma unroll
  for (int ks = 0; ks < 4; ++ks) {
    int ab = row * 256 + ks * 64 + kb * 16; ab ^= ((row & 7) << 4);
    bf16x8 a = *(const bf16x8*)((const char*)Ms + ab);
    #pragma unroll
    for (int nf = 0; nf < 8; ++nf) {
      bf16x8 b = *(const bf16x8*)(Wf + ((nf * 4 + ks) * 64 + lane) * 8);
      acc[nf] = __builtin_amdgcn_mfma_f32_16x16x32_bf16(a, b, acc[nf], 0, 0, 0);
    }
  }
  // aggregate: C rows are edges; row = 4*(lane>>4)+j; node = wid*2 + (row>=8)
  #pragma unroll
  for (int nf = 0; nf < 8; ++nf) {
    float bv = bm2[nf * 16 + (lane & 15)];
    float s = 0.f;
    #pragma unroll
    for (int j = 0; j < 4; ++j) s += swishf(acc[nf][j] + bv);
    s += __shfl_xor(s, 16);
    if ((lane & 31) < 16)
      aggS[wid * 2 + (lane >> 5)][nf * 16 + (lane & 15)] = s * 0.125f;
  }
  __syncthreads();
  {
    int node = tid >> 5;
    int c0 = (tid & 31) * 4;
    int n = (e0 >> 3) + node;
    ushort4 o;
    o.x = f2bf(aggS[node][c0 + 0]);
    o.y = f2bf(aggS[node][c0 + 1]);
    o.z = f2bf(aggS[node][c0 + 2]);
    o.w = f2bf(aggS[node][c0 + 3]);
    *(ushort4*)(Xupd + (size_t)n * 320 + 128 + c0) = o;
  }
}

// hn = h + up, IN-PLACE on the f32 residual stream hB; also per-(graph,channel)
// moment partial sums. Each thread reads/writes only its own elements.
__global__ __launch_bounds__(256) void resid_stats(
    float* hB, const u16* __restrict__ up,
    float* __restrict__ S1, float* __restrict__ S2)
{
  __shared__ float hs[64][129];
  int tid = threadIdx.x;
  int n0 = blockIdx.x * 64;
  for (int c = tid; c < 1024; c += 256) {
    int r = c >> 4, kc = c & 15;
    union { uint4 v; u16 s[8]; } b;
    b.v = *(const uint4*)(up + (size_t)(n0 + r) * 128 + kc * 8);
    float* hp = hB + (size_t)(n0 + r) * 128 + kc * 8;
    float4 h0 = *(const float4*)(hp);
    float4 h1 = *(const float4*)(hp + 4);
    float o[8];
    o[0] = h0.x + bf2f(b.s[0]); o[1] = h0.y + bf2f(b.s[1]);
    o[2] = h0.z + bf2f(b.s[2]); o[3] = h0.w + bf2f(b.s[3]);
    o[4] = h1.x + bf2f(b.s[4]); o[5] = h1.y + bf2f(b.s[5]);
    o[6] = h1.z + bf2f(b.s[6]); o[7] = h1.w + bf2f(b.s[7]);
    #pragma unroll
    for (int j = 0; j < 8; ++j) hs[r][kc * 8 + j] = o[j];
    *(float4*)(hp) = make_float4(o[0], o[1], o[2], o[3]);
    *(float4*)(hp + 4) = make_float4(o[4], o[5], o[6], o[7]);
  }
  __syncthreads();
  if (tid < 128) {
    float s1 = 0.f, s2 = 0.f;
    for (int r = 0; r < 64; ++r) { float v = hs[r][tid]; s1 += v; s2 += v * v; }
    int g = n0 >> 12;
    atomicAdd(&S1[g * 128 + tid], s1);
    atomicAdd(&S2[g * 128 + tid], s2);
  }
}

// instance-norm: h' = (hn - mean) * rsqrt(var + eps), IN-PLACE on hB;
// bf16 copies to Xab[,0:128] and Xupd[,0:128].
__global__ __launch_bounds__(256) void norm_k(
    float* hB, const float* __restrict__ S1, const float* __restrict__ S2,
    u16* __restrict__ Xab, u16* __restrict__ Xupd)
{
  int idx = blockIdx.x * 256 + threadIdx.x;   // N*16 chunks
  int n = idx >> 4, kc = idx & 15;
  int g = n >> 12;
  float* hp = hB + (size_t)n * 128 + kc * 8;
  float4 a0 = *(const float4*)(hp);
  float4 a1 = *(const float4*)(hp + 4);
  float x[8] = {a0.x, a0.y, a0.z, a0.w, a1.x, a1.y, a1.z, a1.w};
  union { uint4 v; u16 s[8]; } o;
  float of[8];
  #pragma unroll
  for (int j = 0; j < 8; ++j) {
    int c = kc * 8 + j;
    float m = S1[g * 128 + c] * (1.f / NPG);
    float var = S2[g * 128 + c] * (1.f / NPG) - m * m;
    float v = (x[j] - m) * rsqrtf(var + EPSC);
    of[j] = v;
    o.s[j] = f2bf(v);
  }
  *(uint4*)(Xab + (size_t)n * 192 + kc * 8) = o.v;
  *(uint4*)(Xupd + (size_t)n * 320 + kc * 8) = o.v;
  *(float4*)(hp) = make_float4(of[0], of[1], of[2], of[3]);
  *(float4*)(hp + 4) = make_float4(of[4], of[5], of[6], of[7]);
}

// Decoder tail: per-node Conv1d(2->8,k16,s3) -> swish -> Conv1d(8->2,k14) ->
// out = u + dt_cum * diff. 16 nodes / block, all staged in LDS.
__global__ __launch_bounds__(256) void dec_conv(
    const u16* __restrict__ x2, const float* __restrict__ u,
    const float* __restrict__ w1, const float* __restrict__ b1,
    const float* __restrict__ w2, const float* __restrict__ b2,
    float* __restrict__ outp)
{
  __shared__ float xs[16][257];
  __shared__ float ys[16][8][39];
  __shared__ float w1s[256], w2s[224], b1s[8], b2s[2];
  int tid = threadIdx.x;
  int n0 = blockIdx.x * 16;
  if (tid < 256) w1s[tid] = w1[tid];
  if (tid < 224) w2s[tid] = w2[tid];
  if (tid < 8) b1s[tid] = b1[tid];
  if (tid < 2) b2s[tid] = b2[tid];
  for (int i = tid; i < 16 * 256; i += 256) {
    int n = i >> 8, c = i & 255;
    xs[n][c] = bf2f(x2[(size_t)(n0 + n) * 256 + c]);
  }
  __syncthreads();
  for (int i = tid; i < 16 * 8 * 38; i += 256) {
    int n = i / 304, r = i % 304, o = r / 38, t = r % 38;
    float acc = b1s[o];
    #pragma unroll
    for (int cc = 0; cc < 2; ++cc) {
      int base = cc * 128 + 3 * t;
      #pragma unroll
      for (int k = 0; k < 16; ++k)
        acc += xs[n][base + k] * w1s[o * 32 + cc * 16 + k];
    }
    ys[n][o][t] = swishf(acc);
  }
  __syncthreads();
  for (int i = tid; i < 16 * 50; i += 256) {
    int n = i / 50, r = i % 50, cch = r / 25, t = r % 25;
    float acc = b2s[cch];
    #pragma unroll
    for (int ic = 0; ic < 8; ++ic)
      #pragma unroll
      for (int k = 0; k < 14; ++k)
        acc += ys[n][ic][t + k] * w2s[cch * 112 + ic * 14 + k];
    int gi = (n0 + n) * 50 + cch * 25 + t;
    outp[gi] = u[gi] + (DTC * (t + 1)) * acc;
  }
}

extern "C" void kernel_launch(void* const* d_in, const int* in_sizes, int n_in,
                              void* d_out, int out_size, void* d_ws, size_t ws_size,
                              hipStream_t stream) {
  const float* u     = (const float*)d_in[0];
  const float* pos   = (const float*)d_in[1];
  const int*   eidx  = (const int*)d_in[2];
  const float* embW1 = (const float*)d_in[4];
  const float* embb1 = (const float*)d_in[5];
  const float* embW2 = (const float*)d_in[6];
  const float* embb2 = (const float*)d_in[7];
  const float* m1W   = (const float*)d_in[8];
  const float* m1b   = (const float*)d_in[9];
  const float* m2W   = (const float*)d_in[10];
  const float* m2b   = (const float*)d_in[11];
  const float* u1W   = (const float*)d_in[12];
  const float* u1b   = (const float*)d_in[13];
  const float* u2W   = (const float*)d_in[14];
  const float* u2b   = (const float*)d_in[15];
  const float* dblW  = (const float*)d_in[16];
  const float* dblb  = (const float*)d_in[17];
  const float* c1W   = (const float*)d_in[18];
  const float* c1b   = (const float*)d_in[19];
  const float* c2W   = (const float*)d_in[20];
  const float* c2b   = (const float*)d_in[21];
  float* outp = (float*)d_out;
  const int* srcI = eidx;   // edge_index[0] = src; dst(e) = e>>3 by construction

  char* ws = (char*)d_ws;
  size_t off = 0;
  auto alloc = [&](size_t bytes) -> char* {
    char* p = ws + off; off += (bytes + 255) & ~(size_t)255; return p;
  };
  u16* X0    = (u16*)alloc((size_t)N_NODES * 64 * 2);
  u16* h1    = (u16*)alloc((size_t)N_NODES * 128 * 2);
  u16* Xab   = (u16*)alloc((size_t)N_NODES * 192 * 2);   // [h(128) | u(50) | px | pt | pad]
  u16* Xupd  = (u16*)alloc((size_t)N_NODES * 320 * 2);   // [h(128) | agg(128) | pt | pad]
  u16* ABbuf = (u16*)alloc((size_t)N_NODES * 256 * 2);   // aliased as x2 after layers
  u16* z1    = (u16*)alloc((size_t)N_NODES * 128 * 2);
  u16* upb   = (u16*)alloc((size_t)N_NODES * 128 * 2);
  float* hB  = (float*)alloc((size_t)N_NODES * 128 * 4); // f32 residual stream (in-place)
  float* stats = (float*)alloc((size_t)NL * 2 * 1024 * 4);
  u16* WembF1 = (u16*)alloc(64 * 128 * 2);
  u16* WembF2 = (u16*)alloc(128 * 128 * 2);
  u16* WABf   = (u16*)alloc((size_t)6 * 192 * 256 * 2);
  float* bABf = (float*)alloc(6 * 256 * 4);
  u16* Wm2f   = (u16*)alloc((size_t)6 * 128 * 128 * 2);
  u16* Wu1f   = (u16*)alloc((size_t)6 * 320 * 128 * 2);
  u16* Wu2f   = (u16*)alloc((size_t)6 * 128 * 128 * 2);
  u16* Wdblf  = (u16*)alloc((size_t)192 * 256 * 2);

  hipMemsetAsync(stats, 0, (size_t)NL * 2 * 1024 * 4, stream);

  prep_std<<<dim3(32, 1), 256, 0, stream>>>(embW1, WembF1, 52, 64, 128);
  prep_std<<<dim3(64, 1), 256, 0, stream>>>(embW2, WembF2, 128, 128, 128);
  prep_std<<<dim3(64, 6), 256, 0, stream>>>(m2W, Wm2f, 128, 128, 128);
  prep_std<<<dim3(160, 6), 256, 0, stream>>>(u1W, Wu1f, 257, 320, 128);
  prep_std<<<dim3(64, 6), 256, 0, stream>>>(u2W, Wu2f, 128, 128, 128);
  prep_std<<<dim3(192, 1), 256, 0, stream>>>(dblW, Wdblf, 128, 192, 256);
  prep_AB<<<dim3(192, 6), 256, 0, stream>>>(m1W, m1b, WABf, bABf);
  build_static<<<N_NODES * 64 / 256, 256, 0, stream>>>(u, pos, X0, Xab, Xupd);

  // encoder
  gemm_act<64, 128, 1><<<512, 256, 0, stream>>>(
      X0, 64, WembF1, embb1, h1, 128, nullptr, 0, nullptr);
  gemm_act<128, 128, 1><<<512, 256, 0, stream>>>(
      h1, 128, WembF2, embb2, Xab, 192, Xupd, 320, hB);

  for (int l = 0; l < NL; ++l) {
    gemm_act<192, 256, 0><<<512, 256, 0, stream>>>(
        Xab, 192, WABf + (size_t)l * 192 * 256, bABf + l * 256, ABbuf, 256,
        nullptr, 0, nullptr);
    msg_kernel<<<N_EDGES / 64, 256, 0, stream>>>(
        ABbuf, srcI, Wm2f + (size_t)l * 128 * 128, m2b + l * 128, Xupd);
    gemm_act<320, 128, 1><<<512, 256, 0, stream>>>(
        Xupd, 320, Wu1f + (size_t)l * 320 * 128, u1b + l * 128, z1, 128,
        nullptr, 0, nullptr);
    gemm_act<128, 128, 1><<<512, 256, 0, stream>>>(
        z1, 128, Wu2f + (size_t)l * 128 * 128, u2b + l * 128, upb, 128,
        nullptr, 0, nullptr);
    resid_stats<<<512, 256, 0, stream>>>(
        hB, upb, stats + l * 2048, stats + l * 2048 + 1024);
    norm_k<<<N_NODES * 16 / 256, 256, 0, stream>>>(
        hB, stats + l * 2048, stats + l * 2048 + 1024, Xab, Xupd);
  }

  u16* x2 = ABbuf;
  gemm_act<192, 256, 1><<<512, 256, 0, stream>>>(
      Xab, 192, Wdblf, dblb, x2, 256, nullptr, 0, nullptr);
  dec_conv<<<N_NODES / 16, 256, 0, stream>>>(x2, u, c1W, c1b, c2W, c2b, outp);
}

// Round 4
// 843.931 us; speedup vs baseline: 1.2577x; 1.2577x over previous
//
#include <hip/hip_runtime.h>
#include <hip/hip_bf16.h>

#define N_NODES 32768
#define N_GRAPHS 8
#define NPG 4096
#define DEG 8
#define N_EDGES (N_NODES*DEG)
#define TW 25
#define NL 6
#define L_PDE 16.0f
#define TMAXC 4.0f
#define DTC 0.04f
#define EPSC 1e-5f

typedef __bf16 bf16x8 __attribute__((ext_vector_type(8)));
typedef float f32x4 __attribute__((ext_vector_type(4)));
typedef unsigned short u16;
typedef unsigned int u32;

__device__ __forceinline__ float bf2f(u16 h){
  union { float f; u32 u; } v; v.u = ((u32)h) << 16; return v.f;
}
__device__ __forceinline__ u16 f2bf(float f){
  union { float f; u32 u; } v; v.f = f;
  u32 r = v.u + 0x7FFFu + ((v.u >> 16) & 1u);
  return (u16)(r >> 16);
}
__device__ __forceinline__ float swishf(float x){
  return x / (1.0f + __expf(-x));
}

// ---------------------------------------------------------------------------
// Weight prep: repack W[K][N] (f32, k-major) into frag-major bf16:
// flat = ((nf*KSTEPS + ks)*64 + lane)*8 + e  maps (c = nf*16 + lane&15,
// k = ks*32 + (lane>>4)*8 + e). Pad rows k>=Ksrc are zero.
// ---------------------------------------------------------------------------
__global__ void prep_std(const float* __restrict__ src, u16* __restrict__ dst,
                         int Ksrc, int KPAD, int NOUT)
{
  int l = blockIdx.y;
  int per = KPAD * NOUT;
  int i = blockIdx.x * 256 + threadIdx.x;
  if (i >= per) return;
  int KSTEPS = KPAD / 32;
  int e = i & 7;
  int lane = (i >> 3) & 63;
  int ks = (i >> 9) % KSTEPS;
  int nf = i / (KSTEPS * 512);
  int c = nf * 16 + (lane & 15);
  int k = ks * 32 + (lane >> 4) * 8 + e;
  float v = (k < Ksrc) ? src[(size_t)l * Ksrc * NOUT + (size_t)k * NOUT + c] : 0.f;
  dst[(size_t)l * per + i] = f2bf(v);
}

// AB factorization weights: cols 0..127 = A (rows 0..127=h_dst, 128..177=+u,
// 178=+px, 179=+pt), cols 128..255 = B (rows 0..127=h_src, 128..177=-u, 178=-px, 179=0)
__global__ void prep_AB(const float* __restrict__ W, const float* __restrict__ bsrc,
                        u16* __restrict__ dst, float* __restrict__ bdst)
{
  int l = blockIdx.y;
  const int KSTEPS = 6;
  int i = blockIdx.x * 256 + threadIdx.x;       // < 192*256 = 49152
  int e = i & 7, lane = (i >> 3) & 63, ks = (i >> 9) % KSTEPS, nf = i / (KSTEPS * 512);
  int c = nf * 16 + (lane & 15);
  int k = ks * 32 + (lane >> 4) * 8 + e;
  const float* Wl = W + (size_t)l * 308 * 128;
  float v = 0.f;
  if (c < 128) {
    int rowi = -1;
    if (k < 128) rowi = k;
    else if (k < 178) rowi = 256 + (k - 128);
    else if (k == 178) rowi = 306;
    else if (k == 179) rowi = 307;
    if (rowi >= 0) v = Wl[rowi * 128 + c];
  } else {
    int cc = c - 128; float sgn = 1.f; int rowi = -1;
    if (k < 128) rowi = 128 + k;
    else if (k < 178) { rowi = 256 + (k - 128); sgn = -1.f; }
    else if (k == 178) { rowi = 306; sgn = -1.f; }
    if (rowi >= 0) v = sgn * Wl[rowi * 128 + cc];
  }
  dst[(size_t)l * 192 * 256 + i] = f2bf(v);
  if (i < 256) bdst[l * 256 + i] = (i < 128) ? bsrc[l * 128 + i] : 0.f;
}

// Static feature columns: X0[N][64] = [u(50), px, pt, 0..]; Xab cols 128..191 same;
// Xupd col 256 = pt.
__global__ __launch_bounds__(256) void build_static(
    const float* __restrict__ u, const float* __restrict__ pos,
    u16* __restrict__ X0, u16* __restrict__ Xab, u16* __restrict__ Xupd)
{
  int idx = blockIdx.x * 256 + threadIdx.x;   // N*64
  int n = idx >> 6, j = idx & 63;
  float px = pos[n * 2 + 1] * (1.f / L_PDE);
  float pt = pos[n * 2 + 0] * (1.f / TMAXC);
  float v;
  if (j < 50) v = u[n * 50 + j];
  else if (j == 50) v = px;
  else if (j == 51) v = pt;
  else v = 0.f;
  u16 b = f2bf(v);
  X0[n * 64 + j] = b;
  Xab[n * 192 + 128 + j] = b;
  if (j == 0) Xupd[n * 320 + 256] = f2bf(pt);
}

// ---------------------------------------------------------------------------
// Generic MFMA GEMM, col-split wave layout: 4 waves, wave = (rowHalf, colHalf)
// owns 32 rows x NOUT/2 cols -> each W-frag load feeds 2 MFMAs.
// X staged in LDS with (row&7)<<4 XOR swizzle. W frag-major from global.
// out==nullptr skips the bf16 output path; outF = optional f32 copy.
// ---------------------------------------------------------------------------
template<int KPAD, int NOUT, int ACT>
__global__ __launch_bounds__(256) void gemm_act(
    const u16* __restrict__ X, int ldx,
    const u16* __restrict__ Wf, const float* __restrict__ bias,
    u16* __restrict__ out, int ldo,
    u16* __restrict__ out2, int ldo2,
    float* __restrict__ outF)
{
  constexpr int KSTEPS = KPAD / 32;
  constexpr int NF = NOUT / 16;
  constexpr int NF2 = NF / 2;
  constexpr int LDO_S = NOUT + 8;
  constexpr int SMEM_US = 64 * (KPAD > LDO_S ? KPAD : LDO_S);
  __shared__ u16 sm[SMEM_US];
  int tid = threadIdx.x, lane = tid & 63, wid = tid >> 6;
  int n0 = blockIdx.x * 64;

  for (int c = tid; c < 64 * KPAD / 8; c += 256) {
    int r = c / (KPAD / 8), kc = c % (KPAD / 8);
    uint4 v = *(const uint4*)(X + (size_t)(n0 + r) * ldx + kc * 8);
    int byte = r * (KPAD * 2) + kc * 16; byte ^= ((r & 7) << 4);
    *(uint4*)((char*)sm + byte) = v;
  }
  __syncthreads();

  int rowHalf = wid & 1, colHalf = wid >> 1;
  f32x4 acc[2][NF2];
  f32x4 zero = {0.f, 0.f, 0.f, 0.f};
  #pragma unroll
  for (int m = 0; m < 2; ++m)
    #pragma unroll
    for (int i = 0; i < NF2; ++i) acc[m][i] = zero;
  int rowA = rowHalf * 32 + (lane & 15);
  int kb = lane >> 4;
  #pragma unroll
  for (int ks = 0; ks < KSTEPS; ++ks) {
    int ab0 = rowA * (KPAD * 2) + ks * 64 + kb * 16; ab0 ^= ((rowA & 7) << 4);
    int rA1 = rowA + 16;
    int ab1 = rA1 * (KPAD * 2) + ks * 64 + kb * 16; ab1 ^= ((rA1 & 7) << 4);
    bf16x8 a0 = *(const bf16x8*)((const char*)sm + ab0);
    bf16x8 a1 = *(const bf16x8*)((const char*)sm + ab1);
    #pragma unroll
    for (int nf2 = 0; nf2 < NF2; ++nf2) {
      bf16x8 b = *(const bf16x8*)(Wf + (((colHalf * NF2 + nf2) * KSTEPS + ks) * 64 + lane) * 8);
      acc[0][nf2] = __builtin_amdgcn_mfma_f32_16x16x32_bf16(a0, b, acc[0][nf2], 0, 0, 0);
      acc[1][nf2] = __builtin_amdgcn_mfma_f32_16x16x32_bf16(a1, b, acc[1][nf2], 0, 0, 0);
    }
  }
  __syncthreads();
  #pragma unroll
  for (int nf2 = 0; nf2 < NF2; ++nf2) {
    int col = colHalf * (NOUT / 2) + nf2 * 16 + (lane & 15);
    float bv = bias[col];
    #pragma unroll
    for (int m = 0; m < 2; ++m)
      #pragma unroll
      for (int j = 0; j < 4; ++j) {
        int r = rowHalf * 32 + m * 16 + (lane >> 4) * 4 + j;
        float v = acc[m][nf2][j] + bv;
        if (ACT == 1) v = swishf(v);
        if (out) sm[r * LDO_S + col] = f2bf(v);
        if (outF) outF[(size_t)(n0 + r) * NOUT + col] = v;
      }
  }
  __syncthreads();
  if (out) {
    for (int c = tid; c < 64 * NOUT / 8; c += 256) {
      int r = c / (NOUT / 8), kc = c % (NOUT / 8);
      uint4 v = *(const uint4*)(sm + r * LDO_S + kc * 8);
      *(uint4*)(out + (size_t)(n0 + r) * ldo + kc * 8) = v;
      if (out2) *(uint4*)(out2 + (size_t)(n0 + r) * ldo2 + kc * 8) = v;
    }
  }
}

// ---------------------------------------------------------------------------
// Edge message + mean-aggregate. 64 edges (=8 nodes, dst = e>>3) per block.
// Col-split wave layout like gemm_act (NF2=4, KSTEPS=4).
// ---------------------------------------------------------------------------
__global__ __launch_bounds__(256) void msg_kernel(
    const u16* __restrict__ AB, const int* __restrict__ srcIdx,
    const u16* __restrict__ Wf, const float* __restrict__ bm2,
    u16* __restrict__ Xupd)
{
  __shared__ u16 Ms[64 * 128];
  __shared__ float aggS[8][132];
  int tid = threadIdx.x, lane = tid & 63, wid = tid >> 6;
  int e0 = blockIdx.x * 64;
  for (int c = tid; c < 1024; c += 256) {
    int i = c >> 4, kc = c & 15;
    int e = e0 + i;
    int nd = e >> 3;
    int ns = srcIdx[e];
    union { uint4 v; u16 s[8]; } va, vb, vo;
    va.v = *(const uint4*)(AB + (size_t)nd * 256 + kc * 8);
    vb.v = *(const uint4*)(AB + (size_t)ns * 256 + 128 + kc * 8);
    #pragma unroll
    for (int j = 0; j < 8; ++j) vo.s[j] = f2bf(swishf(bf2f(va.s[j]) + bf2f(vb.s[j])));
    int byte = i * 256 + kc * 16; byte ^= ((i & 7) << 4);
    *(uint4*)((char*)Ms + byte) = vo.v;
  }
  __syncthreads();
  int rowHalf = wid & 1, colHalf = wid >> 1;
  f32x4 acc[2][4];
  f32x4 zero = {0.f, 0.f, 0.f, 0.f};
  #pragma unroll
  for (int m = 0; m < 2; ++m)
    #pragma unroll
    for (int i = 0; i < 4; ++i) acc[m][i] = zero;
  int rowA = rowHalf * 32 + (lane & 15), kb = lane >> 4;
  #pragma unroll
  for (int ks = 0; ks < 4; ++ks) {
    int ab0 = rowA * 256 + ks * 64 + kb * 16; ab0 ^= ((rowA & 7) << 4);
    int rA1 = rowA + 16;
    int ab1 = rA1 * 256 + ks * 64 + kb * 16; ab1 ^= ((rA1 & 7) << 4);
    bf16x8 a0 = *(const bf16x8*)((const char*)Ms + ab0);
    bf16x8 a1 = *(const bf16x8*)((const char*)Ms + ab1);
    #pragma unroll
    for (int nf2 = 0; nf2 < 4; ++nf2) {
      bf16x8 b = *(const bf16x8*)(Wf + (((colHalf * 4 + nf2) * 4 + ks) * 64 + lane) * 8);
      acc[0][nf2] = __builtin_amdgcn_mfma_f32_16x16x32_bf16(a0, b, acc[0][nf2], 0, 0, 0);
      acc[1][nf2] = __builtin_amdgcn_mfma_f32_16x16x32_bf16(a1, b, acc[1][nf2], 0, 0, 0);
    }
  }
  // aggregate: rows are edges; row = rowHalf*32 + m*16 + 4*(lane>>4)+j
  #pragma unroll
  for (int m = 0; m < 2; ++m)
    #pragma unroll
    for (int nf2 = 0; nf2 < 4; ++nf2) {
      int col = colHalf * 64 + nf2 * 16 + (lane & 15);
      float bv = bm2[col];
      float s = 0.f;
      #pragma unroll
      for (int j = 0; j < 4; ++j) s += swishf(acc[m][nf2][j] + bv);
      s += __shfl_xor(s, 16);
      if ((lane & 31) < 16)
        aggS[rowHalf * 4 + m * 2 + (lane >> 5)][col] = s * 0.125f;
    }
  __syncthreads();
  {
    int node = tid >> 5;
    int c0 = (tid & 31) * 4;
    int n = (e0 >> 3) + node;
    ushort4 o;
    o.x = f2bf(aggS[node][c0 + 0]);
    o.y = f2bf(aggS[node][c0 + 1]);
    o.z = f2bf(aggS[node][c0 + 2]);
    o.w = f2bf(aggS[node][c0 + 3]);
    *(ushort4*)(Xupd + (size_t)n * 320 + 128 + c0) = o;
  }
}

// hn = h + up, IN-PLACE on the f32 residual stream hB; also per-(graph,channel)
// moment partial sums.
__global__ __launch_bounds__(256) void resid_stats(
    float* hB, const u16* __restrict__ up,
    float* __restrict__ S1, float* __restrict__ S2)
{
  __shared__ float hs[64][129];
  int tid = threadIdx.x;
  int n0 = blockIdx.x * 64;
  for (int c = tid; c < 1024; c += 256) {
    int r = c >> 4, kc = c & 15;
    union { uint4 v; u16 s[8]; } b;
    b.v = *(const uint4*)(up + (size_t)(n0 + r) * 128 + kc * 8);
    float* hp = hB + (size_t)(n0 + r) * 128 + kc * 8;
    float4 h0 = *(const float4*)(hp);
    float4 h1 = *(const float4*)(hp + 4);
    float o[8];
    o[0] = h0.x + bf2f(b.s[0]); o[1] = h0.y + bf2f(b.s[1]);
    o[2] = h0.z + bf2f(b.s[2]); o[3] = h0.w + bf2f(b.s[3]);
    o[4] = h1.x + bf2f(b.s[4]); o[5] = h1.y + bf2f(b.s[5]);
    o[6] = h1.z + bf2f(b.s[6]); o[7] = h1.w + bf2f(b.s[7]);
    #pragma unroll
    for (int j = 0; j < 8; ++j) hs[r][kc * 8 + j] = o[j];
    *(float4*)(hp) = make_float4(o[0], o[1], o[2], o[3]);
    *(float4*)(hp + 4) = make_float4(o[4], o[5], o[6], o[7]);
  }
  __syncthreads();
  if (tid < 128) {
    float s1 = 0.f, s2 = 0.f;
    for (int r = 0; r < 64; ++r) { float v = hs[r][tid]; s1 += v; s2 += v * v; }
    int g = n0 >> 12;
    atomicAdd(&S1[g * 128 + tid], s1);
    atomicAdd(&S2[g * 128 + tid], s2);
  }
}

// instance-norm: h' = (hn - mean) * rsqrt(var + eps), IN-PLACE on hB;
// bf16 copies to Xab[,0:128] and Xupd[,0:128].
__global__ __launch_bounds__(256) void norm_k(
    float* hB, const float* __restrict__ S1, const float* __restrict__ S2,
    u16* __restrict__ Xab, u16* __restrict__ Xupd)
{
  int idx = blockIdx.x * 256 + threadIdx.x;   // N*16 chunks
  int n = idx >> 4, kc = idx & 15;
  int g = n >> 12;
  float* hp = hB + (size_t)n * 128 + kc * 8;
  float4 a0 = *(const float4*)(hp);
  float4 a1 = *(const float4*)(hp + 4);
  float x[8] = {a0.x, a0.y, a0.z, a0.w, a1.x, a1.y, a1.z, a1.w};
  union { uint4 v; u16 s[8]; } o;
  float of[8];
  #pragma unroll
  for (int j = 0; j < 8; ++j) {
    int c = kc * 8 + j;
    float m = S1[g * 128 + c] * (1.f / NPG);
    float var = S2[g * 128 + c] * (1.f / NPG) - m * m;
    float v = (x[j] - m) * rsqrtf(var + EPSC);
    of[j] = v;
    o.s[j] = f2bf(v);
  }
  *(uint4*)(Xab + (size_t)n * 192 + kc * 8) = o.v;
  *(uint4*)(Xupd + (size_t)n * 320 + kc * 8) = o.v;
  *(float4*)(hp) = make_float4(of[0], of[1], of[2], of[3]);
  *(float4*)(hp + 4) = make_float4(of[4], of[5], of[6], of[7]);
}

// ---------------------------------------------------------------------------
// Decoder tail, register-resident: 8 threads per node (thread = (n, o)).
// conv1 (2->8,k16,s3) fully unrolled in registers from f32 x2; swish;
// conv2 (8->2,k14) per-output with 3-step shuffle butterfly over the 8 lanes.
// No LDS at all.
// ---------------------------------------------------------------------------
__global__ __launch_bounds__(256) void dec_conv(
    const float* __restrict__ x2f, const float* __restrict__ u,
    const float* __restrict__ w1, const float* __restrict__ b1,
    const float* __restrict__ w2, const float* __restrict__ b2,
    float* __restrict__ outp)
{
  int tid = threadIdx.x;
  int o = tid & 7;
  int n = blockIdx.x * 32 + (tid >> 3);

  float w1r[32];
  {
    const float4* wp = (const float4*)(w1 + o * 32);
    #pragma unroll
    for (int i = 0; i < 8; ++i) {
      float4 v = wp[i];
      w1r[i*4+0]=v.x; w1r[i*4+1]=v.y; w1r[i*4+2]=v.z; w1r[i*4+3]=v.w;
    }
  }
  float b1v = b1[o];
  float y[38];
  #pragma unroll
  for (int t = 0; t < 38; ++t) y[t] = b1v;

  #pragma unroll
  for (int cc = 0; cc < 2; ++cc) {
    #pragma unroll
    for (int h = 0; h < 2; ++h) {
      const int off = h ? 56 : 0;   // 16B-aligned window start
      const int sh  = h ? 1 : 0;    // 3*19 = 57 = off + 1
      const int t0  = h ? 19 : 0;
      float xw[72];
      const float4* xp = (const float4*)(x2f + (size_t)n * 256 + cc * 128 + off);
      #pragma unroll
      for (int i = 0; i < 18; ++i) {
        float4 v = xp[i];
        xw[i*4+0]=v.x; xw[i*4+1]=v.y; xw[i*4+2]=v.z; xw[i*4+3]=v.w;
      }
      #pragma unroll
      for (int tt = 0; tt < 19; ++tt)
        #pragma unroll
        for (int k = 0; k < 16; ++k)
          y[t0 + tt] += xw[sh + 3*tt + k] * w1r[cc*16 + k];
    }
  }
  #pragma unroll
  for (int t = 0; t < 38; ++t) y[t] = swishf(y[t]);

  float w2r[28];
  #pragma unroll
  for (int c = 0; c < 2; ++c)
    #pragma unroll
    for (int k = 0; k < 14; ++k)
      w2r[c*14 + k] = w2[(c*8 + o)*14 + k];
  float b2r0 = b2[0], b2r1 = b2[1];

  #pragma unroll
  for (int i = 0; i < 50; ++i) {
    const int c = i / 25, t = i % 25;
    float p = 0.f;
    #pragma unroll
    for (int k = 0; k < 14; ++k) p += y[t + k] * w2r[c*14 + k];
    p += __shfl_xor(p, 1);
    p += __shfl_xor(p, 2);
    p += __shfl_xor(p, 4);
    if (o == (i & 7)) {
      int gi = n * 50 + i;
      float diff = p + (c ? b2r1 : b2r0);
      outp[gi] = u[gi] + (DTC * (t + 1)) * diff;
    }
  }
}

extern "C" void kernel_launch(void* const* d_in, const int* in_sizes, int n_in,
                              void* d_out, int out_size, void* d_ws, size_t ws_size,
                              hipStream_t stream) {
  const float* u     = (const float*)d_in[0];
  const float* pos   = (const float*)d_in[1];
  const int*   eidx  = (const int*)d_in[2];
  const float* embW1 = (const float*)d_in[4];
  const float* embb1 = (const float*)d_in[5];
  const float* embW2 = (const float*)d_in[6];
  const float* embb2 = (const float*)d_in[7];
  const float* m1W   = (const float*)d_in[8];
  const float* m1b   = (const float*)d_in[9];
  const float* m2W   = (const float*)d_in[10];
  const float* m2b   = (const float*)d_in[11];
  const float* u1W   = (const float*)d_in[12];
  const float* u1b   = (const float*)d_in[13];
  const float* u2W   = (const float*)d_in[14];
  const float* u2b   = (const float*)d_in[15];
  const float* dblW  = (const float*)d_in[16];
  const float* dblb  = (const float*)d_in[17];
  const float* c1W   = (const float*)d_in[18];
  const float* c1b   = (const float*)d_in[19];
  const float* c2W   = (const float*)d_in[20];
  const float* c2b   = (const float*)d_in[21];
  float* outp = (float*)d_out;
  const int* srcI = eidx;   // edge_index[0] = src; dst(e) = e>>3 by construction

  char* ws = (char*)d_ws;
  size_t off = 0;
  auto alloc = [&](size_t bytes) -> char* {
    char* p = ws + off; off += (bytes + 255) & ~(size_t)255; return p;
  };
  u16* X0    = (u16*)alloc((size_t)N_NODES * 64 * 2);
  u16* h1    = (u16*)alloc((size_t)N_NODES * 128 * 2);
  u16* Xab   = (u16*)alloc((size_t)N_NODES * 192 * 2);   // [h(128) | u(50) | px | pt | pad]
  u16* Xupd  = (u16*)alloc((size_t)N_NODES * 320 * 2);   // [h(128) | agg(128) | pt | pad]
  u16* ABbuf = (u16*)alloc((size_t)N_NODES * 256 * 2);
  u16* z1    = (u16*)alloc((size_t)N_NODES * 128 * 2);
  u16* upb   = (u16*)alloc((size_t)N_NODES * 128 * 2);
  float* hB  = (float*)alloc((size_t)N_NODES * 128 * 4); // f32 residual stream (in-place)
  float* stats = (float*)alloc((size_t)NL * 2 * 1024 * 4);
  u16* WembF1 = (u16*)alloc(64 * 128 * 2);
  u16* WembF2 = (u16*)alloc(128 * 128 * 2);
  u16* WABf   = (u16*)alloc((size_t)6 * 192 * 256 * 2);
  float* bABf = (float*)alloc(6 * 256 * 4);
  u16* Wm2f   = (u16*)alloc((size_t)6 * 128 * 128 * 2);
  u16* Wu1f   = (u16*)alloc((size_t)6 * 320 * 128 * 2);
  u16* Wu2f   = (u16*)alloc((size_t)6 * 128 * 128 * 2);
  u16* Wdblf  = (u16*)alloc((size_t)192 * 256 * 2);
  // x2 f32 for the decoder: aliased over ABbuf+z1+upb (dead after last msg);
  // 33.55 MB needed, 33.6+ MB available in that span.
  float* x2f = (float*)ABbuf;

  hipMemsetAsync(stats, 0, (size_t)NL * 2 * 1024 * 4, stream);

  prep_std<<<dim3(32, 1), 256, 0, stream>>>(embW1, WembF1, 52, 64, 128);
  prep_std<<<dim3(64, 1), 256, 0, stream>>>(embW2, WembF2, 128, 128, 128);
  prep_std<<<dim3(64, 6), 256, 0, stream>>>(m2W, Wm2f, 128, 128, 128);
  prep_std<<<dim3(160, 6), 256, 0, stream>>>(u1W, Wu1f, 257, 320, 128);
  prep_std<<<dim3(64, 6), 256, 0, stream>>>(u2W, Wu2f, 128, 128, 128);
  prep_std<<<dim3(192, 1), 256, 0, stream>>>(dblW, Wdblf, 128, 192, 256);
  prep_AB<<<dim3(192, 6), 256, 0, stream>>>(m1W, m1b, WABf, bABf);
  build_static<<<N_NODES * 64 / 256, 256, 0, stream>>>(u, pos, X0, Xab, Xupd);

  // encoder
  gemm_act<64, 128, 1><<<512, 256, 0, stream>>>(
      X0, 64, WembF1, embb1, h1, 128, nullptr, 0, nullptr);
  gemm_act<128, 128, 1><<<512, 256, 0, stream>>>(
      h1, 128, WembF2, embb2, Xab, 192, Xupd, 320, hB);

  for (int l = 0; l < NL; ++l) {
    gemm_act<192, 256, 0><<<512, 256, 0, stream>>>(
        Xab, 192, WABf + (size_t)l * 192 * 256, bABf + l * 256, ABbuf, 256,
        nullptr, 0, nullptr);
    msg_kernel<<<N_EDGES / 64, 256, 0, stream>>>(
        ABbuf, srcI, Wm2f + (size_t)l * 128 * 128, m2b + l * 128, Xupd);
    gemm_act<320, 128, 1><<<512, 256, 0, stream>>>(
        Xupd, 320, Wu1f + (size_t)l * 320 * 128, u1b + l * 128, z1, 128,
        nullptr, 0, nullptr);
    gemm_act<128, 128, 1><<<512, 256, 0, stream>>>(
        z1, 128, Wu2f + (size_t)l * 128 * 128, u2b + l * 128, upb, 128,
        nullptr, 0, nullptr);
    resid_stats<<<512, 256, 0, stream>>>(
        hB, upb, stats + l * 2048, stats + l * 2048 + 1024);
    norm_k<<<N_NODES * 16 / 256, 256, 0, stream>>>(
        hB, stats + l * 2048, stats + l * 2048 + 1024, Xab, Xupd);
  }

  // double_mlp -> f32 x2 (bf16 path skipped), then register-resident decoder
  gemm_act<192, 256, 1><<<512, 256, 0, stream>>>(
      Xab, 192, Wdblf, dblb, nullptr, 0, nullptr, 0, x2f);
  dec_conv<<<N_NODES / 32, 256, 0, stream>>>(x2f, u, c1W, c1b, c2W, c2b, outp);
}

// Round 6
// 788.875 us; speedup vs baseline: 1.3455x; 1.0698x over previous
//
#include <hip/hip_runtime.h>
#include <hip/hip_bf16.h>

#define N_NODES 32768
#define N_GRAPHS 8
#define NPG 4096
#define DEG 8
#define N_EDGES (N_NODES*DEG)
#define TW 25
#define NL 6
#define L_PDE 16.0f
#define TMAXC 4.0f
#define DTC 0.04f
#define EPSC 1e-5f

typedef __bf16 bf16x8 __attribute__((ext_vector_type(8)));
typedef float f32x4 __attribute__((ext_vector_type(4)));
typedef unsigned short u16;
typedef unsigned int u32;

__device__ __forceinline__ float bf2f(u16 h){
  union { float f; u32 u; } v; v.u = ((u32)h) << 16; return v.f;
}
__device__ __forceinline__ u16 f2bf(float f){
  union { float f; u32 u; } v; v.f = f;
  u32 r = v.u + 0x7FFFu + ((v.u >> 16) & 1u);
  return (u16)(r >> 16);
}
__device__ __forceinline__ float swishf(float x){
  return x / (1.0f + __expf(-x));
}

// ---------------------------------------------------------------------------
// Weight prep: repack W[K][N] (f32, k-major) into frag-major bf16.
// ---------------------------------------------------------------------------
__global__ void prep_std(const float* __restrict__ src, u16* __restrict__ dst,
                         int Ksrc, int KPAD, int NOUT)
{
  int l = blockIdx.y;
  int per = KPAD * NOUT;
  int i = blockIdx.x * 256 + threadIdx.x;
  if (i >= per) return;
  int KSTEPS = KPAD / 32;
  int e = i & 7;
  int lane = (i >> 3) & 63;
  int ks = (i >> 9) % KSTEPS;
  int nf = i / (KSTEPS * 512);
  int c = nf * 16 + (lane & 15);
  int k = ks * 32 + (lane >> 4) * 8 + e;
  float v = (k < Ksrc) ? src[(size_t)l * Ksrc * NOUT + (size_t)k * NOUT + c] : 0.f;
  dst[(size_t)l * per + i] = f2bf(v);
}

// AB factorization weights (see earlier rounds).
__global__ void prep_AB(const float* __restrict__ W, const float* __restrict__ bsrc,
                        u16* __restrict__ dst, float* __restrict__ bdst)
{
  int l = blockIdx.y;
  const int KSTEPS = 6;
  int i = blockIdx.x * 256 + threadIdx.x;       // < 192*256 = 49152
  int e = i & 7, lane = (i >> 3) & 63, ks = (i >> 9) % KSTEPS, nf = i / (KSTEPS * 512);
  int c = nf * 16 + (lane & 15);
  int k = ks * 32 + (lane >> 4) * 8 + e;
  const float* Wl = W + (size_t)l * 308 * 128;
  float v = 0.f;
  if (c < 128) {
    int rowi = -1;
    if (k < 128) rowi = k;
    else if (k < 178) rowi = 256 + (k - 128);
    else if (k == 178) rowi = 306;
    else if (k == 179) rowi = 307;
    if (rowi >= 0) v = Wl[rowi * 128 + c];
  } else {
    int cc = c - 128; float sgn = 1.f; int rowi = -1;
    if (k < 128) rowi = 128 + k;
    else if (k < 178) { rowi = 256 + (k - 128); sgn = -1.f; }
    else if (k == 178) { rowi = 306; sgn = -1.f; }
    if (rowi >= 0) v = sgn * Wl[rowi * 128 + cc];
  }
  dst[(size_t)l * 192 * 256 + i] = f2bf(v);
  if (i < 256) bdst[l * 256 + i] = (i < 128) ? bsrc[l * 128 + i] : 0.f;
}

// Static feature columns: X0[N][64] = [u(50), px, pt, 0..]
__global__ __launch_bounds__(256) void build_static(
    const float* __restrict__ u, const float* __restrict__ pos,
    u16* __restrict__ X0)
{
  int idx = blockIdx.x * 256 + threadIdx.x;   // N*64
  int n = idx >> 6, j = idx & 63;
  float v;
  if (j < 50) v = u[n * 50 + j];
  else if (j == 50) v = pos[n * 2 + 1] * (1.f / L_PDE);
  else if (j == 51) v = pos[n * 2 + 0] * (1.f / TMAXC);
  else v = 0.f;
  X0[n * 64 + j] = f2bf(v);
}

// ---------------------------------------------------------------------------
// Unified MFMA GEMM. Col-split wave layout (wave = 32 rows x NOUT/2 cols).
// SMODE: 0 = plain bf16 X[ldx];
//        1 = [norm(hB,statsPrev) (128) | X0 static (KPAD-128)]
//        2 = [norm(hB) (128) | Agg (128) | pt,0.. (KPAD-256)]
// RESID: epilogue does hn = norm(hB)+swish(acc+b), writes hB, accumulates
//        per-(graph,col) moments into S1n/S2n (atomics).
// HASOUT: stage + write bf16 `out`. outF: scattered f32 copy of activation.
// ---------------------------------------------------------------------------
template<int KPAD, int NOUT, int ACT, int SMODE, int RESID, int HASOUT>
__global__ __launch_bounds__(256) void gemm2(
    const u16* __restrict__ X, int ldx,
    const u16* __restrict__ Xaux,
    float* hB,
    const float* __restrict__ S1p, const float* __restrict__ S2p,
    const float* __restrict__ pos,
    const u16* __restrict__ Wf, const float* __restrict__ bias,
    u16* __restrict__ out, int ldo,
    float* __restrict__ outF,
    float* __restrict__ S1n, float* __restrict__ S2n)
{
  constexpr int KSTEPS = KPAD / 32;
  constexpr int NF2 = NOUT / 32;
  constexpr int CHUNKS = KPAD / 8;
  constexpr int LDO_S = NOUT + 8;
  constexpr int SMEM_US = 64 * (HASOUT ? (KPAD > LDO_S ? KPAD : LDO_S) : KPAD);
  __shared__ u16 sm[SMEM_US];
  int tid = threadIdx.x, lane = tid & 63, wid = tid >> 6;
  int n0 = blockIdx.x * 64;
  int g = n0 >> 12;

  for (int c = tid; c < 64 * CHUNKS; c += 256) {
    int r = c / CHUNKS, kc = c % CHUNKS;
    int n = n0 + r;
    union { uint4 v; u16 s[8]; } o;
    if (SMODE == 0) {
      o.v = *(const uint4*)(X + (size_t)n * ldx + kc * 8);
    } else {
      if (kc < 16) {
        const float* hp = hB + (size_t)n * 128 + kc * 8;
        float4 a0 = *(const float4*)hp, a1 = *(const float4*)(hp + 4);
        float xv[8] = {a0.x,a0.y,a0.z,a0.w,a1.x,a1.y,a1.z,a1.w};
        if (S1p) {
          #pragma unroll
          for (int j = 0; j < 8; ++j) {
            int cc = kc * 8 + j;
            float m = S1p[g * 128 + cc] * (1.f / NPG);
            float var = S2p[g * 128 + cc] * (1.f / NPG) - m * m;
            xv[j] = (xv[j] - m) * rsqrtf(var + EPSC);
          }
        }
        #pragma unroll
        for (int j = 0; j < 8; ++j) o.s[j] = f2bf(xv[j]);
      } else if (SMODE == 1) {
        o.v = *(const uint4*)(Xaux + (size_t)n * 64 + (kc - 16) * 8);
      } else {
        if (kc < 32) {
          o.v = *(const uint4*)(Xaux + (size_t)n * 128 + (kc - 16) * 8);
        } else {
          #pragma unroll
          for (int j = 0; j < 8; ++j) o.s[j] = 0;
          if (kc == 32) o.s[0] = f2bf(pos[n * 2] * (1.f / TMAXC));
        }
      }
    }
    int byte = r * (KPAD * 2) + kc * 16; byte ^= ((r & 7) << 4);
    *(uint4*)((char*)sm + byte) = o.v;
  }
  __syncthreads();

  int rowHalf = wid & 1, colHalf = wid >> 1;
  f32x4 acc[2][NF2];
  f32x4 zero = {0.f, 0.f, 0.f, 0.f};
  #pragma unroll
  for (int m = 0; m < 2; ++m)
    #pragma unroll
    for (int i = 0; i < NF2; ++i) acc[m][i] = zero;
  int rowA = rowHalf * 32 + (lane & 15);
  int kb = lane >> 4;
  #pragma unroll
  for (int ks = 0; ks < KSTEPS; ++ks) {
    int ab0 = rowA * (KPAD * 2) + ks * 64 + kb * 16; ab0 ^= ((rowA & 7) << 4);
    int rA1 = rowA + 16;
    int ab1 = rA1 * (KPAD * 2) + ks * 64 + kb * 16; ab1 ^= ((rA1 & 7) << 4);
    bf16x8 a0 = *(const bf16x8*)((const char*)sm + ab0);
    bf16x8 a1 = *(const bf16x8*)((const char*)sm + ab1);
    #pragma unroll
    for (int nf2 = 0; nf2 < NF2; ++nf2) {
      bf16x8 b = *(const bf16x8*)(Wf + (((colHalf * NF2 + nf2) * KSTEPS + ks) * 64 + lane) * 8);
      acc[0][nf2] = __builtin_amdgcn_mfma_f32_16x16x32_bf16(a0, b, acc[0][nf2], 0, 0, 0);
      acc[1][nf2] = __builtin_amdgcn_mfma_f32_16x16x32_bf16(a1, b, acc[1][nf2], 0, 0, 0);
    }
  }

  if (RESID) {
    float s1l[NF2], s2l[NF2];
    #pragma unroll
    for (int i = 0; i < NF2; ++i) { s1l[i] = 0.f; s2l[i] = 0.f; }
    #pragma unroll
    for (int nf2 = 0; nf2 < NF2; ++nf2) {
      int col = colHalf * (NOUT / 2) + nf2 * 16 + (lane & 15);
      float bv = bias[col];
      float mm = 0.f, rsig = 1.f;
      if (S1p) {
        mm = S1p[g * 128 + col] * (1.f / NPG);
        float var = S2p[g * 128 + col] * (1.f / NPG) - mm * mm;
        rsig = rsqrtf(var + EPSC);
      }
      #pragma unroll
      for (int m = 0; m < 2; ++m)
        #pragma unroll
        for (int j = 0; j < 4; ++j) {
          int r = rowHalf * 32 + m * 16 + (lane >> 4) * 4 + j;
          int n = n0 + r;
          float v = acc[m][nf2][j] + bv;
          if (ACT == 1) v = swishf(v);
          float hc = hB[(size_t)n * 128 + col];
          hc = (hc - mm) * rsig;
          float hn = hc + v;
          hB[(size_t)n * 128 + col] = hn;
          s1l[nf2] += hn; s2l[nf2] += hn * hn;
        }
    }
    #pragma unroll
    for (int nf2 = 0; nf2 < NF2; ++nf2) {
      float s1 = s1l[nf2], s2 = s2l[nf2];
      s1 += __shfl_xor(s1, 16); s1 += __shfl_xor(s1, 32);
      s2 += __shfl_xor(s2, 16); s2 += __shfl_xor(s2, 32);
      if ((lane >> 4) == 0) {
        int col = colHalf * (NOUT / 2) + nf2 * 16 + (lane & 15);
        atomicAdd(&S1n[g * 128 + col], s1);
        atomicAdd(&S2n[g * 128 + col], s2);
      }
    }
  } else {
    if (HASOUT) __syncthreads();
    #pragma unroll
    for (int nf2 = 0; nf2 < NF2; ++nf2) {
      int col = colHalf * (NOUT / 2) + nf2 * 16 + (lane & 15);
      float bv = bias[col];
      #pragma unroll
      for (int m = 0; m < 2; ++m)
        #pragma unroll
        for (int j = 0; j < 4; ++j) {
          int r = rowHalf * 32 + m * 16 + (lane >> 4) * 4 + j;
          float v = acc[m][nf2][j] + bv;
          if (ACT == 1) v = swishf(v);
          if (HASOUT) sm[r * LDO_S + col] = f2bf(v);
          if (outF) outF[(size_t)(n0 + r) * NOUT + col] = v;
        }
    }
    if (HASOUT) {
      __syncthreads();
      for (int c = tid; c < 64 * NOUT / 8; c += 256) {
        int r = c / (NOUT / 8), kc = c % (NOUT / 8);
        uint4 v = *(const uint4*)(sm + r * LDO_S + kc * 8);
        *(uint4*)(out + (size_t)(n0 + r) * ldo + kc * 8) = v;
      }
    }
  }
}

// ---------------------------------------------------------------------------
// Edge message + mean-aggregate -> Agg[n][128] bf16.
// ---------------------------------------------------------------------------
__global__ __launch_bounds__(256) void msg_kernel(
    const u16* __restrict__ AB, const int* __restrict__ srcIdx,
    const u16* __restrict__ Wf, const float* __restrict__ bm2,
    u16* __restrict__ Agg)
{
  __shared__ u16 Ms[64 * 128];
  __shared__ float aggS[8][132];
  int tid = threadIdx.x, lane = tid & 63, wid = tid >> 6;
  int e0 = blockIdx.x * 64;
  for (int c = tid; c < 1024; c += 256) {
    int i = c >> 4, kc = c & 15;
    int e = e0 + i;
    int nd = e >> 3;
    int ns = srcIdx[e];
    union { uint4 v; u16 s[8]; } va, vb, vo;
    va.v = *(const uint4*)(AB + (size_t)nd * 256 + kc * 8);
    vb.v = *(const uint4*)(AB + (size_t)ns * 256 + 128 + kc * 8);
    #pragma unroll
    for (int j = 0; j < 8; ++j) vo.s[j] = f2bf(swishf(bf2f(va.s[j]) + bf2f(vb.s[j])));
    int byte = i * 256 + kc * 16; byte ^= ((i & 7) << 4);
    *(uint4*)((char*)Ms + byte) = vo.v;
  }
  __syncthreads();
  int rowHalf = wid & 1, colHalf = wid >> 1;
  f32x4 acc[2][4];
  f32x4 zero = {0.f, 0.f, 0.f, 0.f};
  #pragma unroll
  for (int m = 0; m < 2; ++m)
    #pragma unroll
    for (int i = 0; i < 4; ++i) acc[m][i] = zero;
  int rowA = rowHalf * 32 + (lane & 15), kb = lane >> 4;
  #pragma unroll
  for (int ks = 0; ks < 4; ++ks) {
    int ab0 = rowA * 256 + ks * 64 + kb * 16; ab0 ^= ((rowA & 7) << 4);
    int rA1 = rowA + 16;
    int ab1 = rA1 * 256 + ks * 64 + kb * 16; ab1 ^= ((rA1 & 7) << 4);
    bf16x8 a0 = *(const bf16x8*)((const char*)Ms + ab0);
    bf16x8 a1 = *(const bf16x8*)((const char*)Ms + ab1);
    #pragma unroll
    for (int nf2 = 0; nf2 < 4; ++nf2) {
      bf16x8 b = *(const bf16x8*)(Wf + (((colHalf * 4 + nf2) * 4 + ks) * 64 + lane) * 8);
      acc[0][nf2] = __builtin_amdgcn_mfma_f32_16x16x32_bf16(a0, b, acc[0][nf2], 0, 0, 0);
      acc[1][nf2] = __builtin_amdgcn_mfma_f32_16x16x32_bf16(a1, b, acc[1][nf2], 0, 0, 0);
    }
  }
  #pragma unroll
  for (int m = 0; m < 2; ++m)
    #pragma unroll
    for (int nf2 = 0; nf2 < 4; ++nf2) {
      int col = colHalf * 64 + nf2 * 16 + (lane & 15);
      float bv = bm2[col];
      float s = 0.f;
      #pragma unroll
      for (int j = 0; j < 4; ++j) s += swishf(acc[m][nf2][j] + bv);
      s += __shfl_xor(s, 16);
      if ((lane & 31) < 16)
        aggS[rowHalf * 4 + m * 2 + (lane >> 5)][col] = s * 0.125f;
    }
  __syncthreads();
  {
    int node = tid >> 5;
    int c0 = (tid & 31) * 4;
    int n = (e0 >> 3) + node;
    ushort4 o;
    o.x = f2bf(aggS[node][c0 + 0]);
    o.y = f2bf(aggS[node][c0 + 1]);
    o.z = f2bf(aggS[node][c0 + 2]);
    o.w = f2bf(aggS[node][c0 + 3]);
    *(ushort4*)(Agg + (size_t)n * 128 + c0) = o;
  }
}

// ---------------------------------------------------------------------------
// Decoder, streaming-scatter conv1: 8 threads/node (thread = (n,o)).
// x2 row streamed once per cc in float4 chunks, scattered into y[38] with
// compile-time (t,k) patterns -> no big live window. conv2 via 3-step
// butterfly over the 8 o-lanes.
// ---------------------------------------------------------------------------
__global__ __launch_bounds__(256) void dec_conv(
    const float* __restrict__ x2f, const float* __restrict__ u,
    const float* __restrict__ w1, const float* __restrict__ b1,
    const float* __restrict__ w2, const float* __restrict__ b2,
    float* __restrict__ outp)
{
  int tid = threadIdx.x;
  int o = tid & 7;
  int n = blockIdx.x * 32 + (tid >> 3);

  float b1v = b1[o];
  float y[38];
  #pragma unroll
  for (int t = 0; t < 38; ++t) y[t] = b1v;

  #pragma unroll
  for (int cc = 0; cc < 2; ++cc) {
    float w1r[16];
    {
      const float4* wp = (const float4*)(w1 + o * 32 + cc * 16);
      #pragma unroll
      for (int i = 0; i < 4; ++i) {
        float4 v = wp[i];
        w1r[i*4+0]=v.x; w1r[i*4+1]=v.y; w1r[i*4+2]=v.z; w1r[i*4+3]=v.w;
      }
    }
    const float4* xp = (const float4*)(x2f + (size_t)n * 256 + cc * 128);
    #pragma unroll
    for (int ch = 0; ch < 32; ++ch) {
      float4 xv = xp[ch];
      float xe[4] = {xv.x, xv.y, xv.z, xv.w};
      #pragma unroll
      for (int e = 0; e < 4; ++e) {
        const int j = ch * 4 + e;
        #pragma unroll
        for (int k = 0; k < 16; ++k) {
          const int tm = j - k;
          if (tm >= 0 && (tm % 3) == 0 && (tm / 3) < 38)
            y[tm / 3] += xe[e] * w1r[k];
        }
      }
    }
  }
  #pragma unroll
  for (int t = 0; t < 38; ++t) y[t] = swishf(y[t]);

  float w2r[28];
  #pragma unroll
  for (int c = 0; c < 2; ++c)
    #pragma unroll
    for (int k = 0; k < 14; ++k)
      w2r[c*14 + k] = w2[(c*8 + o)*14 + k];
  float b2r0 = b2[0], b2r1 = b2[1];

  #pragma unroll
  for (int i = 0; i < 50; ++i) {
    const int c = i / 25, t = i % 25;
    float p = 0.f;
    #pragma unroll
    for (int k = 0; k < 14; ++k) p += y[t + k] * w2r[c*14 + k];
    p += __shfl_xor(p, 1);
    p += __shfl_xor(p, 2);
    p += __shfl_xor(p, 4);
    if (o == (i & 7)) {
      int gi = n * 50 + i;
      float diff = p + (c ? b2r1 : b2r0);
      outp[gi] = u[gi] + (DTC * (t + 1)) * diff;
    }
  }
}

extern "C" void kernel_launch(void* const* d_in, const int* in_sizes, int n_in,
                              void* d_out, int out_size, void* d_ws, size_t ws_size,
                              hipStream_t stream) {
  const float* u     = (const float*)d_in[0];
  const float* pos   = (const float*)d_in[1];
  const int*   eidx  = (const int*)d_in[2];
  const float* embW1 = (const float*)d_in[4];
  const float* embb1 = (const float*)d_in[5];
  const float* embW2 = (const float*)d_in[6];
  const float* embb2 = (const float*)d_in[7];
  const float* m1W   = (const float*)d_in[8];
  const float* m1b   = (const float*)d_in[9];
  const float* m2W   = (const float*)d_in[10];
  const float* m2b   = (const float*)d_in[11];
  const float* u1W   = (const float*)d_in[12];
  const float* u1b   = (const float*)d_in[13];
  const float* u2W   = (const float*)d_in[14];
  const float* u2b   = (const float*)d_in[15];
  const float* dblW  = (const float*)d_in[16];
  const float* dblb  = (const float*)d_in[17];
  const float* c1W   = (const float*)d_in[18];
  const float* c1b   = (const float*)d_in[19];
  const float* c2W   = (const float*)d_in[20];
  const float* c2b   = (const float*)d_in[21];
  float* outp = (float*)d_out;
  const int* srcI = eidx;   // edge_index[0] = src; dst(e) = e>>3 by construction

  char* ws = (char*)d_ws;
  size_t off = 0;
  auto alloc = [&](size_t bytes) -> char* {
    char* p = ws + off; off += (bytes + 255) & ~(size_t)255; return p;
  };
  u16* X0    = (u16*)alloc((size_t)N_NODES * 64 * 2);    // static cols
  u16* h1    = (u16*)alloc((size_t)N_NODES * 128 * 2);
  u16* ABbuf = (u16*)alloc((size_t)N_NODES * 256 * 2);
  u16* z1    = (u16*)alloc((size_t)N_NODES * 128 * 2);
  u16* Agg   = (u16*)alloc((size_t)N_NODES * 128 * 2);
  float* hB  = (float*)alloc((size_t)N_NODES * 128 * 4); // f32 residual (un-normed hn + stats)
  float* x2f = (float*)alloc((size_t)N_NODES * 256 * 4);
  float* stats = (float*)alloc((size_t)NL * 2 * 1024 * 4);
  u16* WembF1 = (u16*)alloc(64 * 128 * 2);
  u16* WembF2 = (u16*)alloc(128 * 128 * 2);
  u16* WABf   = (u16*)alloc((size_t)6 * 192 * 256 * 2);
  float* bABf = (float*)alloc(6 * 256 * 4);
  u16* Wm2f   = (u16*)alloc((size_t)6 * 128 * 128 * 2);
  u16* Wu1f   = (u16*)alloc((size_t)6 * 320 * 128 * 2);
  u16* Wu2f   = (u16*)alloc((size_t)6 * 128 * 128 * 2);
  u16* Wdblf  = (u16*)alloc((size_t)128 * 256 * 2);

  hipMemsetAsync(stats, 0, (size_t)NL * 2 * 1024 * 4, stream);

  prep_std<<<dim3(32, 1), 256, 0, stream>>>(embW1, WembF1, 52, 64, 128);
  prep_std<<<dim3(64, 1), 256, 0, stream>>>(embW2, WembF2, 128, 128, 128);
  prep_std<<<dim3(64, 6), 256, 0, stream>>>(m2W, Wm2f, 128, 128, 128);
  prep_std<<<dim3(160, 6), 256, 0, stream>>>(u1W, Wu1f, 257, 320, 128);
  prep_std<<<dim3(64, 6), 256, 0, stream>>>(u2W, Wu2f, 128, 128, 128);
  prep_std<<<dim3(128, 1), 256, 0, stream>>>(dblW, Wdblf, 128, 128, 256);
  prep_AB<<<dim3(192, 6), 256, 0, stream>>>(m1W, m1b, WABf, bABf);
  build_static<<<N_NODES * 64 / 256, 256, 0, stream>>>(u, pos, X0);

  // encoder: X0 -> h1 -> hB (f32 residual seed)
  gemm2<64, 128, 1, 0, 0, 1><<<512, 256, 0, stream>>>(
      X0, 64, nullptr, nullptr, nullptr, nullptr, nullptr,
      WembF1, embb1, h1, 128, nullptr, nullptr, nullptr);
  gemm2<128, 128, 1, 0, 0, 0><<<512, 256, 0, stream>>>(
      h1, 128, nullptr, nullptr, nullptr, nullptr, nullptr,
      WembF2, embb2, nullptr, 0, hB, nullptr, nullptr);

  for (int l = 0; l < NL; ++l) {
    const float* S1p = l ? stats + (size_t)(l - 1) * 2048 : nullptr;
    const float* S2p = l ? stats + (size_t)(l - 1) * 2048 + 1024 : nullptr;
    float* S1n = stats + (size_t)l * 2048;
    float* S2n = S1n + 1024;
    gemm2<192, 256, 0, 1, 0, 1><<<512, 256, 0, stream>>>(
        nullptr, 0, X0, hB, S1p, S2p, nullptr,
        WABf + (size_t)l * 192 * 256, bABf + l * 256, ABbuf, 256,
        nullptr, nullptr, nullptr);
    msg_kernel<<<N_EDGES / 64, 256, 0, stream>>>(
        ABbuf, srcI, Wm2f + (size_t)l * 128 * 128, m2b + l * 128, Agg);
    gemm2<320, 128, 1, 2, 0, 1><<<512, 256, 0, stream>>>(
        nullptr, 0, Agg, hB, S1p, S2p, pos,
        Wu1f + (size_t)l * 320 * 128, u1b + l * 128, z1, 128,
        nullptr, nullptr, nullptr);
    gemm2<128, 128, 1, 0, 1, 0><<<512, 256, 0, stream>>>(
        z1, 128, nullptr, hB, S1p, S2p, nullptr,
        Wu2f + (size_t)l * 128 * 128, u2b + l * 128, nullptr, 0,
        nullptr, S1n, S2n);
  }

  // double_mlp (norm-on-load with layer-5 stats) -> f32 x2, then decoder
  gemm2<128, 256, 1, 1, 0, 0><<<512, 256, 0, stream>>>(
      nullptr, 0, nullptr, hB, stats + (size_t)5 * 2048, stats + (size_t)5 * 2048 + 1024,
      nullptr, Wdblf, dblb, nullptr, 0, x2f, nullptr, nullptr);
  dec_conv<<<N_NODES / 32, 256, 0, stream>>>(x2f, u, c1W, c1b, c2W, c2b, outp);
}

// Round 7
// 730.709 us; speedup vs baseline: 1.4526x; 1.0796x over previous
//
#include <hip/hip_runtime.h>
#include <hip/hip_bf16.h>

#define N_NODES 32768
#define N_GRAPHS 8
#define NPG 4096
#define DEG 8
#define N_EDGES (N_NODES*DEG)
#define TW 25
#define NL 6
#define L_PDE 16.0f
#define TMAXC 4.0f
#define DTC 0.04f
#define EPSC 1e-5f

typedef __bf16 bf16x8 __attribute__((ext_vector_type(8)));
typedef float f32x4 __attribute__((ext_vector_type(4)));
typedef unsigned short u16;
typedef unsigned int u32;

__device__ __forceinline__ float bf2f(u16 h){
  union { float f; u32 u; } v; v.u = ((u32)h) << 16; return v.f;
}
__device__ __forceinline__ u16 f2bf(float f){
  union { float f; u32 u; } v; v.f = f;
  u32 r = v.u + 0x7FFFu + ((v.u >> 16) & 1u);
  return (u16)(r >> 16);
}
__device__ __forceinline__ float swishf(float x){
  return x / (1.0f + __expf(-x));
}

// ---------------------------------------------------------------------------
// Weight prep: repack W[K][N] (f32, k-major) into frag-major bf16.
// ---------------------------------------------------------------------------
__global__ void prep_std(const float* __restrict__ src, u16* __restrict__ dst,
                         int Ksrc, int KPAD, int NOUT)
{
  int l = blockIdx.y;
  int per = KPAD * NOUT;
  int i = blockIdx.x * 256 + threadIdx.x;
  if (i >= per) return;
  int KSTEPS = KPAD / 32;
  int e = i & 7;
  int lane = (i >> 3) & 63;
  int ks = (i >> 9) % KSTEPS;
  int nf = i / (KSTEPS * 512);
  int c = nf * 16 + (lane & 15);
  int k = ks * 32 + (lane >> 4) * 8 + e;
  float v = (k < Ksrc) ? src[(size_t)l * Ksrc * NOUT + (size_t)k * NOUT + c] : 0.f;
  dst[(size_t)l * per + i] = f2bf(v);
}

// AB factorization weights (see earlier rounds).
__global__ void prep_AB(const float* __restrict__ W, const float* __restrict__ bsrc,
                        u16* __restrict__ dst, float* __restrict__ bdst)
{
  int l = blockIdx.y;
  const int KSTEPS = 6;
  int i = blockIdx.x * 256 + threadIdx.x;       // < 192*256 = 49152
  int e = i & 7, lane = (i >> 3) & 63, ks = (i >> 9) % KSTEPS, nf = i / (KSTEPS * 512);
  int c = nf * 16 + (lane & 15);
  int k = ks * 32 + (lane >> 4) * 8 + e;
  const float* Wl = W + (size_t)l * 308 * 128;
  float v = 0.f;
  if (c < 128) {
    int rowi = -1;
    if (k < 128) rowi = k;
    else if (k < 178) rowi = 256 + (k - 128);
    else if (k == 178) rowi = 306;
    else if (k == 179) rowi = 307;
    if (rowi >= 0) v = Wl[rowi * 128 + c];
  } else {
    int cc = c - 128; float sgn = 1.f; int rowi = -1;
    if (k < 128) rowi = 128 + k;
    else if (k < 178) { rowi = 256 + (k - 128); sgn = -1.f; }
    else if (k == 178) { rowi = 306; sgn = -1.f; }
    if (rowi >= 0) v = sgn * Wl[rowi * 128 + cc];
  }
  dst[(size_t)l * 192 * 256 + i] = f2bf(v);
  if (i < 256) bdst[l * 256 + i] = (i < 128) ? bsrc[l * 128 + i] : 0.f;
}

// Static feature columns: X0[N][64] = [u(50), px, pt, 0..]
__global__ __launch_bounds__(256) void build_static(
    const float* __restrict__ u, const float* __restrict__ pos,
    u16* __restrict__ X0)
{
  int idx = blockIdx.x * 256 + threadIdx.x;   // N*64
  int n = idx >> 6, j = idx & 63;
  float v;
  if (j < 50) v = u[n * 50 + j];
  else if (j == 50) v = pos[n * 2 + 1] * (1.f / L_PDE);
  else if (j == 51) v = pos[n * 2 + 0] * (1.f / TMAXC);
  else v = 0.f;
  X0[n * 64 + j] = f2bf(v);
}

// ---------------------------------------------------------------------------
// Unified MFMA GEMM (used for AB and dbl). Col-split wave layout.
// SMODE: 1 = [norm(hB,statsPrev) (128) | X0 static (KPAD-128)]
// HASOUT: stage + write bf16 `out`. outF: scattered f32 copy of activation.
// ---------------------------------------------------------------------------
template<int KPAD, int NOUT, int ACT, int SMODE, int RESID, int HASOUT>
__global__ __launch_bounds__(256) void gemm2(
    const u16* __restrict__ X, int ldx,
    const u16* __restrict__ Xaux,
    float* hB,
    const float* __restrict__ S1p, const float* __restrict__ S2p,
    const float* __restrict__ pos,
    const u16* __restrict__ Wf, const float* __restrict__ bias,
    u16* __restrict__ out, int ldo,
    float* __restrict__ outF,
    float* __restrict__ S1n, float* __restrict__ S2n)
{
  constexpr int KSTEPS = KPAD / 32;
  constexpr int NF2 = NOUT / 32;
  constexpr int CHUNKS = KPAD / 8;
  constexpr int LDO_S = NOUT + 8;
  constexpr int SMEM_US = 64 * (HASOUT ? (KPAD > LDO_S ? KPAD : LDO_S) : KPAD);
  __shared__ u16 sm[SMEM_US];
  int tid = threadIdx.x, lane = tid & 63, wid = tid >> 6;
  int n0 = blockIdx.x * 64;
  int g = n0 >> 12;

  for (int c = tid; c < 64 * CHUNKS; c += 256) {
    int r = c / CHUNKS, kc = c % CHUNKS;
    int n = n0 + r;
    union { uint4 v; u16 s[8]; } o;
    if (SMODE == 0) {
      o.v = *(const uint4*)(X + (size_t)n * ldx + kc * 8);
    } else {
      if (kc < 16) {
        const float* hp = hB + (size_t)n * 128 + kc * 8;
        float4 a0 = *(const float4*)hp, a1 = *(const float4*)(hp + 4);
        float xv[8] = {a0.x,a0.y,a0.z,a0.w,a1.x,a1.y,a1.z,a1.w};
        if (S1p) {
          #pragma unroll
          for (int j = 0; j < 8; ++j) {
            int cc = kc * 8 + j;
            float m = S1p[g * 128 + cc] * (1.f / NPG);
            float var = S2p[g * 128 + cc] * (1.f / NPG) - m * m;
            xv[j] = (xv[j] - m) * rsqrtf(var + EPSC);
          }
        }
        #pragma unroll
        for (int j = 0; j < 8; ++j) o.s[j] = f2bf(xv[j]);
      } else {
        o.v = *(const uint4*)(Xaux + (size_t)n * 64 + (kc - 16) * 8);
      }
    }
    int byte = r * (KPAD * 2) + kc * 16; byte ^= ((r & 7) << 4);
    *(uint4*)((char*)sm + byte) = o.v;
  }
  __syncthreads();

  int rowHalf = wid & 1, colHalf = wid >> 1;
  f32x4 acc[2][NF2];
  f32x4 zero = {0.f, 0.f, 0.f, 0.f};
  #pragma unroll
  for (int m = 0; m < 2; ++m)
    #pragma unroll
    for (int i = 0; i < NF2; ++i) acc[m][i] = zero;
  int rowA = rowHalf * 32 + (lane & 15);
  int kb = lane >> 4;
  #pragma unroll
  for (int ks = 0; ks < KSTEPS; ++ks) {
    int ab0 = rowA * (KPAD * 2) + ks * 64 + kb * 16; ab0 ^= ((rowA & 7) << 4);
    int rA1 = rowA + 16;
    int ab1 = rA1 * (KPAD * 2) + ks * 64 + kb * 16; ab1 ^= ((rA1 & 7) << 4);
    bf16x8 a0 = *(const bf16x8*)((const char*)sm + ab0);
    bf16x8 a1 = *(const bf16x8*)((const char*)sm + ab1);
    #pragma unroll
    for (int nf2 = 0; nf2 < NF2; ++nf2) {
      bf16x8 b = *(const bf16x8*)(Wf + (((colHalf * NF2 + nf2) * KSTEPS + ks) * 64 + lane) * 8);
      acc[0][nf2] = __builtin_amdgcn_mfma_f32_16x16x32_bf16(a0, b, acc[0][nf2], 0, 0, 0);
      acc[1][nf2] = __builtin_amdgcn_mfma_f32_16x16x32_bf16(a1, b, acc[1][nf2], 0, 0, 0);
    }
  }

  if (HASOUT) __syncthreads();
  #pragma unroll
  for (int nf2 = 0; nf2 < NF2; ++nf2) {
    int col = colHalf * (NOUT / 2) + nf2 * 16 + (lane & 15);
    float bv = bias[col];
    #pragma unroll
    for (int m = 0; m < 2; ++m)
      #pragma unroll
      for (int j = 0; j < 4; ++j) {
        int r = rowHalf * 32 + m * 16 + (lane >> 4) * 4 + j;
        float v = acc[m][nf2][j] + bv;
        if (ACT == 1) v = swishf(v);
        if (HASOUT) sm[r * LDO_S + col] = f2bf(v);
        if (outF) outF[(size_t)(n0 + r) * NOUT + col] = v;
      }
  }
  if (HASOUT) {
    __syncthreads();
    for (int c = tid; c < 64 * NOUT / 8; c += 256) {
      int r = c / (NOUT / 8), kc = c % (NOUT / 8);
      uint4 v = *(const uint4*)(sm + r * LDO_S + kc * 8);
      *(uint4*)(out + (size_t)(n0 + r) * ldo + kc * 8) = v;
    }
  }
}

// ---------------------------------------------------------------------------
// Fused encoder: h = swish(swish(X0@W1+b1)@W2+b2) -> hB (f32).
// Intermediate z lives only in LDS (swizzled [64][128] bf16).
// ---------------------------------------------------------------------------
__global__ __launch_bounds__(256) void enc_fused(
    const u16* __restrict__ X0,
    const u16* __restrict__ W1f, const float* __restrict__ b1,
    const u16* __restrict__ W2f, const float* __restrict__ b2,
    float* __restrict__ hB)
{
  __shared__ u16 s1[64 * 64];
  __shared__ u16 s2[64 * 128];
  int tid = threadIdx.x, lane = tid & 63, wid = tid >> 6;
  int n0 = blockIdx.x * 64;

  for (int c = tid; c < 64 * 8; c += 256) {
    int r = c >> 3, kc = c & 7;
    uint4 v = *(const uint4*)(X0 + (size_t)(n0 + r) * 64 + kc * 8);
    int byte = r * 128 + kc * 16; byte ^= ((r & 7) << 4);
    *(uint4*)((char*)s1 + byte) = v;
  }
  __syncthreads();

  int rowHalf = wid & 1, colHalf = wid >> 1;
  int rowA = rowHalf * 32 + (lane & 15), kb = lane >> 4;
  f32x4 acc[2][4];
  f32x4 zero = {0.f, 0.f, 0.f, 0.f};
  #pragma unroll
  for (int m = 0; m < 2; ++m)
    #pragma unroll
    for (int i = 0; i < 4; ++i) acc[m][i] = zero;
  #pragma unroll
  for (int ks = 0; ks < 2; ++ks) {
    int ab0 = rowA * 128 + ks * 64 + kb * 16; ab0 ^= ((rowA & 7) << 4);
    int rA1 = rowA + 16;
    int ab1 = rA1 * 128 + ks * 64 + kb * 16; ab1 ^= ((rA1 & 7) << 4);
    bf16x8 a0 = *(const bf16x8*)((const char*)s1 + ab0);
    bf16x8 a1 = *(const bf16x8*)((const char*)s1 + ab1);
    #pragma unroll
    for (int nf2 = 0; nf2 < 4; ++nf2) {
      bf16x8 b = *(const bf16x8*)(W1f + (((colHalf * 4 + nf2) * 2 + ks) * 64 + lane) * 8);
      acc[0][nf2] = __builtin_amdgcn_mfma_f32_16x16x32_bf16(a0, b, acc[0][nf2], 0, 0, 0);
      acc[1][nf2] = __builtin_amdgcn_mfma_f32_16x16x32_bf16(a1, b, acc[1][nf2], 0, 0, 0);
    }
  }
  // z = swish(acc+b1) -> s2 (swizzled, row stride 256B)
  #pragma unroll
  for (int nf2 = 0; nf2 < 4; ++nf2) {
    int col = colHalf * 64 + nf2 * 16 + (lane & 15);
    float bv = b1[col];
    #pragma unroll
    for (int m = 0; m < 2; ++m)
      #pragma unroll
      for (int j = 0; j < 4; ++j) {
        int r = rowHalf * 32 + m * 16 + (lane >> 4) * 4 + j;
        int byte = r * 256 + col * 2; byte ^= ((r & 7) << 4);
        *(u16*)((char*)s2 + byte) = f2bf(swishf(acc[m][nf2][j] + bv));
      }
  }
  __syncthreads();
  #pragma unroll
  for (int m = 0; m < 2; ++m)
    #pragma unroll
    for (int i = 0; i < 4; ++i) acc[m][i] = zero;
  #pragma unroll
  for (int ks = 0; ks < 4; ++ks) {
    int ab0 = rowA * 256 + ks * 64 + kb * 16; ab0 ^= ((rowA & 7) << 4);
    int rA1 = rowA + 16;
    int ab1 = rA1 * 256 + ks * 64 + kb * 16; ab1 ^= ((rA1 & 7) << 4);
    bf16x8 a0 = *(const bf16x8*)((const char*)s2 + ab0);
    bf16x8 a1 = *(const bf16x8*)((const char*)s2 + ab1);
    #pragma unroll
    for (int nf2 = 0; nf2 < 4; ++nf2) {
      bf16x8 b = *(const bf16x8*)(W2f + (((colHalf * 4 + nf2) * 4 + ks) * 64 + lane) * 8);
      acc[0][nf2] = __builtin_amdgcn_mfma_f32_16x16x32_bf16(a0, b, acc[0][nf2], 0, 0, 0);
      acc[1][nf2] = __builtin_amdgcn_mfma_f32_16x16x32_bf16(a1, b, acc[1][nf2], 0, 0, 0);
    }
  }
  #pragma unroll
  for (int nf2 = 0; nf2 < 4; ++nf2) {
    int col = colHalf * 64 + nf2 * 16 + (lane & 15);
    float bv = b2[col];
    #pragma unroll
    for (int m = 0; m < 2; ++m)
      #pragma unroll
      for (int j = 0; j < 4; ++j) {
        int r = rowHalf * 32 + m * 16 + (lane >> 4) * 4 + j;
        hB[(size_t)(n0 + r) * 128 + col] = swishf(acc[m][nf2][j] + bv);
      }
  }
}

// ---------------------------------------------------------------------------
// Fused update MLP: z = swish([norm(hB)|Agg|pt] @ Wu1 + b1) (z in LDS only),
// up = swish(z @ Wu2 + b2); hn = norm(hB) + up -> hB; moment atomics.
// ---------------------------------------------------------------------------
__global__ __launch_bounds__(256) void upd_fused(
    const u16* __restrict__ Agg,
    float* hB,
    const float* __restrict__ S1p, const float* __restrict__ S2p,
    const float* __restrict__ pos,
    const u16* __restrict__ W1f, const float* __restrict__ b1,
    const u16* __restrict__ W2f, const float* __restrict__ b2,
    float* __restrict__ S1n, float* __restrict__ S2n)
{
  __shared__ u16 s1[64 * 320];    // 40KB: [norm(hB)|Agg|pt,0..] swizzled, stride 640B
  __shared__ u16 s2[64 * 128];    // 16KB: z swizzled, stride 256B
  int tid = threadIdx.x, lane = tid & 63, wid = tid >> 6;
  int n0 = blockIdx.x * 64;
  int g = n0 >> 12;

  for (int c = tid; c < 64 * 40; c += 256) {
    int r = c / 40, kc = c % 40;
    int n = n0 + r;
    union { uint4 v; u16 s[8]; } o;
    if (kc < 16) {
      const float* hp = hB + (size_t)n * 128 + kc * 8;
      float4 a0 = *(const float4*)hp, a1 = *(const float4*)(hp + 4);
      float xv[8] = {a0.x,a0.y,a0.z,a0.w,a1.x,a1.y,a1.z,a1.w};
      if (S1p) {
        #pragma unroll
        for (int j = 0; j < 8; ++j) {
          int cc = kc * 8 + j;
          float m = S1p[g * 128 + cc] * (1.f / NPG);
          float var = S2p[g * 128 + cc] * (1.f / NPG) - m * m;
          xv[j] = (xv[j] - m) * rsqrtf(var + EPSC);
        }
      }
      #pragma unroll
      for (int j = 0; j < 8; ++j) o.s[j] = f2bf(xv[j]);
    } else if (kc < 32) {
      o.v = *(const uint4*)(Agg + (size_t)n * 128 + (kc - 16) * 8);
    } else {
      #pragma unroll
      for (int j = 0; j < 8; ++j) o.s[j] = 0;
      if (kc == 32) o.s[0] = f2bf(pos[n * 2] * (1.f / TMAXC));
    }
    int byte = r * 640 + kc * 16; byte ^= ((r & 7) << 4);
    *(uint4*)((char*)s1 + byte) = o.v;
  }
  __syncthreads();

  int rowHalf = wid & 1, colHalf = wid >> 1;
  int rowA = rowHalf * 32 + (lane & 15), kb = lane >> 4;
  f32x4 acc[2][4];
  f32x4 zero = {0.f, 0.f, 0.f, 0.f};
  #pragma unroll
  for (int m = 0; m < 2; ++m)
    #pragma unroll
    for (int i = 0; i < 4; ++i) acc[m][i] = zero;
  #pragma unroll
  for (int ks = 0; ks < 10; ++ks) {
    int ab0 = rowA * 640 + ks * 64 + kb * 16; ab0 ^= ((rowA & 7) << 4);
    int rA1 = rowA + 16;
    int ab1 = rA1 * 640 + ks * 64 + kb * 16; ab1 ^= ((rA1 & 7) << 4);
    bf16x8 a0 = *(const bf16x8*)((const char*)s1 + ab0);
    bf16x8 a1 = *(const bf16x8*)((const char*)s1 + ab1);
    #pragma unroll
    for (int nf2 = 0; nf2 < 4; ++nf2) {
      bf16x8 b = *(const bf16x8*)(W1f + (((colHalf * 4 + nf2) * 10 + ks) * 64 + lane) * 8);
      acc[0][nf2] = __builtin_amdgcn_mfma_f32_16x16x32_bf16(a0, b, acc[0][nf2], 0, 0, 0);
      acc[1][nf2] = __builtin_amdgcn_mfma_f32_16x16x32_bf16(a1, b, acc[1][nf2], 0, 0, 0);
    }
  }
  // z = swish(acc+b1) -> s2
  #pragma unroll
  for (int nf2 = 0; nf2 < 4; ++nf2) {
    int col = colHalf * 64 + nf2 * 16 + (lane & 15);
    float bv = b1[col];
    #pragma unroll
    for (int m = 0; m < 2; ++m)
      #pragma unroll
      for (int j = 0; j < 4; ++j) {
        int r = rowHalf * 32 + m * 16 + (lane >> 4) * 4 + j;
        int byte = r * 256 + col * 2; byte ^= ((r & 7) << 4);
        *(u16*)((char*)s2 + byte) = f2bf(swishf(acc[m][nf2][j] + bv));
      }
  }
  __syncthreads();
  #pragma unroll
  for (int m = 0; m < 2; ++m)
    #pragma unroll
    for (int i = 0; i < 4; ++i) acc[m][i] = zero;
  #pragma unroll
  for (int ks = 0; ks < 4; ++ks) {
    int ab0 = rowA * 256 + ks * 64 + kb * 16; ab0 ^= ((rowA & 7) << 4);
    int rA1 = rowA + 16;
    int ab1 = rA1 * 256 + ks * 64 + kb * 16; ab1 ^= ((rA1 & 7) << 4);
    bf16x8 a0 = *(const bf16x8*)((const char*)s2 + ab0);
    bf16x8 a1 = *(const bf16x8*)((const char*)s2 + ab1);
    #pragma unroll
    for (int nf2 = 0; nf2 < 4; ++nf2) {
      bf16x8 b = *(const bf16x8*)(W2f + (((colHalf * 4 + nf2) * 4 + ks) * 64 + lane) * 8);
      acc[0][nf2] = __builtin_amdgcn_mfma_f32_16x16x32_bf16(a0, b, acc[0][nf2], 0, 0, 0);
      acc[1][nf2] = __builtin_amdgcn_mfma_f32_16x16x32_bf16(a1, b, acc[1][nf2], 0, 0, 0);
    }
  }
  // RESID epilogue: hn = norm(hB) + swish(acc+b2) -> hB; moments -> atomics
  float s1l[4], s2l[4];
  #pragma unroll
  for (int i = 0; i < 4; ++i) { s1l[i] = 0.f; s2l[i] = 0.f; }
  #pragma unroll
  for (int nf2 = 0; nf2 < 4; ++nf2) {
    int col = colHalf * 64 + nf2 * 16 + (lane & 15);
    float bv = b2[col];
    float mm = 0.f, rsig = 1.f;
    if (S1p) {
      mm = S1p[g * 128 + col] * (1.f / NPG);
      float var = S2p[g * 128 + col] * (1.f / NPG) - mm * mm;
      rsig = rsqrtf(var + EPSC);
    }
    #pragma unroll
    for (int m = 0; m < 2; ++m)
      #pragma unroll
      for (int j = 0; j < 4; ++j) {
        int r = rowHalf * 32 + m * 16 + (lane >> 4) * 4 + j;
        int n = n0 + r;
        float v = swishf(acc[m][nf2][j] + bv);
        float hc = hB[(size_t)n * 128 + col];
        hc = (hc - mm) * rsig;
        float hn = hc + v;
        hB[(size_t)n * 128 + col] = hn;
        s1l[nf2] += hn; s2l[nf2] += hn * hn;
      }
  }
  #pragma unroll
  for (int nf2 = 0; nf2 < 4; ++nf2) {
    float s1v = s1l[nf2], s2v = s2l[nf2];
    s1v += __shfl_xor(s1v, 16); s1v += __shfl_xor(s1v, 32);
    s2v += __shfl_xor(s2v, 16); s2v += __shfl_xor(s2v, 32);
    if ((lane >> 4) == 0) {
      int col = colHalf * 64 + nf2 * 16 + (lane & 15);
      atomicAdd(&S1n[g * 128 + col], s1v);
      atomicAdd(&S2n[g * 128 + col], s2v);
    }
  }
}

// ---------------------------------------------------------------------------
// Edge message + mean-aggregate -> Agg[n][128] bf16.
// ---------------------------------------------------------------------------
__global__ __launch_bounds__(256) void msg_kernel(
    const u16* __restrict__ AB, const int* __restrict__ srcIdx,
    const u16* __restrict__ Wf, const float* __restrict__ bm2,
    u16* __restrict__ Agg)
{
  __shared__ u16 Ms[64 * 128];
  __shared__ float aggS[8][132];
  int tid = threadIdx.x, lane = tid & 63, wid = tid >> 6;
  int e0 = blockIdx.x * 64;
  for (int c = tid; c < 1024; c += 256) {
    int i = c >> 4, kc = c & 15;
    int e = e0 + i;
    int nd = e >> 3;
    int ns = srcIdx[e];
    union { uint4 v; u16 s[8]; } va, vb, vo;
    va.v = *(const uint4*)(AB + (size_t)nd * 256 + kc * 8);
    vb.v = *(const uint4*)(AB + (size_t)ns * 256 + 128 + kc * 8);
    #pragma unroll
    for (int j = 0; j < 8; ++j) vo.s[j] = f2bf(swishf(bf2f(va.s[j]) + bf2f(vb.s[j])));
    int byte = i * 256 + kc * 16; byte ^= ((i & 7) << 4);
    *(uint4*)((char*)Ms + byte) = vo.v;
  }
  __syncthreads();
  int rowHalf = wid & 1, colHalf = wid >> 1;
  f32x4 acc[2][4];
  f32x4 zero = {0.f, 0.f, 0.f, 0.f};
  #pragma unroll
  for (int m = 0; m < 2; ++m)
    #pragma unroll
    for (int i = 0; i < 4; ++i) acc[m][i] = zero;
  int rowA = rowHalf * 32 + (lane & 15), kb = lane >> 4;
  #pragma unroll
  for (int ks = 0; ks < 4; ++ks) {
    int ab0 = rowA * 256 + ks * 64 + kb * 16; ab0 ^= ((rowA & 7) << 4);
    int rA1 = rowA + 16;
    int ab1 = rA1 * 256 + ks * 64 + kb * 16; ab1 ^= ((rA1 & 7) << 4);
    bf16x8 a0 = *(const bf16x8*)((const char*)Ms + ab0);
    bf16x8 a1 = *(const bf16x8*)((const char*)Ms + ab1);
    #pragma unroll
    for (int nf2 = 0; nf2 < 4; ++nf2) {
      bf16x8 b = *(const bf16x8*)(Wf + (((colHalf * 4 + nf2) * 4 + ks) * 64 + lane) * 8);
      acc[0][nf2] = __builtin_amdgcn_mfma_f32_16x16x32_bf16(a0, b, acc[0][nf2], 0, 0, 0);
      acc[1][nf2] = __builtin_amdgcn_mfma_f32_16x16x32_bf16(a1, b, acc[1][nf2], 0, 0, 0);
    }
  }
  #pragma unroll
  for (int m = 0; m < 2; ++m)
    #pragma unroll
    for (int nf2 = 0; nf2 < 4; ++nf2) {
      int col = colHalf * 64 + nf2 * 16 + (lane & 15);
      float bv = bm2[col];
      float s = 0.f;
      #pragma unroll
      for (int j = 0; j < 4; ++j) s += swishf(acc[m][nf2][j] + bv);
      s += __shfl_xor(s, 16);
      if ((lane & 31) < 16)
        aggS[rowHalf * 4 + m * 2 + (lane >> 5)][col] = s * 0.125f;
    }
  __syncthreads();
  {
    int node = tid >> 5;
    int c0 = (tid & 31) * 4;
    int n = (e0 >> 3) + node;
    ushort4 o;
    o.x = f2bf(aggS[node][c0 + 0]);
    o.y = f2bf(aggS[node][c0 + 1]);
    o.z = f2bf(aggS[node][c0 + 2]);
    o.w = f2bf(aggS[node][c0 + 3]);
    *(ushort4*)(Agg + (size_t)n * 128 + c0) = o;
  }
}

// ---------------------------------------------------------------------------
// Decoder: stage x2 rows ONCE into LDS (f32, [32][260] -> conflict-free
// broadcast reads), then scatter-conv1 + butterfly conv2. 8 threads/node.
// ---------------------------------------------------------------------------
__global__ __launch_bounds__(256) void dec_conv(
    const float* __restrict__ x2f, const float* __restrict__ u,
    const float* __restrict__ w1, const float* __restrict__ b1,
    const float* __restrict__ w2, const float* __restrict__ b2,
    float* __restrict__ outp)
{
  __shared__ float xs[32 * 260];
  int tid = threadIdx.x;
  int o = tid & 7;
  int nn = tid >> 3;
  int n0 = blockIdx.x * 32;
  int n = n0 + nn;

  for (int i = tid; i < 32 * 64; i += 256) {
    int r = i >> 6, c = i & 63;
    float4 v = *(const float4*)(x2f + (size_t)(n0 + r) * 256 + c * 4);
    *(float4*)(xs + r * 260 + c * 4) = v;
  }
  __syncthreads();

  float b1v = b1[o];
  float y[38];
  #pragma unroll
  for (int t = 0; t < 38; ++t) y[t] = b1v;

  #pragma unroll
  for (int cc = 0; cc < 2; ++cc) {
    float w1r[16];
    {
      const float4* wp = (const float4*)(w1 + o * 32 + cc * 16);
      #pragma unroll
      for (int i = 0; i < 4; ++i) {
        float4 v = wp[i];
        w1r[i*4+0]=v.x; w1r[i*4+1]=v.y; w1r[i*4+2]=v.z; w1r[i*4+3]=v.w;
      }
    }
    const float4* xp = (const float4*)(xs + nn * 260 + cc * 128);
    #pragma unroll
    for (int ch = 0; ch < 32; ++ch) {
      float4 xv = xp[ch];
      float xe[4] = {xv.x, xv.y, xv.z, xv.w};
      #pragma unroll
      for (int e = 0; e < 4; ++e) {
        const int j = ch * 4 + e;
        #pragma unroll
        for (int k = 0; k < 16; ++k) {
          const int tm = j - k;
          if (tm >= 0 && (tm % 3) == 0 && (tm / 3) < 38)
            y[tm / 3] += xe[e] * w1r[k];
        }
      }
    }
  }
  #pragma unroll
  for (int t = 0; t < 38; ++t) y[t] = swishf(y[t]);

  float w2r[28];
  #pragma unroll
  for (int c = 0; c < 2; ++c)
    #pragma unroll
    for (int k = 0; k < 14; ++k)
      w2r[c*14 + k] = w2[(c*8 + o)*14 + k];
  float b2r0 = b2[0], b2r1 = b2[1];

  #pragma unroll
  for (int i = 0; i < 50; ++i) {
    const int c = i / 25, t = i % 25;
    float p = 0.f;
    #pragma unroll
    for (int k = 0; k < 14; ++k) p += y[t + k] * w2r[c*14 + k];
    p += __shfl_xor(p, 1);
    p += __shfl_xor(p, 2);
    p += __shfl_xor(p, 4);
    if (o == (i & 7)) {
      int gi = n * 50 + i;
      float diff = p + (c ? b2r1 : b2r0);
      outp[gi] = u[gi] + (DTC * (t + 1)) * diff;
    }
  }
}

extern "C" void kernel_launch(void* const* d_in, const int* in_sizes, int n_in,
                              void* d_out, int out_size, void* d_ws, size_t ws_size,
                              hipStream_t stream) {
  const float* u     = (const float*)d_in[0];
  const float* pos   = (const float*)d_in[1];
  const int*   eidx  = (const int*)d_in[2];
  const float* embW1 = (const float*)d_in[4];
  const float* embb1 = (const float*)d_in[5];
  const float* embW2 = (const float*)d_in[6];
  const float* embb2 = (const float*)d_in[7];
  const float* m1W   = (const float*)d_in[8];
  const float* m1b   = (const float*)d_in[9];
  const float* m2W   = (const float*)d_in[10];
  const float* m2b   = (const float*)d_in[11];
  const float* u1W   = (const float*)d_in[12];
  const float* u1b   = (const float*)d_in[13];
  const float* u2W   = (const float*)d_in[14];
  const float* u2b   = (const float*)d_in[15];
  const float* dblW  = (const float*)d_in[16];
  const float* dblb  = (const float*)d_in[17];
  const float* c1W   = (const float*)d_in[18];
  const float* c1b   = (const float*)d_in[19];
  const float* c2W   = (const float*)d_in[20];
  const float* c2b   = (const float*)d_in[21];
  float* outp = (float*)d_out;
  const int* srcI = eidx;   // edge_index[0] = src; dst(e) = e>>3 by construction

  char* ws = (char*)d_ws;
  size_t off = 0;
  auto alloc = [&](size_t bytes) -> char* {
    char* p = ws + off; off += (bytes + 255) & ~(size_t)255; return p;
  };
  u16* X0    = (u16*)alloc((size_t)N_NODES * 64 * 2);
  u16* ABbuf = (u16*)alloc((size_t)N_NODES * 256 * 2);
  u16* Agg   = (u16*)alloc((size_t)N_NODES * 128 * 2);
  float* hB  = (float*)alloc((size_t)N_NODES * 128 * 4);
  float* x2f = (float*)alloc((size_t)N_NODES * 256 * 4);
  float* stats = (float*)alloc((size_t)NL * 2 * 1024 * 4);
  u16* WembF1 = (u16*)alloc(64 * 128 * 2);
  u16* WembF2 = (u16*)alloc(128 * 128 * 2);
  u16* WABf   = (u16*)alloc((size_t)6 * 192 * 256 * 2);
  float* bABf = (float*)alloc(6 * 256 * 4);
  u16* Wm2f   = (u16*)alloc((size_t)6 * 128 * 128 * 2);
  u16* Wu1f   = (u16*)alloc((size_t)6 * 320 * 128 * 2);
  u16* Wu2f   = (u16*)alloc((size_t)6 * 128 * 128 * 2);
  u16* Wdblf  = (u16*)alloc((size_t)128 * 256 * 2);

  hipMemsetAsync(stats, 0, (size_t)NL * 2 * 1024 * 4, stream);

  prep_std<<<dim3(32, 1), 256, 0, stream>>>(embW1, WembF1, 52, 64, 128);
  prep_std<<<dim3(64, 1), 256, 0, stream>>>(embW2, WembF2, 128, 128, 128);
  prep_std<<<dim3(64, 6), 256, 0, stream>>>(m2W, Wm2f, 128, 128, 128);
  prep_std<<<dim3(160, 6), 256, 0, stream>>>(u1W, Wu1f, 257, 320, 128);
  prep_std<<<dim3(64, 6), 256, 0, stream>>>(u2W, Wu2f, 128, 128, 128);
  prep_std<<<dim3(128, 1), 256, 0, stream>>>(dblW, Wdblf, 128, 128, 256);
  prep_AB<<<dim3(192, 6), 256, 0, stream>>>(m1W, m1b, WABf, bABf);
  build_static<<<N_NODES * 64 / 256, 256, 0, stream>>>(u, pos, X0);

  // fused encoder: X0 -> hB
  enc_fused<<<512, 256, 0, stream>>>(X0, WembF1, embb1, WembF2, embb2, hB);

  for (int l = 0; l < NL; ++l) {
    const float* S1p = l ? stats + (size_t)(l - 1) * 2048 : nullptr;
    const float* S2p = l ? stats + (size_t)(l - 1) * 2048 + 1024 : nullptr;
    float* S1n = stats + (size_t)l * 2048;
    float* S2n = S1n + 1024;
    gemm2<192, 256, 0, 1, 0, 1><<<512, 256, 0, stream>>>(
        nullptr, 0, X0, hB, S1p, S2p, nullptr,
        WABf + (size_t)l * 192 * 256, bABf + l * 256, ABbuf, 256,
        nullptr, nullptr, nullptr);
    msg_kernel<<<N_EDGES / 64, 256, 0, stream>>>(
        ABbuf, srcI, Wm2f + (size_t)l * 128 * 128, m2b + l * 128, Agg);
    upd_fused<<<512, 256, 0, stream>>>(
        Agg, hB, S1p, S2p, pos,
        Wu1f + (size_t)l * 320 * 128, u1b + l * 128,
        Wu2f + (size_t)l * 128 * 128, u2b + l * 128,
        S1n, S2n);
  }

  // double_mlp (norm-on-load with layer-5 stats) -> f32 x2, then decoder
  gemm2<128, 256, 1, 1, 0, 0><<<512, 256, 0, stream>>>(
      nullptr, 0, nullptr, hB, stats + (size_t)5 * 2048, stats + (size_t)5 * 2048 + 1024,
      nullptr, Wdblf, dblb, nullptr, 0, x2f, nullptr, nullptr);
  dec_conv<<<N_NODES / 32, 256, 0, stream>>>(x2f, u, c1W, c1b, c2W, c2b, outp);
}

// Round 8
// 710.956 us; speedup vs baseline: 1.4929x; 1.0278x over previous
//
#include <hip/hip_runtime.h>
#include <hip/hip_bf16.h>

#define N_NODES 32768
#define N_GRAPHS 8
#define NPG 4096
#define DEG 8
#define N_EDGES (N_NODES*DEG)
#define TW 25
#define NL 6
#define L_PDE 16.0f
#define TMAXC 4.0f
#define DTC 0.04f
#define EPSC 1e-5f

typedef __bf16 bf16x8 __attribute__((ext_vector_type(8)));
typedef float f32x4 __attribute__((ext_vector_type(4)));
typedef unsigned short u16;
typedef unsigned int u32;

__device__ __forceinline__ float bf2f(u16 h){
  union { float f; u32 u; } v; v.u = ((u32)h) << 16; return v.f;
}
__device__ __forceinline__ u16 f2bf(float f){
  union { float f; u32 u; } v; v.f = f;
  u32 r = v.u + 0x7FFFu + ((v.u >> 16) & 1u);
  return (u16)(r >> 16);
}
__device__ __forceinline__ float swishf(float x){
  return x / (1.0f + __expf(-x));
}

// ---------------------------------------------------------------------------
// Weight prep: repack W[K][N] (f32, k-major) into frag-major bf16.
// ---------------------------------------------------------------------------
__global__ void prep_std(const float* __restrict__ src, u16* __restrict__ dst,
                         int Ksrc, int KPAD, int NOUT)
{
  int l = blockIdx.y;
  int per = KPAD * NOUT;
  int i = blockIdx.x * 256 + threadIdx.x;
  if (i >= per) return;
  int KSTEPS = KPAD / 32;
  int e = i & 7;
  int lane = (i >> 3) & 63;
  int ks = (i >> 9) % KSTEPS;
  int nf = i / (KSTEPS * 512);
  int c = nf * 16 + (lane & 15);
  int k = ks * 32 + (lane >> 4) * 8 + e;
  float v = (k < Ksrc) ? src[(size_t)l * Ksrc * NOUT + (size_t)k * NOUT + c] : 0.f;
  dst[(size_t)l * per + i] = f2bf(v);
}

// AB factorization weights (see earlier rounds).
__global__ void prep_AB(const float* __restrict__ W, const float* __restrict__ bsrc,
                        u16* __restrict__ dst, float* __restrict__ bdst)
{
  int l = blockIdx.y;
  const int KSTEPS = 6;
  int i = blockIdx.x * 256 + threadIdx.x;       // < 192*256 = 49152
  int e = i & 7, lane = (i >> 3) & 63, ks = (i >> 9) % KSTEPS, nf = i / (KSTEPS * 512);
  int c = nf * 16 + (lane & 15);
  int k = ks * 32 + (lane >> 4) * 8 + e;
  const float* Wl = W + (size_t)l * 308 * 128;
  float v = 0.f;
  if (c < 128) {
    int rowi = -1;
    if (k < 128) rowi = k;
    else if (k < 178) rowi = 256 + (k - 128);
    else if (k == 178) rowi = 306;
    else if (k == 179) rowi = 307;
    if (rowi >= 0) v = Wl[rowi * 128 + c];
  } else {
    int cc = c - 128; float sgn = 1.f; int rowi = -1;
    if (k < 128) rowi = 128 + k;
    else if (k < 178) { rowi = 256 + (k - 128); sgn = -1.f; }
    else if (k == 178) { rowi = 306; sgn = -1.f; }
    if (rowi >= 0) v = sgn * Wl[rowi * 128 + cc];
  }
  dst[(size_t)l * 192 * 256 + i] = f2bf(v);
  if (i < 256) bdst[l * 256 + i] = (i < 128) ? bsrc[l * 128 + i] : 0.f;
}

// Static feature columns: X0[N][64] = [u(50), px, pt, 0..]
__global__ __launch_bounds__(256) void build_static(
    const float* __restrict__ u, const float* __restrict__ pos,
    u16* __restrict__ X0)
{
  int idx = blockIdx.x * 256 + threadIdx.x;   // N*64
  int n = idx >> 6, j = idx & 63;
  float v;
  if (j < 50) v = u[n * 50 + j];
  else if (j == 50) v = pos[n * 2 + 1] * (1.f / L_PDE);
  else if (j == 51) v = pos[n * 2 + 0] * (1.f / TMAXC);
  else v = 0.f;
  X0[n * 64 + j] = f2bf(v);
}

// ---------------------------------------------------------------------------
// Unified MFMA GEMM (used for AB and dbl). Col-split wave layout.
// SMODE: 1 = [norm(hB,statsPrev) (128) | X0 static (KPAD-128)]
// HASOUT: stage + write bf16 `out`. outF: scattered f32 copy of activation.
// ---------------------------------------------------------------------------
template<int KPAD, int NOUT, int ACT, int SMODE, int RESID, int HASOUT>
__global__ __launch_bounds__(256) void gemm2(
    const u16* __restrict__ X, int ldx,
    const u16* __restrict__ Xaux,
    float* hB,
    const float* __restrict__ S1p, const float* __restrict__ S2p,
    const float* __restrict__ pos,
    const u16* __restrict__ Wf, const float* __restrict__ bias,
    u16* __restrict__ out, int ldo,
    float* __restrict__ outF,
    float* __restrict__ S1n, float* __restrict__ S2n)
{
  constexpr int KSTEPS = KPAD / 32;
  constexpr int NF2 = NOUT / 32;
  constexpr int CHUNKS = KPAD / 8;
  constexpr int LDO_S = NOUT + 8;
  constexpr int SMEM_US = 64 * (HASOUT ? (KPAD > LDO_S ? KPAD : LDO_S) : KPAD);
  __shared__ u16 sm[SMEM_US];
  int tid = threadIdx.x, lane = tid & 63, wid = tid >> 6;
  int n0 = blockIdx.x * 64;
  int g = n0 >> 12;

  for (int c = tid; c < 64 * CHUNKS; c += 256) {
    int r = c / CHUNKS, kc = c % CHUNKS;
    int n = n0 + r;
    union { uint4 v; u16 s[8]; } o;
    if (SMODE == 0) {
      o.v = *(const uint4*)(X + (size_t)n * ldx + kc * 8);
    } else {
      if (kc < 16) {
        const float* hp = hB + (size_t)n * 128 + kc * 8;
        float4 a0 = *(const float4*)hp, a1 = *(const float4*)(hp + 4);
        float xv[8] = {a0.x,a0.y,a0.z,a0.w,a1.x,a1.y,a1.z,a1.w};
        if (S1p) {
          #pragma unroll
          for (int j = 0; j < 8; ++j) {
            int cc = kc * 8 + j;
            float m = S1p[g * 128 + cc] * (1.f / NPG);
            float var = S2p[g * 128 + cc] * (1.f / NPG) - m * m;
            xv[j] = (xv[j] - m) * rsqrtf(var + EPSC);
          }
        }
        #pragma unroll
        for (int j = 0; j < 8; ++j) o.s[j] = f2bf(xv[j]);
      } else {
        o.v = *(const uint4*)(Xaux + (size_t)n * 64 + (kc - 16) * 8);
      }
    }
    int byte = r * (KPAD * 2) + kc * 16; byte ^= ((r & 7) << 4);
    *(uint4*)((char*)sm + byte) = o.v;
  }
  __syncthreads();

  int rowHalf = wid & 1, colHalf = wid >> 1;
  f32x4 acc[2][NF2];
  f32x4 zero = {0.f, 0.f, 0.f, 0.f};
  #pragma unroll
  for (int m = 0; m < 2; ++m)
    #pragma unroll
    for (int i = 0; i < NF2; ++i) acc[m][i] = zero;
  int rowA = rowHalf * 32 + (lane & 15);
  int kb = lane >> 4;
  #pragma unroll
  for (int ks = 0; ks < KSTEPS; ++ks) {
    int ab0 = rowA * (KPAD * 2) + ks * 64 + kb * 16; ab0 ^= ((rowA & 7) << 4);
    int rA1 = rowA + 16;
    int ab1 = rA1 * (KPAD * 2) + ks * 64 + kb * 16; ab1 ^= ((rA1 & 7) << 4);
    bf16x8 a0 = *(const bf16x8*)((const char*)sm + ab0);
    bf16x8 a1 = *(const bf16x8*)((const char*)sm + ab1);
    #pragma unroll
    for (int nf2 = 0; nf2 < NF2; ++nf2) {
      bf16x8 b = *(const bf16x8*)(Wf + (((colHalf * NF2 + nf2) * KSTEPS + ks) * 64 + lane) * 8);
      acc[0][nf2] = __builtin_amdgcn_mfma_f32_16x16x32_bf16(a0, b, acc[0][nf2], 0, 0, 0);
      acc[1][nf2] = __builtin_amdgcn_mfma_f32_16x16x32_bf16(a1, b, acc[1][nf2], 0, 0, 0);
    }
  }

  if (HASOUT) __syncthreads();
  #pragma unroll
  for (int nf2 = 0; nf2 < NF2; ++nf2) {
    int col = colHalf * (NOUT / 2) + nf2 * 16 + (lane & 15);
    float bv = bias[col];
    #pragma unroll
    for (int m = 0; m < 2; ++m)
      #pragma unroll
      for (int j = 0; j < 4; ++j) {
        int r = rowHalf * 32 + m * 16 + (lane >> 4) * 4 + j;
        float v = acc[m][nf2][j] + bv;
        if (ACT == 1) v = swishf(v);
        if (HASOUT) sm[r * LDO_S + col] = f2bf(v);
        if (outF) outF[(size_t)(n0 + r) * NOUT + col] = v;
      }
  }
  if (HASOUT) {
    __syncthreads();
    for (int c = tid; c < 64 * NOUT / 8; c += 256) {
      int r = c / (NOUT / 8), kc = c % (NOUT / 8);
      uint4 v = *(const uint4*)(sm + r * LDO_S + kc * 8);
      *(uint4*)(out + (size_t)(n0 + r) * ldo + kc * 8) = v;
    }
  }
}

// ---------------------------------------------------------------------------
// Fused encoder: h = swish(swish(X0@W1+b1)@W2+b2) -> hB (f32).
// ---------------------------------------------------------------------------
__global__ __launch_bounds__(256) void enc_fused(
    const u16* __restrict__ X0,
    const u16* __restrict__ W1f, const float* __restrict__ b1,
    const u16* __restrict__ W2f, const float* __restrict__ b2,
    float* __restrict__ hB)
{
  __shared__ u16 s1[64 * 64];
  __shared__ u16 s2[64 * 128];
  int tid = threadIdx.x, lane = tid & 63, wid = tid >> 6;
  int n0 = blockIdx.x * 64;

  for (int c = tid; c < 64 * 8; c += 256) {
    int r = c >> 3, kc = c & 7;
    uint4 v = *(const uint4*)(X0 + (size_t)(n0 + r) * 64 + kc * 8);
    int byte = r * 128 + kc * 16; byte ^= ((r & 7) << 4);
    *(uint4*)((char*)s1 + byte) = v;
  }
  __syncthreads();

  int rowHalf = wid & 1, colHalf = wid >> 1;
  int rowA = rowHalf * 32 + (lane & 15), kb = lane >> 4;
  f32x4 acc[2][4];
  f32x4 zero = {0.f, 0.f, 0.f, 0.f};
  #pragma unroll
  for (int m = 0; m < 2; ++m)
    #pragma unroll
    for (int i = 0; i < 4; ++i) acc[m][i] = zero;
  #pragma unroll
  for (int ks = 0; ks < 2; ++ks) {
    int ab0 = rowA * 128 + ks * 64 + kb * 16; ab0 ^= ((rowA & 7) << 4);
    int rA1 = rowA + 16;
    int ab1 = rA1 * 128 + ks * 64 + kb * 16; ab1 ^= ((rA1 & 7) << 4);
    bf16x8 a0 = *(const bf16x8*)((const char*)s1 + ab0);
    bf16x8 a1 = *(const bf16x8*)((const char*)s1 + ab1);
    #pragma unroll
    for (int nf2 = 0; nf2 < 4; ++nf2) {
      bf16x8 b = *(const bf16x8*)(W1f + (((colHalf * 4 + nf2) * 2 + ks) * 64 + lane) * 8);
      acc[0][nf2] = __builtin_amdgcn_mfma_f32_16x16x32_bf16(a0, b, acc[0][nf2], 0, 0, 0);
      acc[1][nf2] = __builtin_amdgcn_mfma_f32_16x16x32_bf16(a1, b, acc[1][nf2], 0, 0, 0);
    }
  }
  #pragma unroll
  for (int nf2 = 0; nf2 < 4; ++nf2) {
    int col = colHalf * 64 + nf2 * 16 + (lane & 15);
    float bv = b1[col];
    #pragma unroll
    for (int m = 0; m < 2; ++m)
      #pragma unroll
      for (int j = 0; j < 4; ++j) {
        int r = rowHalf * 32 + m * 16 + (lane >> 4) * 4 + j;
        int byte = r * 256 + col * 2; byte ^= ((r & 7) << 4);
        *(u16*)((char*)s2 + byte) = f2bf(swishf(acc[m][nf2][j] + bv));
      }
  }
  __syncthreads();
  #pragma unroll
  for (int m = 0; m < 2; ++m)
    #pragma unroll
    for (int i = 0; i < 4; ++i) acc[m][i] = zero;
  #pragma unroll
  for (int ks = 0; ks < 4; ++ks) {
    int ab0 = rowA * 256 + ks * 64 + kb * 16; ab0 ^= ((rowA & 7) << 4);
    int rA1 = rowA + 16;
    int ab1 = rA1 * 256 + ks * 64 + kb * 16; ab1 ^= ((rA1 & 7) << 4);
    bf16x8 a0 = *(const bf16x8*)((const char*)s2 + ab0);
    bf16x8 a1 = *(const bf16x8*)((const char*)s2 + ab1);
    #pragma unroll
    for (int nf2 = 0; nf2 < 4; ++nf2) {
      bf16x8 b = *(const bf16x8*)(W2f + (((colHalf * 4 + nf2) * 4 + ks) * 64 + lane) * 8);
      acc[0][nf2] = __builtin_amdgcn_mfma_f32_16x16x32_bf16(a0, b, acc[0][nf2], 0, 0, 0);
      acc[1][nf2] = __builtin_amdgcn_mfma_f32_16x16x32_bf16(a1, b, acc[1][nf2], 0, 0, 0);
    }
  }
  #pragma unroll
  for (int nf2 = 0; nf2 < 4; ++nf2) {
    int col = colHalf * 64 + nf2 * 16 + (lane & 15);
    float bv = b2[col];
    #pragma unroll
    for (int m = 0; m < 2; ++m)
      #pragma unroll
      for (int j = 0; j < 4; ++j) {
        int r = rowHalf * 32 + m * 16 + (lane >> 4) * 4 + j;
        hB[(size_t)(n0 + r) * 128 + col] = swishf(acc[m][nf2][j] + bv);
      }
  }
}

// ---------------------------------------------------------------------------
// Fused update MLP: z = swish([norm(hB)|Agg|pt] @ Wu1 + b1) (z in LDS only),
// up = swish(z @ Wu2 + b2); hn = norm(hB) + up -> hB; moment atomics.
// ---------------------------------------------------------------------------
__global__ __launch_bounds__(256) void upd_fused(
    const u16* __restrict__ Agg,
    float* hB,
    const float* __restrict__ S1p, const float* __restrict__ S2p,
    const float* __restrict__ pos,
    const u16* __restrict__ W1f, const float* __restrict__ b1,
    const u16* __restrict__ W2f, const float* __restrict__ b2,
    float* __restrict__ S1n, float* __restrict__ S2n)
{
  __shared__ u16 s1[64 * 320];
  __shared__ u16 s2[64 * 128];
  int tid = threadIdx.x, lane = tid & 63, wid = tid >> 6;
  int n0 = blockIdx.x * 64;
  int g = n0 >> 12;

  for (int c = tid; c < 64 * 40; c += 256) {
    int r = c / 40, kc = c % 40;
    int n = n0 + r;
    union { uint4 v; u16 s[8]; } o;
    if (kc < 16) {
      const float* hp = hB + (size_t)n * 128 + kc * 8;
      float4 a0 = *(const float4*)hp, a1 = *(const float4*)(hp + 4);
      float xv[8] = {a0.x,a0.y,a0.z,a0.w,a1.x,a1.y,a1.z,a1.w};
      if (S1p) {
        #pragma unroll
        for (int j = 0; j < 8; ++j) {
          int cc = kc * 8 + j;
          float m = S1p[g * 128 + cc] * (1.f / NPG);
          float var = S2p[g * 128 + cc] * (1.f / NPG) - m * m;
          xv[j] = (xv[j] - m) * rsqrtf(var + EPSC);
        }
      }
      #pragma unroll
      for (int j = 0; j < 8; ++j) o.s[j] = f2bf(xv[j]);
    } else if (kc < 32) {
      o.v = *(const uint4*)(Agg + (size_t)n * 128 + (kc - 16) * 8);
    } else {
      #pragma unroll
      for (int j = 0; j < 8; ++j) o.s[j] = 0;
      if (kc == 32) o.s[0] = f2bf(pos[n * 2] * (1.f / TMAXC));
    }
    int byte = r * 640 + kc * 16; byte ^= ((r & 7) << 4);
    *(uint4*)((char*)s1 + byte) = o.v;
  }
  __syncthreads();

  int rowHalf = wid & 1, colHalf = wid >> 1;
  int rowA = rowHalf * 32 + (lane & 15), kb = lane >> 4;
  f32x4 acc[2][4];
  f32x4 zero = {0.f, 0.f, 0.f, 0.f};
  #pragma unroll
  for (int m = 0; m < 2; ++m)
    #pragma unroll
    for (int i = 0; i < 4; ++i) acc[m][i] = zero;
  #pragma unroll
  for (int ks = 0; ks < 10; ++ks) {
    int ab0 = rowA * 640 + ks * 64 + kb * 16; ab0 ^= ((rowA & 7) << 4);
    int rA1 = rowA + 16;
    int ab1 = rA1 * 640 + ks * 64 + kb * 16; ab1 ^= ((rA1 & 7) << 4);
    bf16x8 a0 = *(const bf16x8*)((const char*)s1 + ab0);
    bf16x8 a1 = *(const bf16x8*)((const char*)s1 + ab1);
    #pragma unroll
    for (int nf2 = 0; nf2 < 4; ++nf2) {
      bf16x8 b = *(const bf16x8*)(W1f + (((colHalf * 4 + nf2) * 10 + ks) * 64 + lane) * 8);
      acc[0][nf2] = __builtin_amdgcn_mfma_f32_16x16x32_bf16(a0, b, acc[0][nf2], 0, 0, 0);
      acc[1][nf2] = __builtin_amdgcn_mfma_f32_16x16x32_bf16(a1, b, acc[1][nf2], 0, 0, 0);
    }
  }
  #pragma unroll
  for (int nf2 = 0; nf2 < 4; ++nf2) {
    int col = colHalf * 64 + nf2 * 16 + (lane & 15);
    float bv = b1[col];
    #pragma unroll
    for (int m = 0; m < 2; ++m)
      #pragma unroll
      for (int j = 0; j < 4; ++j) {
        int r = rowHalf * 32 + m * 16 + (lane >> 4) * 4 + j;
        int byte = r * 256 + col * 2; byte ^= ((r & 7) << 4);
        *(u16*)((char*)s2 + byte) = f2bf(swishf(acc[m][nf2][j] + bv));
      }
  }
  __syncthreads();
  #pragma unroll
  for (int m = 0; m < 2; ++m)
    #pragma unroll
    for (int i = 0; i < 4; ++i) acc[m][i] = zero;
  #pragma unroll
  for (int ks = 0; ks < 4; ++ks) {
    int ab0 = rowA * 256 + ks * 64 + kb * 16; ab0 ^= ((rowA & 7) << 4);
    int rA1 = rowA + 16;
    int ab1 = rA1 * 256 + ks * 64 + kb * 16; ab1 ^= ((rA1 & 7) << 4);
    bf16x8 a0 = *(const bf16x8*)((const char*)s2 + ab0);
    bf16x8 a1 = *(const bf16x8*)((const char*)s2 + ab1);
    #pragma unroll
    for (int nf2 = 0; nf2 < 4; ++nf2) {
      bf16x8 b = *(const bf16x8*)(W2f + (((colHalf * 4 + nf2) * 4 + ks) * 64 + lane) * 8);
      acc[0][nf2] = __builtin_amdgcn_mfma_f32_16x16x32_bf16(a0, b, acc[0][nf2], 0, 0, 0);
      acc[1][nf2] = __builtin_amdgcn_mfma_f32_16x16x32_bf16(a1, b, acc[1][nf2], 0, 0, 0);
    }
  }
  float s1l[4], s2l[4];
  #pragma unroll
  for (int i = 0; i < 4; ++i) { s1l[i] = 0.f; s2l[i] = 0.f; }
  #pragma unroll
  for (int nf2 = 0; nf2 < 4; ++nf2) {
    int col = colHalf * 64 + nf2 * 16 + (lane & 15);
    float bv = b2[col];
    float mm = 0.f, rsig = 1.f;
    if (S1p) {
      mm = S1p[g * 128 + col] * (1.f / NPG);
      float var = S2p[g * 128 + col] * (1.f / NPG) - mm * mm;
      rsig = rsqrtf(var + EPSC);
    }
    #pragma unroll
    for (int m = 0; m < 2; ++m)
      #pragma unroll
      for (int j = 0; j < 4; ++j) {
        int r = rowHalf * 32 + m * 16 + (lane >> 4) * 4 + j;
        int n = n0 + r;
        float v = swishf(acc[m][nf2][j] + bv);
        float hc = hB[(size_t)n * 128 + col];
        hc = (hc - mm) * rsig;
        float hn = hc + v;
        hB[(size_t)n * 128 + col] = hn;
        s1l[nf2] += hn; s2l[nf2] += hn * hn;
      }
  }
  #pragma unroll
  for (int nf2 = 0; nf2 < 4; ++nf2) {
    float s1v = s1l[nf2], s2v = s2l[nf2];
    s1v += __shfl_xor(s1v, 16); s1v += __shfl_xor(s1v, 32);
    s2v += __shfl_xor(s2v, 16); s2v += __shfl_xor(s2v, 32);
    if ((lane >> 4) == 0) {
      int col = colHalf * 64 + nf2 * 16 + (lane & 15);
      atomicAdd(&S1n[g * 128 + col], s1v);
      atomicAdd(&S2n[g * 128 + col], s2v);
    }
  }
}

// ---------------------------------------------------------------------------
// Edge message + mean-aggregate -> Agg[n][128] bf16.
// ---------------------------------------------------------------------------
__global__ __launch_bounds__(256) void msg_kernel(
    const u16* __restrict__ AB, const int* __restrict__ srcIdx,
    const u16* __restrict__ Wf, const float* __restrict__ bm2,
    u16* __restrict__ Agg)
{
  __shared__ u16 Ms[64 * 128];
  __shared__ float aggS[8][132];
  int tid = threadIdx.x, lane = tid & 63, wid = tid >> 6;
  int e0 = blockIdx.x * 64;
  for (int c = tid; c < 1024; c += 256) {
    int i = c >> 4, kc = c & 15;
    int e = e0 + i;
    int nd = e >> 3;
    int ns = srcIdx[e];
    union { uint4 v; u16 s[8]; } va, vb, vo;
    va.v = *(const uint4*)(AB + (size_t)nd * 256 + kc * 8);
    vb.v = *(const uint4*)(AB + (size_t)ns * 256 + 128 + kc * 8);
    #pragma unroll
    for (int j = 0; j < 8; ++j) vo.s[j] = f2bf(swishf(bf2f(va.s[j]) + bf2f(vb.s[j])));
    int byte = i * 256 + kc * 16; byte ^= ((i & 7) << 4);
    *(uint4*)((char*)Ms + byte) = vo.v;
  }
  __syncthreads();
  int rowHalf = wid & 1, colHalf = wid >> 1;
  f32x4 acc[2][4];
  f32x4 zero = {0.f, 0.f, 0.f, 0.f};
  #pragma unroll
  for (int m = 0; m < 2; ++m)
    #pragma unroll
    for (int i = 0; i < 4; ++i) acc[m][i] = zero;
  int rowA = rowHalf * 32 + (lane & 15), kb = lane >> 4;
  #pragma unroll
  for (int ks = 0; ks < 4; ++ks) {
    int ab0 = rowA * 256 + ks * 64 + kb * 16; ab0 ^= ((rowA & 7) << 4);
    int rA1 = rowA + 16;
    int ab1 = rA1 * 256 + ks * 64 + kb * 16; ab1 ^= ((rA1 & 7) << 4);
    bf16x8 a0 = *(const bf16x8*)((const char*)Ms + ab0);
    bf16x8 a1 = *(const bf16x8*)((const char*)Ms + ab1);
    #pragma unroll
    for (int nf2 = 0; nf2 < 4; ++nf2) {
      bf16x8 b = *(const bf16x8*)(Wf + (((colHalf * 4 + nf2) * 4 + ks) * 64 + lane) * 8);
      acc[0][nf2] = __builtin_amdgcn_mfma_f32_16x16x32_bf16(a0, b, acc[0][nf2], 0, 0, 0);
      acc[1][nf2] = __builtin_amdgcn_mfma_f32_16x16x32_bf16(a1, b, acc[1][nf2], 0, 0, 0);
    }
  }
  #pragma unroll
  for (int m = 0; m < 2; ++m)
    #pragma unroll
    for (int nf2 = 0; nf2 < 4; ++nf2) {
      int col = colHalf * 64 + nf2 * 16 + (lane & 15);
      float bv = bm2[col];
      float s = 0.f;
      #pragma unroll
      for (int j = 0; j < 4; ++j) s += swishf(acc[m][nf2][j] + bv);
      s += __shfl_xor(s, 16);
      if ((lane & 31) < 16)
        aggS[rowHalf * 4 + m * 2 + (lane >> 5)][col] = s * 0.125f;
    }
  __syncthreads();
  {
    int node = tid >> 5;
    int c0 = (tid & 31) * 4;
    int n = (e0 >> 3) + node;
    ushort4 o;
    o.x = f2bf(aggS[node][c0 + 0]);
    o.y = f2bf(aggS[node][c0 + 1]);
    o.z = f2bf(aggS[node][c0 + 2]);
    o.w = f2bf(aggS[node][c0 + 3]);
    *(ushort4*)(Agg + (size_t)n * 128 + c0) = o;
  }
}

// ---------------------------------------------------------------------------
// Decoder, compact-code version: 16 nodes/block, 16 threads/node.
// conv1: thread=(n,o,th), rolled 19-iter t-loop, 32-FMA body; y -> LDS.
// conv2: thread=(n,c,ts), rolled t-loop (t = ts, ts+8, ...), 112-FMA body.
// Small code footprint (no giant unroll) to avoid i-fetch-bound execution.
// ---------------------------------------------------------------------------
__global__ __launch_bounds__(256) void dec_conv(
    const float* __restrict__ x2f, const float* __restrict__ u,
    const float* __restrict__ w1, const float* __restrict__ b1,
    const float* __restrict__ w2, const float* __restrict__ b2,
    float* __restrict__ outp)
{
  __shared__ float xs[16][260];
  __shared__ float ys[16][8][41];
  __shared__ float w1s[256], w2s[224];
  int tid = threadIdx.x;
  int n0 = blockIdx.x * 16;

  w1s[tid] = w1[tid];
  if (tid < 224) w2s[tid] = w2[tid];
  for (int i = tid; i < 16 * 64; i += 256) {
    int r = i >> 6, c = i & 63;
    *(float4*)(&xs[r][c * 4]) = *(const float4*)(x2f + (size_t)(n0 + r) * 256 + c * 4);
  }
  __syncthreads();

  {
    int n = tid >> 4;
    int o = (tid >> 1) & 7;
    int th = tid & 1;              // t in [19*th, 19*th+19)
    float b1v = b1[o];
    float wA[16], wB[16];
    #pragma unroll
    for (int k = 0; k < 16; ++k) { wA[k] = w1s[o * 32 + k]; wB[k] = w1s[o * 32 + 16 + k]; }
    int tEnd = th * 19 + 19;
    for (int t = th * 19; t < tEnd; ++t) {
      float acc = b1v;
      const float* xa = &xs[n][3 * t];
      const float* xb = &xs[n][128 + 3 * t];
      #pragma unroll
      for (int k = 0; k < 16; ++k) acc += xa[k] * wA[k] + xb[k] * wB[k];
      ys[n][o][t] = swishf(acc);
    }
  }
  __syncthreads();

  {
    int n = tid >> 4;
    int c = (tid >> 3) & 1;
    int ts = tid & 7;
    float b2v = b2[c];
    for (int t = ts; t < 25; t += 8) {
      float acc = b2v;
      #pragma unroll
      for (int ic = 0; ic < 8; ++ic) {
        const float* yp = &ys[n][ic][t];
        const float* wp = &w2s[c * 112 + ic * 14];
        #pragma unroll
        for (int k = 0; k < 14; ++k) acc += yp[k] * wp[k];
      }
      int gi = (n0 + n) * 50 + c * 25 + t;
      outp[gi] = u[gi] + (DTC * (t + 1)) * acc;
    }
  }
}

extern "C" void kernel_launch(void* const* d_in, const int* in_sizes, int n_in,
                              void* d_out, int out_size, void* d_ws, size_t ws_size,
                              hipStream_t stream) {
  const float* u     = (const float*)d_in[0];
  const float* pos   = (const float*)d_in[1];
  const int*   eidx  = (const int*)d_in[2];
  const float* embW1 = (const float*)d_in[4];
  const float* embb1 = (const float*)d_in[5];
  const float* embW2 = (const float*)d_in[6];
  const float* embb2 = (const float*)d_in[7];
  const float* m1W   = (const float*)d_in[8];
  const float* m1b   = (const float*)d_in[9];
  const float* m2W   = (const float*)d_in[10];
  const float* m2b   = (const float*)d_in[11];
  const float* u1W   = (const float*)d_in[12];
  const float* u1b   = (const float*)d_in[13];
  const float* u2W   = (const float*)d_in[14];
  const float* u2b   = (const float*)d_in[15];
  const float* dblW  = (const float*)d_in[16];
  const float* dblb  = (const float*)d_in[17];
  const float* c1W   = (const float*)d_in[18];
  const float* c1b   = (const float*)d_in[19];
  const float* c2W   = (const float*)d_in[20];
  const float* c2b   = (const float*)d_in[21];
  float* outp = (float*)d_out;
  const int* srcI = eidx;   // edge_index[0] = src; dst(e) = e>>3 by construction

  char* ws = (char*)d_ws;
  size_t off = 0;
  auto alloc = [&](size_t bytes) -> char* {
    char* p = ws + off; off += (bytes + 255) & ~(size_t)255; return p;
  };
  u16* X0    = (u16*)alloc((size_t)N_NODES * 64 * 2);
  u16* ABbuf = (u16*)alloc((size_t)N_NODES * 256 * 2);
  u16* Agg   = (u16*)alloc((size_t)N_NODES * 128 * 2);
  float* hB  = (float*)alloc((size_t)N_NODES * 128 * 4);
  float* x2f = (float*)alloc((size_t)N_NODES * 256 * 4);
  float* stats = (float*)alloc((size_t)NL * 2 * 1024 * 4);
  u16* WembF1 = (u16*)alloc(64 * 128 * 2);
  u16* WembF2 = (u16*)alloc(128 * 128 * 2);
  u16* WABf   = (u16*)alloc((size_t)6 * 192 * 256 * 2);
  float* bABf = (float*)alloc(6 * 256 * 4);
  u16* Wm2f   = (u16*)alloc((size_t)6 * 128 * 128 * 2);
  u16* Wu1f   = (u16*)alloc((size_t)6 * 320 * 128 * 2);
  u16* Wu2f   = (u16*)alloc((size_t)6 * 128 * 128 * 2);
  u16* Wdblf  = (u16*)alloc((size_t)128 * 256 * 2);

  hipMemsetAsync(stats, 0, (size_t)NL * 2 * 1024 * 4, stream);

  prep_std<<<dim3(32, 1), 256, 0, stream>>>(embW1, WembF1, 52, 64, 128);
  prep_std<<<dim3(64, 1), 256, 0, stream>>>(embW2, WembF2, 128, 128, 128);
  prep_std<<<dim3(64, 6), 256, 0, stream>>>(m2W, Wm2f, 128, 128, 128);
  prep_std<<<dim3(160, 6), 256, 0, stream>>>(u1W, Wu1f, 257, 320, 128);
  prep_std<<<dim3(64, 6), 256, 0, stream>>>(u2W, Wu2f, 128, 128, 128);
  prep_std<<<dim3(128, 1), 256, 0, stream>>>(dblW, Wdblf, 128, 128, 256);
  prep_AB<<<dim3(192, 6), 256, 0, stream>>>(m1W, m1b, WABf, bABf);
  build_static<<<N_NODES * 64 / 256, 256, 0, stream>>>(u, pos, X0);

  enc_fused<<<512, 256, 0, stream>>>(X0, WembF1, embb1, WembF2, embb2, hB);

  for (int l = 0; l < NL; ++l) {
    const float* S1p = l ? stats + (size_t)(l - 1) * 2048 : nullptr;
    const float* S2p = l ? stats + (size_t)(l - 1) * 2048 + 1024 : nullptr;
    float* S1n = stats + (size_t)l * 2048;
    float* S2n = S1n + 1024;
    gemm2<192, 256, 0, 1, 0, 1><<<512, 256, 0, stream>>>(
        nullptr, 0, X0, hB, S1p, S2p, nullptr,
        WABf + (size_t)l * 192 * 256, bABf + l * 256, ABbuf, 256,
        nullptr, nullptr, nullptr);
    msg_kernel<<<N_EDGES / 64, 256, 0, stream>>>(
        ABbuf, srcI, Wm2f + (size_t)l * 128 * 128, m2b + l * 128, Agg);
    upd_fused<<<512, 256, 0, stream>>>(
        Agg, hB, S1p, S2p, pos,
        Wu1f + (size_t)l * 320 * 128, u1b + l * 128,
        Wu2f + (size_t)l * 128 * 128, u2b + l * 128,
        S1n, S2n);
  }

  gemm2<128, 256, 1, 1, 0, 0><<<512, 256, 0, stream>>>(
      nullptr, 0, nullptr, hB, stats + (size_t)5 * 2048, stats + (size_t)5 * 2048 + 1024,
      nullptr, Wdblf, dblb, nullptr, 0, x2f, nullptr, nullptr);
  dec_conv<<<N_NODES / 16, 256, 0, stream>>>(x2f, u, c1W, c1b, c2W, c2b, outp);
}

// Round 9
// 614.641 us; speedup vs baseline: 1.7269x; 1.1567x over previous
//
#include <hip/hip_runtime.h>
#include <hip/hip_bf16.h>

#define N_NODES 32768
#define N_GRAPHS 8
#define NPG 4096
#define DEG 8
#define N_EDGES (N_NODES*DEG)
#define TW 25
#define NL 6
#define L_PDE 16.0f
#define TMAXC 4.0f
#define DTC 0.04f
#define EPSC 1e-5f

typedef __bf16 bf16x8 __attribute__((ext_vector_type(8)));
typedef float f32x4 __attribute__((ext_vector_type(4)));
typedef unsigned short u16;
typedef unsigned int u32;

__device__ __forceinline__ float bf2f(u16 h){
  union { float f; u32 u; } v; v.u = ((u32)h) << 16; return v.f;
}
__device__ __forceinline__ u16 f2bf(float f){
  union { float f; u32 u; } v; v.f = f;
  u32 r = v.u + 0x7FFFu + ((v.u >> 16) & 1u);
  return (u16)(r >> 16);
}
// swish via v_rcp_f32 (~1ulp) instead of IEEE divide (~12 VALU ops -> ~5).
__device__ __forceinline__ float swishf(float x){
  return x * __builtin_amdgcn_rcpf(1.0f + __expf(-x));
}

// ---------------------------------------------------------------------------
// Weight prep: repack W[K][N] (f32, k-major) into frag-major bf16.
// ---------------------------------------------------------------------------
__global__ void prep_std(const float* __restrict__ src, u16* __restrict__ dst,
                         int Ksrc, int KPAD, int NOUT)
{
  int l = blockIdx.y;
  int per = KPAD * NOUT;
  int i = blockIdx.x * 256 + threadIdx.x;
  if (i >= per) return;
  int KSTEPS = KPAD / 32;
  int e = i & 7;
  int lane = (i >> 3) & 63;
  int ks = (i >> 9) % KSTEPS;
  int nf = i / (KSTEPS * 512);
  int c = nf * 16 + (lane & 15);
  int k = ks * 32 + (lane >> 4) * 8 + e;
  float v = (k < Ksrc) ? src[(size_t)l * Ksrc * NOUT + (size_t)k * NOUT + c] : 0.f;
  dst[(size_t)l * per + i] = f2bf(v);
}

// AB factorization weights (see earlier rounds).
__global__ void prep_AB(const float* __restrict__ W, const float* __restrict__ bsrc,
                        u16* __restrict__ dst, float* __restrict__ bdst)
{
  int l = blockIdx.y;
  const int KSTEPS = 6;
  int i = blockIdx.x * 256 + threadIdx.x;       // < 192*256 = 49152
  int e = i & 7, lane = (i >> 3) & 63, ks = (i >> 9) % KSTEPS, nf = i / (KSTEPS * 512);
  int c = nf * 16 + (lane & 15);
  int k = ks * 32 + (lane >> 4) * 8 + e;
  const float* Wl = W + (size_t)l * 308 * 128;
  float v = 0.f;
  if (c < 128) {
    int rowi = -1;
    if (k < 128) rowi = k;
    else if (k < 178) rowi = 256 + (k - 128);
    else if (k == 178) rowi = 306;
    else if (k == 179) rowi = 307;
    if (rowi >= 0) v = Wl[rowi * 128 + c];
  } else {
    int cc = c - 128; float sgn = 1.f; int rowi = -1;
    if (k < 128) rowi = 128 + k;
    else if (k < 178) { rowi = 256 + (k - 128); sgn = -1.f; }
    else if (k == 178) { rowi = 306; sgn = -1.f; }
    if (rowi >= 0) v = sgn * Wl[rowi * 128 + cc];
  }
  dst[(size_t)l * 192 * 256 + i] = f2bf(v);
  if (i < 256) bdst[l * 256 + i] = (i < 128) ? bsrc[l * 128 + i] : 0.f;
}

// Static feature columns: X0[N][64] = [u(50), px, pt, 0..]
__global__ __launch_bounds__(256) void build_static(
    const float* __restrict__ u, const float* __restrict__ pos,
    u16* __restrict__ X0)
{
  int idx = blockIdx.x * 256 + threadIdx.x;   // N*64
  int n = idx >> 6, j = idx & 63;
  float v;
  if (j < 50) v = u[n * 50 + j];
  else if (j == 50) v = pos[n * 2 + 1] * (1.f / L_PDE);
  else if (j == 51) v = pos[n * 2 + 0] * (1.f / TMAXC);
  else v = 0.f;
  X0[n * 64 + j] = f2bf(v);
}

// ---------------------------------------------------------------------------
// Unified MFMA GEMM (used for AB and dbl). Col-split wave layout.
// SMODE: 1 = [norm(hB,statsPrev) (128) | X0 static (KPAD-128)]
// HASOUT: stage + write bf16 `out`. outF: scattered f32 copy of activation.
// ---------------------------------------------------------------------------
template<int KPAD, int NOUT, int ACT, int SMODE, int RESID, int HASOUT>
__global__ __launch_bounds__(256) void gemm2(
    const u16* __restrict__ X, int ldx,
    const u16* __restrict__ Xaux,
    float* hB,
    const float* __restrict__ S1p, const float* __restrict__ S2p,
    const float* __restrict__ pos,
    const u16* __restrict__ Wf, const float* __restrict__ bias,
    u16* __restrict__ out, int ldo,
    float* __restrict__ outF,
    float* __restrict__ S1n, float* __restrict__ S2n)
{
  constexpr int KSTEPS = KPAD / 32;
  constexpr int NF2 = NOUT / 32;
  constexpr int CHUNKS = KPAD / 8;
  constexpr int LDO_S = NOUT + 8;
  constexpr int SMEM_US = 64 * (HASOUT ? (KPAD > LDO_S ? KPAD : LDO_S) : KPAD);
  __shared__ u16 sm[SMEM_US];
  int tid = threadIdx.x, lane = tid & 63, wid = tid >> 6;
  int n0 = blockIdx.x * 64;
  int g = n0 >> 12;

  for (int c = tid; c < 64 * CHUNKS; c += 256) {
    int r = c / CHUNKS, kc = c % CHUNKS;
    int n = n0 + r;
    union { uint4 v; u16 s[8]; } o;
    if (SMODE == 0) {
      o.v = *(const uint4*)(X + (size_t)n * ldx + kc * 8);
    } else {
      if (kc < 16) {
        const float* hp = hB + (size_t)n * 128 + kc * 8;
        float4 a0 = *(const float4*)hp, a1 = *(const float4*)(hp + 4);
        float xv[8] = {a0.x,a0.y,a0.z,a0.w,a1.x,a1.y,a1.z,a1.w};
        if (S1p) {
          #pragma unroll
          for (int j = 0; j < 8; ++j) {
            int cc = kc * 8 + j;
            float m = S1p[g * 128 + cc] * (1.f / NPG);
            float var = S2p[g * 128 + cc] * (1.f / NPG) - m * m;
            xv[j] = (xv[j] - m) * rsqrtf(var + EPSC);
          }
        }
        #pragma unroll
        for (int j = 0; j < 8; ++j) o.s[j] = f2bf(xv[j]);
      } else {
        o.v = *(const uint4*)(Xaux + (size_t)n * 64 + (kc - 16) * 8);
      }
    }
    int byte = r * (KPAD * 2) + kc * 16; byte ^= ((r & 7) << 4);
    *(uint4*)((char*)sm + byte) = o.v;
  }
  __syncthreads();

  int rowHalf = wid & 1, colHalf = wid >> 1;
  f32x4 acc[2][NF2];
  f32x4 zero = {0.f, 0.f, 0.f, 0.f};
  #pragma unroll
  for (int m = 0; m < 2; ++m)
    #pragma unroll
    for (int i = 0; i < NF2; ++i) acc[m][i] = zero;
  int rowA = rowHalf * 32 + (lane & 15);
  int kb = lane >> 4;
  #pragma unroll
  for (int ks = 0; ks < KSTEPS; ++ks) {
    int ab0 = rowA * (KPAD * 2) + ks * 64 + kb * 16; ab0 ^= ((rowA & 7) << 4);
    int rA1 = rowA + 16;
    int ab1 = rA1 * (KPAD * 2) + ks * 64 + kb * 16; ab1 ^= ((rA1 & 7) << 4);
    bf16x8 a0 = *(const bf16x8*)((const char*)sm + ab0);
    bf16x8 a1 = *(const bf16x8*)((const char*)sm + ab1);
    #pragma unroll
    for (int nf2 = 0; nf2 < NF2; ++nf2) {
      bf16x8 b = *(const bf16x8*)(Wf + (((colHalf * NF2 + nf2) * KSTEPS + ks) * 64 + lane) * 8);
      acc[0][nf2] = __builtin_amdgcn_mfma_f32_16x16x32_bf16(a0, b, acc[0][nf2], 0, 0, 0);
      acc[1][nf2] = __builtin_amdgcn_mfma_f32_16x16x32_bf16(a1, b, acc[1][nf2], 0, 0, 0);
    }
  }

  if (HASOUT) __syncthreads();
  #pragma unroll
  for (int nf2 = 0; nf2 < NF2; ++nf2) {
    int col = colHalf * (NOUT / 2) + nf2 * 16 + (lane & 15);
    float bv = bias[col];
    #pragma unroll
    for (int m = 0; m < 2; ++m)
      #pragma unroll
      for (int j = 0; j < 4; ++j) {
        int r = rowHalf * 32 + m * 16 + (lane >> 4) * 4 + j;
        float v = acc[m][nf2][j] + bv;
        if (ACT == 1) v = swishf(v);
        if (HASOUT) sm[r * LDO_S + col] = f2bf(v);
        if (outF) outF[(size_t)(n0 + r) * NOUT + col] = v;
      }
  }
  if (HASOUT) {
    __syncthreads();
    for (int c = tid; c < 64 * NOUT / 8; c += 256) {
      int r = c / (NOUT / 8), kc = c % (NOUT / 8);
      uint4 v = *(const uint4*)(sm + r * LDO_S + kc * 8);
      *(uint4*)(out + (size_t)(n0 + r) * ldo + kc * 8) = v;
    }
  }
}

// ---------------------------------------------------------------------------
// Fused encoder: h = swish(swish(X0@W1+b1)@W2+b2) -> hB (f32).
// ---------------------------------------------------------------------------
__global__ __launch_bounds__(256) void enc_fused(
    const u16* __restrict__ X0,
    const u16* __restrict__ W1f, const float* __restrict__ b1,
    const u16* __restrict__ W2f, const float* __restrict__ b2,
    float* __restrict__ hB)
{
  __shared__ u16 s1[64 * 64];
  __shared__ u16 s2[64 * 128];
  int tid = threadIdx.x, lane = tid & 63, wid = tid >> 6;
  int n0 = blockIdx.x * 64;

  for (int c = tid; c < 64 * 8; c += 256) {
    int r = c >> 3, kc = c & 7;
    uint4 v = *(const uint4*)(X0 + (size_t)(n0 + r) * 64 + kc * 8);
    int byte = r * 128 + kc * 16; byte ^= ((r & 7) << 4);
    *(uint4*)((char*)s1 + byte) = v;
  }
  __syncthreads();

  int rowHalf = wid & 1, colHalf = wid >> 1;
  int rowA = rowHalf * 32 + (lane & 15), kb = lane >> 4;
  f32x4 acc[2][4];
  f32x4 zero = {0.f, 0.f, 0.f, 0.f};
  #pragma unroll
  for (int m = 0; m < 2; ++m)
    #pragma unroll
    for (int i = 0; i < 4; ++i) acc[m][i] = zero;
  #pragma unroll
  for (int ks = 0; ks < 2; ++ks) {
    int ab0 = rowA * 128 + ks * 64 + kb * 16; ab0 ^= ((rowA & 7) << 4);
    int rA1 = rowA + 16;
    int ab1 = rA1 * 128 + ks * 64 + kb * 16; ab1 ^= ((rA1 & 7) << 4);
    bf16x8 a0 = *(const bf16x8*)((const char*)s1 + ab0);
    bf16x8 a1 = *(const bf16x8*)((const char*)s1 + ab1);
    #pragma unroll
    for (int nf2 = 0; nf2 < 4; ++nf2) {
      bf16x8 b = *(const bf16x8*)(W1f + (((colHalf * 4 + nf2) * 2 + ks) * 64 + lane) * 8);
      acc[0][nf2] = __builtin_amdgcn_mfma_f32_16x16x32_bf16(a0, b, acc[0][nf2], 0, 0, 0);
      acc[1][nf2] = __builtin_amdgcn_mfma_f32_16x16x32_bf16(a1, b, acc[1][nf2], 0, 0, 0);
    }
  }
  #pragma unroll
  for (int nf2 = 0; nf2 < 4; ++nf2) {
    int col = colHalf * 64 + nf2 * 16 + (lane & 15);
    float bv = b1[col];
    #pragma unroll
    for (int m = 0; m < 2; ++m)
      #pragma unroll
      for (int j = 0; j < 4; ++j) {
        int r = rowHalf * 32 + m * 16 + (lane >> 4) * 4 + j;
        int byte = r * 256 + col * 2; byte ^= ((r & 7) << 4);
        *(u16*)((char*)s2 + byte) = f2bf(swishf(acc[m][nf2][j] + bv));
      }
  }
  __syncthreads();
  #pragma unroll
  for (int m = 0; m < 2; ++m)
    #pragma unroll
    for (int i = 0; i < 4; ++i) acc[m][i] = zero;
  #pragma unroll
  for (int ks = 0; ks < 4; ++ks) {
    int ab0 = rowA * 256 + ks * 64 + kb * 16; ab0 ^= ((rowA & 7) << 4);
    int rA1 = rowA + 16;
    int ab1 = rA1 * 256 + ks * 64 + kb * 16; ab1 ^= ((rA1 & 7) << 4);
    bf16x8 a0 = *(const bf16x8*)((const char*)s2 + ab0);
    bf16x8 a1 = *(const bf16x8*)((const char*)s2 + ab1);
    #pragma unroll
    for (int nf2 = 0; nf2 < 4; ++nf2) {
      bf16x8 b = *(const bf16x8*)(W2f + (((colHalf * 4 + nf2) * 4 + ks) * 64 + lane) * 8);
      acc[0][nf2] = __builtin_amdgcn_mfma_f32_16x16x32_bf16(a0, b, acc[0][nf2], 0, 0, 0);
      acc[1][nf2] = __builtin_amdgcn_mfma_f32_16x16x32_bf16(a1, b, acc[1][nf2], 0, 0, 0);
    }
  }
  #pragma unroll
  for (int nf2 = 0; nf2 < 4; ++nf2) {
    int col = colHalf * 64 + nf2 * 16 + (lane & 15);
    float bv = b2[col];
    #pragma unroll
    for (int m = 0; m < 2; ++m)
      #pragma unroll
      for (int j = 0; j < 4; ++j) {
        int r = rowHalf * 32 + m * 16 + (lane >> 4) * 4 + j;
        hB[(size_t)(n0 + r) * 128 + col] = swishf(acc[m][nf2][j] + bv);
      }
  }
}

// ---------------------------------------------------------------------------
// Fused update MLP: z = swish([norm(hB)|Agg|pt] @ Wu1 + b1) (z in LDS only),
// up = swish(z @ Wu2 + b2); hn = norm(hB) + up -> hB; moment atomics.
// ---------------------------------------------------------------------------
__global__ __launch_bounds__(256) void upd_fused(
    const u16* __restrict__ Agg,
    float* hB,
    const float* __restrict__ S1p, const float* __restrict__ S2p,
    const float* __restrict__ pos,
    const u16* __restrict__ W1f, const float* __restrict__ b1,
    const u16* __restrict__ W2f, const float* __restrict__ b2,
    float* __restrict__ S1n, float* __restrict__ S2n)
{
  __shared__ u16 s1[64 * 320];
  __shared__ u16 s2[64 * 128];
  int tid = threadIdx.x, lane = tid & 63, wid = tid >> 6;
  int n0 = blockIdx.x * 64;
  int g = n0 >> 12;

  for (int c = tid; c < 64 * 40; c += 256) {
    int r = c / 40, kc = c % 40;
    int n = n0 + r;
    union { uint4 v; u16 s[8]; } o;
    if (kc < 16) {
      const float* hp = hB + (size_t)n * 128 + kc * 8;
      float4 a0 = *(const float4*)hp, a1 = *(const float4*)(hp + 4);
      float xv[8] = {a0.x,a0.y,a0.z,a0.w,a1.x,a1.y,a1.z,a1.w};
      if (S1p) {
        #pragma unroll
        for (int j = 0; j < 8; ++j) {
          int cc = kc * 8 + j;
          float m = S1p[g * 128 + cc] * (1.f / NPG);
          float var = S2p[g * 128 + cc] * (1.f / NPG) - m * m;
          xv[j] = (xv[j] - m) * rsqrtf(var + EPSC);
        }
      }
      #pragma unroll
      for (int j = 0; j < 8; ++j) o.s[j] = f2bf(xv[j]);
    } else if (kc < 32) {
      o.v = *(const uint4*)(Agg + (size_t)n * 128 + (kc - 16) * 8);
    } else {
      #pragma unroll
      for (int j = 0; j < 8; ++j) o.s[j] = 0;
      if (kc == 32) o.s[0] = f2bf(pos[n * 2] * (1.f / TMAXC));
    }
    int byte = r * 640 + kc * 16; byte ^= ((r & 7) << 4);
    *(uint4*)((char*)s1 + byte) = o.v;
  }
  __syncthreads();

  int rowHalf = wid & 1, colHalf = wid >> 1;
  int rowA = rowHalf * 32 + (lane & 15), kb = lane >> 4;
  f32x4 acc[2][4];
  f32x4 zero = {0.f, 0.f, 0.f, 0.f};
  #pragma unroll
  for (int m = 0; m < 2; ++m)
    #pragma unroll
    for (int i = 0; i < 4; ++i) acc[m][i] = zero;
  #pragma unroll
  for (int ks = 0; ks < 10; ++ks) {
    int ab0 = rowA * 640 + ks * 64 + kb * 16; ab0 ^= ((rowA & 7) << 4);
    int rA1 = rowA + 16;
    int ab1 = rA1 * 640 + ks * 64 + kb * 16; ab1 ^= ((rA1 & 7) << 4);
    bf16x8 a0 = *(const bf16x8*)((const char*)s1 + ab0);
    bf16x8 a1 = *(const bf16x8*)((const char*)s1 + ab1);
    #pragma unroll
    for (int nf2 = 0; nf2 < 4; ++nf2) {
      bf16x8 b = *(const bf16x8*)(W1f + (((colHalf * 4 + nf2) * 10 + ks) * 64 + lane) * 8);
      acc[0][nf2] = __builtin_amdgcn_mfma_f32_16x16x32_bf16(a0, b, acc[0][nf2], 0, 0, 0);
      acc[1][nf2] = __builtin_amdgcn_mfma_f32_16x16x32_bf16(a1, b, acc[1][nf2], 0, 0, 0);
    }
  }
  #pragma unroll
  for (int nf2 = 0; nf2 < 4; ++nf2) {
    int col = colHalf * 64 + nf2 * 16 + (lane & 15);
    float bv = b1[col];
    #pragma unroll
    for (int m = 0; m < 2; ++m)
      #pragma unroll
      for (int j = 0; j < 4; ++j) {
        int r = rowHalf * 32 + m * 16 + (lane >> 4) * 4 + j;
        int byte = r * 256 + col * 2; byte ^= ((r & 7) << 4);
        *(u16*)((char*)s2 + byte) = f2bf(swishf(acc[m][nf2][j] + bv));
      }
  }
  __syncthreads();
  #pragma unroll
  for (int m = 0; m < 2; ++m)
    #pragma unroll
    for (int i = 0; i < 4; ++i) acc[m][i] = zero;
  #pragma unroll
  for (int ks = 0; ks < 4; ++ks) {
    int ab0 = rowA * 256 + ks * 64 + kb * 16; ab0 ^= ((rowA & 7) << 4);
    int rA1 = rowA + 16;
    int ab1 = rA1 * 256 + ks * 64 + kb * 16; ab1 ^= ((rA1 & 7) << 4);
    bf16x8 a0 = *(const bf16x8*)((const char*)s2 + ab0);
    bf16x8 a1 = *(const bf16x8*)((const char*)s2 + ab1);
    #pragma unroll
    for (int nf2 = 0; nf2 < 4; ++nf2) {
      bf16x8 b = *(const bf16x8*)(W2f + (((colHalf * 4 + nf2) * 4 + ks) * 64 + lane) * 8);
      acc[0][nf2] = __builtin_amdgcn_mfma_f32_16x16x32_bf16(a0, b, acc[0][nf2], 0, 0, 0);
      acc[1][nf2] = __builtin_amdgcn_mfma_f32_16x16x32_bf16(a1, b, acc[1][nf2], 0, 0, 0);
    }
  }
  float s1l[4], s2l[4];
  #pragma unroll
  for (int i = 0; i < 4; ++i) { s1l[i] = 0.f; s2l[i] = 0.f; }
  #pragma unroll
  for (int nf2 = 0; nf2 < 4; ++nf2) {
    int col = colHalf * 64 + nf2 * 16 + (lane & 15);
    float bv = b2[col];
    float mm = 0.f, rsig = 1.f;
    if (S1p) {
      mm = S1p[g * 128 + col] * (1.f / NPG);
      float var = S2p[g * 128 + col] * (1.f / NPG) - mm * mm;
      rsig = rsqrtf(var + EPSC);
    }
    #pragma unroll
    for (int m = 0; m < 2; ++m)
      #pragma unroll
      for (int j = 0; j < 4; ++j) {
        int r = rowHalf * 32 + m * 16 + (lane >> 4) * 4 + j;
        int n = n0 + r;
        float v = swishf(acc[m][nf2][j] + bv);
        float hc = hB[(size_t)n * 128 + col];
        hc = (hc - mm) * rsig;
        float hn = hc + v;
        hB[(size_t)n * 128 + col] = hn;
        s1l[nf2] += hn; s2l[nf2] += hn * hn;
      }
  }
  #pragma unroll
  for (int nf2 = 0; nf2 < 4; ++nf2) {
    float s1v = s1l[nf2], s2v = s2l[nf2];
    s1v += __shfl_xor(s1v, 16); s1v += __shfl_xor(s1v, 32);
    s2v += __shfl_xor(s2v, 16); s2v += __shfl_xor(s2v, 32);
    if ((lane >> 4) == 0) {
      int col = colHalf * 64 + nf2 * 16 + (lane & 15);
      atomicAdd(&S1n[g * 128 + col], s1v);
      atomicAdd(&S2n[g * 128 + col], s2v);
    }
  }
}

// ---------------------------------------------------------------------------
// Edge message + mean-aggregate -> Agg[n][128] bf16.
// ---------------------------------------------------------------------------
__global__ __launch_bounds__(256) void msg_kernel(
    const u16* __restrict__ AB, const int* __restrict__ srcIdx,
    const u16* __restrict__ Wf, const float* __restrict__ bm2,
    u16* __restrict__ Agg)
{
  __shared__ u16 Ms[64 * 128];
  __shared__ float aggS[8][132];
  int tid = threadIdx.x, lane = tid & 63, wid = tid >> 6;
  int e0 = blockIdx.x * 64;
  for (int c = tid; c < 1024; c += 256) {
    int i = c >> 4, kc = c & 15;
    int e = e0 + i;
    int nd = e >> 3;
    int ns = srcIdx[e];
    union { uint4 v; u16 s[8]; } va, vb, vo;
    va.v = *(const uint4*)(AB + (size_t)nd * 256 + kc * 8);
    vb.v = *(const uint4*)(AB + (size_t)ns * 256 + 128 + kc * 8);
    #pragma unroll
    for (int j = 0; j < 8; ++j) vo.s[j] = f2bf(swishf(bf2f(va.s[j]) + bf2f(vb.s[j])));
    int byte = i * 256 + kc * 16; byte ^= ((i & 7) << 4);
    *(uint4*)((char*)Ms + byte) = vo.v;
  }
  __syncthreads();
  int rowHalf = wid & 1, colHalf = wid >> 1;
  f32x4 acc[2][4];
  f32x4 zero = {0.f, 0.f, 0.f, 0.f};
  #pragma unroll
  for (int m = 0; m < 2; ++m)
    #pragma unroll
    for (int i = 0; i < 4; ++i) acc[m][i] = zero;
  int rowA = rowHalf * 32 + (lane & 15), kb = lane >> 4;
  #pragma unroll
  for (int ks = 0; ks < 4; ++ks) {
    int ab0 = rowA * 256 + ks * 64 + kb * 16; ab0 ^= ((rowA & 7) << 4);
    int rA1 = rowA + 16;
    int ab1 = rA1 * 256 + ks * 64 + kb * 16; ab1 ^= ((rA1 & 7) << 4);
    bf16x8 a0 = *(const bf16x8*)((const char*)Ms + ab0);
    bf16x8 a1 = *(const bf16x8*)((const char*)Ms + ab1);
    #pragma unroll
    for (int nf2 = 0; nf2 < 4; ++nf2) {
      bf16x8 b = *(const bf16x8*)(Wf + (((colHalf * 4 + nf2) * 4 + ks) * 64 + lane) * 8);
      acc[0][nf2] = __builtin_amdgcn_mfma_f32_16x16x32_bf16(a0, b, acc[0][nf2], 0, 0, 0);
      acc[1][nf2] = __builtin_amdgcn_mfma_f32_16x16x32_bf16(a1, b, acc[1][nf2], 0, 0, 0);
    }
  }
  #pragma unroll
  for (int m = 0; m < 2; ++m)
    #pragma unroll
    for (int nf2 = 0; nf2 < 4; ++nf2) {
      int col = colHalf * 64 + nf2 * 16 + (lane & 15);
      float bv = bm2[col];
      float s = 0.f;
      #pragma unroll
      for (int j = 0; j < 4; ++j) s += swishf(acc[m][nf2][j] + bv);
      s += __shfl_xor(s, 16);
      if ((lane & 31) < 16)
        aggS[rowHalf * 4 + m * 2 + (lane >> 5)][col] = s * 0.125f;
    }
  __syncthreads();
  {
    int node = tid >> 5;
    int c0 = (tid & 31) * 4;
    int n = (e0 >> 3) + node;
    ushort4 o;
    o.x = f2bf(aggS[node][c0 + 0]);
    o.y = f2bf(aggS[node][c0 + 1]);
    o.z = f2bf(aggS[node][c0 + 2]);
    o.w = f2bf(aggS[node][c0 + 3]);
    *(ushort4*)(Agg + (size_t)n * 128 + c0) = o;
  }
}

// ---------------------------------------------------------------------------
// Decoder, compact-code version: 16 nodes/block, 16 threads/node.
// ---------------------------------------------------------------------------
__global__ __launch_bounds__(256) void dec_conv(
    const float* __restrict__ x2f, const float* __restrict__ u,
    const float* __restrict__ w1, const float* __restrict__ b1,
    const float* __restrict__ w2, const float* __restrict__ b2,
    float* __restrict__ outp)
{
  __shared__ float xs[16][260];
  __shared__ float ys[16][8][41];
  __shared__ float w1s[256], w2s[224];
  int tid = threadIdx.x;
  int n0 = blockIdx.x * 16;

  w1s[tid] = w1[tid];
  if (tid < 224) w2s[tid] = w2[tid];
  for (int i = tid; i < 16 * 64; i += 256) {
    int r = i >> 6, c = i & 63;
    *(float4*)(&xs[r][c * 4]) = *(const float4*)(x2f + (size_t)(n0 + r) * 256 + c * 4);
  }
  __syncthreads();

  {
    int n = tid >> 4;
    int o = (tid >> 1) & 7;
    int th = tid & 1;              // t in [19*th, 19*th+19)
    float b1v = b1[o];
    float wA[16], wB[16];
    #pragma unroll
    for (int k = 0; k < 16; ++k) { wA[k] = w1s[o * 32 + k]; wB[k] = w1s[o * 32 + 16 + k]; }
    int tEnd = th * 19 + 19;
    for (int t = th * 19; t < tEnd; ++t) {
      float acc = b1v;
      const float* xa = &xs[n][3 * t];
      const float* xb = &xs[n][128 + 3 * t];
      #pragma unroll
      for (int k = 0; k < 16; ++k) acc += xa[k] * wA[k] + xb[k] * wB[k];
      ys[n][o][t] = swishf(acc);
    }
  }
  __syncthreads();

  {
    int n = tid >> 4;
    int c = (tid >> 3) & 1;
    int ts = tid & 7;
    float b2v = b2[c];
    for (int t = ts; t < 25; t += 8) {
      float acc = b2v;
      #pragma unroll
      for (int ic = 0; ic < 8; ++ic) {
        const float* yp = &ys[n][ic][t];
        const float* wp = &w2s[c * 112 + ic * 14];
        #pragma unroll
        for (int k = 0; k < 14; ++k) acc += yp[k] * wp[k];
      }
      int gi = (n0 + n) * 50 + c * 25 + t;
      outp[gi] = u[gi] + (DTC * (t + 1)) * acc;
    }
  }
}

extern "C" void kernel_launch(void* const* d_in, const int* in_sizes, int n_in,
                              void* d_out, int out_size, void* d_ws, size_t ws_size,
                              hipStream_t stream) {
  const float* u     = (const float*)d_in[0];
  const float* pos   = (const float*)d_in[1];
  const int*   eidx  = (const int*)d_in[2];
  const float* embW1 = (const float*)d_in[4];
  const float* embb1 = (const float*)d_in[5];
  const float* embW2 = (const float*)d_in[6];
  const float* embb2 = (const float*)d_in[7];
  const float* m1W   = (const float*)d_in[8];
  const float* m1b   = (const float*)d_in[9];
  const float* m2W   = (const float*)d_in[10];
  const float* m2b   = (const float*)d_in[11];
  const float* u1W   = (const float*)d_in[12];
  const float* u1b   = (const float*)d_in[13];
  const float* u2W   = (const float*)d_in[14];
  const float* u2b   = (const float*)d_in[15];
  const float* dblW  = (const float*)d_in[16];
  const float* dblb  = (const float*)d_in[17];
  const float* c1W   = (const float*)d_in[18];
  const float* c1b   = (const float*)d_in[19];
  const float* c2W   = (const float*)d_in[20];
  const float* c2b   = (const float*)d_in[21];
  float* outp = (float*)d_out;
  const int* srcI = eidx;   // edge_index[0] = src; dst(e) = e>>3 by construction

  char* ws = (char*)d_ws;
  size_t off = 0;
  auto alloc = [&](size_t bytes) -> char* {
    char* p = ws + off; off += (bytes + 255) & ~(size_t)255; return p;
  };
  u16* X0    = (u16*)alloc((size_t)N_NODES * 64 * 2);
  u16* ABbuf = (u16*)alloc((size_t)N_NODES * 256 * 2);
  u16* Agg   = (u16*)alloc((size_t)N_NODES * 128 * 2);
  float* hB  = (float*)alloc((size_t)N_NODES * 128 * 4);
  float* x2f = (float*)alloc((size_t)N_NODES * 256 * 4);
  float* stats = (float*)alloc((size_t)NL * 2 * 1024 * 4);
  u16* WembF1 = (u16*)alloc(64 * 128 * 2);
  u16* WembF2 = (u16*)alloc(128 * 128 * 2);
  u16* WABf   = (u16*)alloc((size_t)6 * 192 * 256 * 2);
  float* bABf = (float*)alloc(6 * 256 * 4);
  u16* Wm2f   = (u16*)alloc((size_t)6 * 128 * 128 * 2);
  u16* Wu1f   = (u16*)alloc((size_t)6 * 320 * 128 * 2);
  u16* Wu2f   = (u16*)alloc((size_t)6 * 128 * 128 * 2);
  u16* Wdblf  = (u16*)alloc((size_t)128 * 256 * 2);

  hipMemsetAsync(stats, 0, (size_t)NL * 2 * 1024 * 4, stream);

  prep_std<<<dim3(32, 1), 256, 0, stream>>>(embW1, WembF1, 52, 64, 128);
  prep_std<<<dim3(64, 1), 256, 0, stream>>>(embW2, WembF2, 128, 128, 128);
  prep_std<<<dim3(64, 6), 256, 0, stream>>>(m2W, Wm2f, 128, 128, 128);
  prep_std<<<dim3(160, 6), 256, 0, stream>>>(u1W, Wu1f, 257, 320, 128);
  prep_std<<<dim3(64, 6), 256, 0, stream>>>(u2W, Wu2f, 128, 128, 128);
  prep_std<<<dim3(128, 1), 256, 0, stream>>>(dblW, Wdblf, 128, 128, 256);
  prep_AB<<<dim3(192, 6), 256, 0, stream>>>(m1W, m1b, WABf, bABf);
  build_static<<<N_NODES * 64 / 256, 256, 0, stream>>>(u, pos, X0);

  enc_fused<<<512, 256, 0, stream>>>(X0, WembF1, embb1, WembF2, embb2, hB);

  for (int l = 0; l < NL; ++l) {
    const float* S1p = l ? stats + (size_t)(l - 1) * 2048 : nullptr;
    const float* S2p = l ? stats + (size_t)(l - 1) * 2048 + 1024 : nullptr;
    float* S1n = stats + (size_t)l * 2048;
    float* S2n = S1n + 1024;
    gemm2<192, 256, 0, 1, 0, 1><<<512, 256, 0, stream>>>(
        nullptr, 0, X0, hB, S1p, S2p, nullptr,
        WABf + (size_t)l * 192 * 256, bABf + l * 256, ABbuf, 256,
        nullptr, nullptr, nullptr);
    msg_kernel<<<N_EDGES / 64, 256, 0, stream>>>(
        ABbuf, srcI, Wm2f + (size_t)l * 128 * 128, m2b + l * 128, Agg);
    upd_fused<<<512, 256, 0, stream>>>(
        Agg, hB, S1p, S2p, pos,
        Wu1f + (size_t)l * 320 * 128, u1b + l * 128,
        Wu2f + (size_t)l * 128 * 128, u2b + l * 128,
        S1n, S2n);
  }

  gemm2<128, 256, 1, 1, 0, 0><<<512, 256, 0, stream>>>(
      nullptr, 0, nullptr, hB, stats + (size_t)5 * 2048, stats + (size_t)5 * 2048 + 1024,
      nullptr, Wdblf, dblb, nullptr, 0, x2f, nullptr, nullptr);
  dec_conv<<<N_NODES / 16, 256, 0, stream>>>(x2f, u, c1W, c1b, c2W, c2b, outp);
}

// Round 10
// 607.530 us; speedup vs baseline: 1.7471x; 1.0117x over previous
//
#include <hip/hip_runtime.h>
#include <hip/hip_bf16.h>

#define N_NODES 32768
#define N_GRAPHS 8
#define NPG 4096
#define DEG 8
#define N_EDGES (N_NODES*DEG)
#define TW 25
#define NL 6
#define L_PDE 16.0f
#define TMAXC 4.0f
#define DTC 0.04f
#define EPSC 1e-5f

typedef __bf16 bf16x8 __attribute__((ext_vector_type(8)));
typedef float f32x4 __attribute__((ext_vector_type(4)));
typedef unsigned short u16;
typedef unsigned int u32;

__device__ __forceinline__ float bf2f(u16 h){
  union { float f; u32 u; } v; v.u = ((u32)h) << 16; return v.f;
}
__device__ __forceinline__ u16 f2bf(float f){
  union { float f; u32 u; } v; v.f = f;
  u32 r = v.u + 0x7FFFu + ((v.u >> 16) & 1u);
  return (u16)(r >> 16);
}
// swish via v_rcp_f32 (~1ulp) instead of IEEE divide (~12 VALU ops -> ~5).
__device__ __forceinline__ float swishf(float x){
  return x * __builtin_amdgcn_rcpf(1.0f + __expf(-x));
}

// ---------------------------------------------------------------------------
// Weight prep: repack W[K][N] (f32, k-major) into frag-major bf16.
// ---------------------------------------------------------------------------
__global__ void prep_std(const float* __restrict__ src, u16* __restrict__ dst,
                         int Ksrc, int KPAD, int NOUT)
{
  int l = blockIdx.y;
  int per = KPAD * NOUT;
  int i = blockIdx.x * 256 + threadIdx.x;
  if (i >= per) return;
  int KSTEPS = KPAD / 32;
  int e = i & 7;
  int lane = (i >> 3) & 63;
  int ks = (i >> 9) % KSTEPS;
  int nf = i / (KSTEPS * 512);
  int c = nf * 16 + (lane & 15);
  int k = ks * 32 + (lane >> 4) * 8 + e;
  float v = (k < Ksrc) ? src[(size_t)l * Ksrc * NOUT + (size_t)k * NOUT + c] : 0.f;
  dst[(size_t)l * per + i] = f2bf(v);
}

// AB factorization weights (see earlier rounds).
__global__ void prep_AB(const float* __restrict__ W, const float* __restrict__ bsrc,
                        u16* __restrict__ dst, float* __restrict__ bdst)
{
  int l = blockIdx.y;
  const int KSTEPS = 6;
  int i = blockIdx.x * 256 + threadIdx.x;       // < 192*256 = 49152
  int e = i & 7, lane = (i >> 3) & 63, ks = (i >> 9) % KSTEPS, nf = i / (KSTEPS * 512);
  int c = nf * 16 + (lane & 15);
  int k = ks * 32 + (lane >> 4) * 8 + e;
  const float* Wl = W + (size_t)l * 308 * 128;
  float v = 0.f;
  if (c < 128) {
    int rowi = -1;
    if (k < 128) rowi = k;
    else if (k < 178) rowi = 256 + (k - 128);
    else if (k == 178) rowi = 306;
    else if (k == 179) rowi = 307;
    if (rowi >= 0) v = Wl[rowi * 128 + c];
  } else {
    int cc = c - 128; float sgn = 1.f; int rowi = -1;
    if (k < 128) rowi = 128 + k;
    else if (k < 178) { rowi = 256 + (k - 128); sgn = -1.f; }
    else if (k == 178) { rowi = 306; sgn = -1.f; }
    if (rowi >= 0) v = sgn * Wl[rowi * 128 + cc];
  }
  dst[(size_t)l * 192 * 256 + i] = f2bf(v);
  if (i < 256) bdst[l * 256 + i] = (i < 128) ? bsrc[l * 128 + i] : 0.f;
}

// Static feature columns: X0[N][64] = [u(50), px, pt, 0..]
__global__ __launch_bounds__(256) void build_static(
    const float* __restrict__ u, const float* __restrict__ pos,
    u16* __restrict__ X0)
{
  int idx = blockIdx.x * 256 + threadIdx.x;   // N*64
  int n = idx >> 6, j = idx & 63;
  float v;
  if (j < 50) v = u[n * 50 + j];
  else if (j == 50) v = pos[n * 2 + 1] * (1.f / L_PDE);
  else if (j == 51) v = pos[n * 2 + 0] * (1.f / TMAXC);
  else v = 0.f;
  X0[n * 64 + j] = f2bf(v);
}

// ---------------------------------------------------------------------------
// Unified MFMA GEMM (used for AB and dbl). Col-split wave layout.
// SMODE: 1 = [norm(hB,statsPrev) (128) | X0 static (KPAD-128)]
// HASOUT: stage + write bf16 `out`. outF: scattered f32 copy of activation.
// ---------------------------------------------------------------------------
template<int KPAD, int NOUT, int ACT, int SMODE, int RESID, int HASOUT>
__global__ __launch_bounds__(256) void gemm2(
    const u16* __restrict__ X, int ldx,
    const u16* __restrict__ Xaux,
    float* hB,
    const float* __restrict__ S1p, const float* __restrict__ S2p,
    const float* __restrict__ pos,
    const u16* __restrict__ Wf, const float* __restrict__ bias,
    u16* __restrict__ out, int ldo,
    float* __restrict__ outF,
    float* __restrict__ S1n, float* __restrict__ S2n)
{
  constexpr int KSTEPS = KPAD / 32;
  constexpr int NF2 = NOUT / 32;
  constexpr int CHUNKS = KPAD / 8;
  constexpr int LDO_S = NOUT + 8;
  constexpr int SMEM_US = 64 * (HASOUT ? (KPAD > LDO_S ? KPAD : LDO_S) : KPAD);
  __shared__ u16 sm[SMEM_US];
  int tid = threadIdx.x, lane = tid & 63, wid = tid >> 6;
  int n0 = blockIdx.x * 64;
  int g = n0 >> 12;

  for (int c = tid; c < 64 * CHUNKS; c += 256) {
    int r = c / CHUNKS, kc = c % CHUNKS;
    int n = n0 + r;
    union { uint4 v; u16 s[8]; } o;
    if (SMODE == 0) {
      o.v = *(const uint4*)(X + (size_t)n * ldx + kc * 8);
    } else {
      if (kc < 16) {
        const float* hp = hB + (size_t)n * 128 + kc * 8;
        float4 a0 = *(const float4*)hp, a1 = *(const float4*)(hp + 4);
        float xv[8] = {a0.x,a0.y,a0.z,a0.w,a1.x,a1.y,a1.z,a1.w};
        if (S1p) {
          #pragma unroll
          for (int j = 0; j < 8; ++j) {
            int cc = kc * 8 + j;
            float m = S1p[g * 128 + cc] * (1.f / NPG);
            float var = S2p[g * 128 + cc] * (1.f / NPG) - m * m;
            xv[j] = (xv[j] - m) * rsqrtf(var + EPSC);
          }
        }
        #pragma unroll
        for (int j = 0; j < 8; ++j) o.s[j] = f2bf(xv[j]);
      } else {
        o.v = *(const uint4*)(Xaux + (size_t)n * 64 + (kc - 16) * 8);
      }
    }
    int byte = r * (KPAD * 2) + kc * 16; byte ^= ((r & 7) << 4);
    *(uint4*)((char*)sm + byte) = o.v;
  }
  __syncthreads();

  int rowHalf = wid & 1, colHalf = wid >> 1;
  f32x4 acc[2][NF2];
  f32x4 zero = {0.f, 0.f, 0.f, 0.f};
  #pragma unroll
  for (int m = 0; m < 2; ++m)
    #pragma unroll
    for (int i = 0; i < NF2; ++i) acc[m][i] = zero;
  int rowA = rowHalf * 32 + (lane & 15);
  int kb = lane >> 4;
  #pragma unroll
  for (int ks = 0; ks < KSTEPS; ++ks) {
    int ab0 = rowA * (KPAD * 2) + ks * 64 + kb * 16; ab0 ^= ((rowA & 7) << 4);
    int rA1 = rowA + 16;
    int ab1 = rA1 * (KPAD * 2) + ks * 64 + kb * 16; ab1 ^= ((rA1 & 7) << 4);
    bf16x8 a0 = *(const bf16x8*)((const char*)sm + ab0);
    bf16x8 a1 = *(const bf16x8*)((const char*)sm + ab1);
    #pragma unroll
    for (int nf2 = 0; nf2 < NF2; ++nf2) {
      bf16x8 b = *(const bf16x8*)(Wf + (((colHalf * NF2 + nf2) * KSTEPS + ks) * 64 + lane) * 8);
      acc[0][nf2] = __builtin_amdgcn_mfma_f32_16x16x32_bf16(a0, b, acc[0][nf2], 0, 0, 0);
      acc[1][nf2] = __builtin_amdgcn_mfma_f32_16x16x32_bf16(a1, b, acc[1][nf2], 0, 0, 0);
    }
  }

  if (HASOUT) __syncthreads();
  #pragma unroll
  for (int nf2 = 0; nf2 < NF2; ++nf2) {
    int col = colHalf * (NOUT / 2) + nf2 * 16 + (lane & 15);
    float bv = bias[col];
    #pragma unroll
    for (int m = 0; m < 2; ++m)
      #pragma unroll
      for (int j = 0; j < 4; ++j) {
        int r = rowHalf * 32 + m * 16 + (lane >> 4) * 4 + j;
        float v = acc[m][nf2][j] + bv;
        if (ACT == 1) v = swishf(v);
        if (HASOUT) sm[r * LDO_S + col] = f2bf(v);
        if (outF) outF[(size_t)(n0 + r) * NOUT + col] = v;
      }
  }
  if (HASOUT) {
    __syncthreads();
    for (int c = tid; c < 64 * NOUT / 8; c += 256) {
      int r = c / (NOUT / 8), kc = c % (NOUT / 8);
      uint4 v = *(const uint4*)(sm + r * LDO_S + kc * 8);
      *(uint4*)(out + (size_t)(n0 + r) * ldo + kc * 8) = v;
    }
  }
}

// ---------------------------------------------------------------------------
// Fused encoder: h = swish(swish(X0@W1+b1)@W2+b2) -> hB (f32).
// ---------------------------------------------------------------------------
__global__ __launch_bounds__(256) void enc_fused(
    const u16* __restrict__ X0,
    const u16* __restrict__ W1f, const float* __restrict__ b1,
    const u16* __restrict__ W2f, const float* __restrict__ b2,
    float* __restrict__ hB)
{
  __shared__ u16 s1[64 * 64];
  __shared__ u16 s2[64 * 128];
  int tid = threadIdx.x, lane = tid & 63, wid = tid >> 6;
  int n0 = blockIdx.x * 64;

  for (int c = tid; c < 64 * 8; c += 256) {
    int r = c >> 3, kc = c & 7;
    uint4 v = *(const uint4*)(X0 + (size_t)(n0 + r) * 64 + kc * 8);
    int byte = r * 128 + kc * 16; byte ^= ((r & 7) << 4);
    *(uint4*)((char*)s1 + byte) = v;
  }
  __syncthreads();

  int rowHalf = wid & 1, colHalf = wid >> 1;
  int rowA = rowHalf * 32 + (lane & 15), kb = lane >> 4;
  f32x4 acc[2][4];
  f32x4 zero = {0.f, 0.f, 0.f, 0.f};
  #pragma unroll
  for (int m = 0; m < 2; ++m)
    #pragma unroll
    for (int i = 0; i < 4; ++i) acc[m][i] = zero;
  #pragma unroll
  for (int ks = 0; ks < 2; ++ks) {
    int ab0 = rowA * 128 + ks * 64 + kb * 16; ab0 ^= ((rowA & 7) << 4);
    int rA1 = rowA + 16;
    int ab1 = rA1 * 128 + ks * 64 + kb * 16; ab1 ^= ((rA1 & 7) << 4);
    bf16x8 a0 = *(const bf16x8*)((const char*)s1 + ab0);
    bf16x8 a1 = *(const bf16x8*)((const char*)s1 + ab1);
    #pragma unroll
    for (int nf2 = 0; nf2 < 4; ++nf2) {
      bf16x8 b = *(const bf16x8*)(W1f + (((colHalf * 4 + nf2) * 2 + ks) * 64 + lane) * 8);
      acc[0][nf2] = __builtin_amdgcn_mfma_f32_16x16x32_bf16(a0, b, acc[0][nf2], 0, 0, 0);
      acc[1][nf2] = __builtin_amdgcn_mfma_f32_16x16x32_bf16(a1, b, acc[1][nf2], 0, 0, 0);
    }
  }
  #pragma unroll
  for (int nf2 = 0; nf2 < 4; ++nf2) {
    int col = colHalf * 64 + nf2 * 16 + (lane & 15);
    float bv = b1[col];
    #pragma unroll
    for (int m = 0; m < 2; ++m)
      #pragma unroll
      for (int j = 0; j < 4; ++j) {
        int r = rowHalf * 32 + m * 16 + (lane >> 4) * 4 + j;
        int byte = r * 256 + col * 2; byte ^= ((r & 7) << 4);
        *(u16*)((char*)s2 + byte) = f2bf(swishf(acc[m][nf2][j] + bv));
      }
  }
  __syncthreads();
  #pragma unroll
  for (int m = 0; m < 2; ++m)
    #pragma unroll
    for (int i = 0; i < 4; ++i) acc[m][i] = zero;
  #pragma unroll
  for (int ks = 0; ks < 4; ++ks) {
    int ab0 = rowA * 256 + ks * 64 + kb * 16; ab0 ^= ((rowA & 7) << 4);
    int rA1 = rowA + 16;
    int ab1 = rA1 * 256 + ks * 64 + kb * 16; ab1 ^= ((rA1 & 7) << 4);
    bf16x8 a0 = *(const bf16x8*)((const char*)s2 + ab0);
    bf16x8 a1 = *(const bf16x8*)((const char*)s2 + ab1);
    #pragma unroll
    for (int nf2 = 0; nf2 < 4; ++nf2) {
      bf16x8 b = *(const bf16x8*)(W2f + (((colHalf * 4 + nf2) * 4 + ks) * 64 + lane) * 8);
      acc[0][nf2] = __builtin_amdgcn_mfma_f32_16x16x32_bf16(a0, b, acc[0][nf2], 0, 0, 0);
      acc[1][nf2] = __builtin_amdgcn_mfma_f32_16x16x32_bf16(a1, b, acc[1][nf2], 0, 0, 0);
    }
  }
  #pragma unroll
  for (int nf2 = 0; nf2 < 4; ++nf2) {
    int col = colHalf * 64 + nf2 * 16 + (lane & 15);
    float bv = b2[col];
    #pragma unroll
    for (int m = 0; m < 2; ++m)
      #pragma unroll
      for (int j = 0; j < 4; ++j) {
        int r = rowHalf * 32 + m * 16 + (lane >> 4) * 4 + j;
        hB[(size_t)(n0 + r) * 128 + col] = swishf(acc[m][nf2][j] + bv);
      }
  }
}

// ---------------------------------------------------------------------------
// Fused update MLP: z = swish([norm(hB)|Agg|pt] @ Wu1 + b1) (z in LDS only),
// up = swish(z @ Wu2 + b2); hn = norm(hB) + up -> hB; moment atomics.
// ---------------------------------------------------------------------------
__global__ __launch_bounds__(256) void upd_fused(
    const u16* __restrict__ Agg,
    float* hB,
    const float* __restrict__ S1p, const float* __restrict__ S2p,
    const float* __restrict__ pos,
    const u16* __restrict__ W1f, const float* __restrict__ b1,
    const u16* __restrict__ W2f, const float* __restrict__ b2,
    float* __restrict__ S1n, float* __restrict__ S2n)
{
  __shared__ u16 s1[64 * 320];
  __shared__ u16 s2[64 * 128];
  int tid = threadIdx.x, lane = tid & 63, wid = tid >> 6;
  int n0 = blockIdx.x * 64;
  int g = n0 >> 12;

  for (int c = tid; c < 64 * 40; c += 256) {
    int r = c / 40, kc = c % 40;
    int n = n0 + r;
    union { uint4 v; u16 s[8]; } o;
    if (kc < 16) {
      const float* hp = hB + (size_t)n * 128 + kc * 8;
      float4 a0 = *(const float4*)hp, a1 = *(const float4*)(hp + 4);
      float xv[8] = {a0.x,a0.y,a0.z,a0.w,a1.x,a1.y,a1.z,a1.w};
      if (S1p) {
        #pragma unroll
        for (int j = 0; j < 8; ++j) {
          int cc = kc * 8 + j;
          float m = S1p[g * 128 + cc] * (1.f / NPG);
          float var = S2p[g * 128 + cc] * (1.f / NPG) - m * m;
          xv[j] = (xv[j] - m) * rsqrtf(var + EPSC);
        }
      }
      #pragma unroll
      for (int j = 0; j < 8; ++j) o.s[j] = f2bf(xv[j]);
    } else if (kc < 32) {
      o.v = *(const uint4*)(Agg + (size_t)n * 128 + (kc - 16) * 8);
    } else {
      #pragma unroll
      for (int j = 0; j < 8; ++j) o.s[j] = 0;
      if (kc == 32) o.s[0] = f2bf(pos[n * 2] * (1.f / TMAXC));
    }
    int byte = r * 640 + kc * 16; byte ^= ((r & 7) << 4);
    *(uint4*)((char*)s1 + byte) = o.v;
  }
  __syncthreads();

  int rowHalf = wid & 1, colHalf = wid >> 1;
  int rowA = rowHalf * 32 + (lane & 15), kb = lane >> 4;
  f32x4 acc[2][4];
  f32x4 zero = {0.f, 0.f, 0.f, 0.f};
  #pragma unroll
  for (int m = 0; m < 2; ++m)
    #pragma unroll
    for (int i = 0; i < 4; ++i) acc[m][i] = zero;
  #pragma unroll
  for (int ks = 0; ks < 10; ++ks) {
    int ab0 = rowA * 640 + ks * 64 + kb * 16; ab0 ^= ((rowA & 7) << 4);
    int rA1 = rowA + 16;
    int ab1 = rA1 * 640 + ks * 64 + kb * 16; ab1 ^= ((rA1 & 7) << 4);
    bf16x8 a0 = *(const bf16x8*)((const char*)s1 + ab0);
    bf16x8 a1 = *(const bf16x8*)((const char*)s1 + ab1);
    #pragma unroll
    for (int nf2 = 0; nf2 < 4; ++nf2) {
      bf16x8 b = *(const bf16x8*)(W1f + (((colHalf * 4 + nf2) * 10 + ks) * 64 + lane) * 8);
      acc[0][nf2] = __builtin_amdgcn_mfma_f32_16x16x32_bf16(a0, b, acc[0][nf2], 0, 0, 0);
      acc[1][nf2] = __builtin_amdgcn_mfma_f32_16x16x32_bf16(a1, b, acc[1][nf2], 0, 0, 0);
    }
  }
  #pragma unroll
  for (int nf2 = 0; nf2 < 4; ++nf2) {
    int col = colHalf * 64 + nf2 * 16 + (lane & 15);
    float bv = b1[col];
    #pragma unroll
    for (int m = 0; m < 2; ++m)
      #pragma unroll
      for (int j = 0; j < 4; ++j) {
        int r = rowHalf * 32 + m * 16 + (lane >> 4) * 4 + j;
        int byte = r * 256 + col * 2; byte ^= ((r & 7) << 4);
        *(u16*)((char*)s2 + byte) = f2bf(swishf(acc[m][nf2][j] + bv));
      }
  }
  __syncthreads();
  #pragma unroll
  for (int m = 0; m < 2; ++m)
    #pragma unroll
    for (int i = 0; i < 4; ++i) acc[m][i] = zero;
  #pragma unroll
  for (int ks = 0; ks < 4; ++ks) {
    int ab0 = rowA * 256 + ks * 64 + kb * 16; ab0 ^= ((rowA & 7) << 4);
    int rA1 = rowA + 16;
    int ab1 = rA1 * 256 + ks * 64 + kb * 16; ab1 ^= ((rA1 & 7) << 4);
    bf16x8 a0 = *(const bf16x8*)((const char*)s2 + ab0);
    bf16x8 a1 = *(const bf16x8*)((const char*)s2 + ab1);
    #pragma unroll
    for (int nf2 = 0; nf2 < 4; ++nf2) {
      bf16x8 b = *(const bf16x8*)(W2f + (((colHalf * 4 + nf2) * 4 + ks) * 64 + lane) * 8);
      acc[0][nf2] = __builtin_amdgcn_mfma_f32_16x16x32_bf16(a0, b, acc[0][nf2], 0, 0, 0);
      acc[1][nf2] = __builtin_amdgcn_mfma_f32_16x16x32_bf16(a1, b, acc[1][nf2], 0, 0, 0);
    }
  }
  float s1l[4], s2l[4];
  #pragma unroll
  for (int i = 0; i < 4; ++i) { s1l[i] = 0.f; s2l[i] = 0.f; }
  #pragma unroll
  for (int nf2 = 0; nf2 < 4; ++nf2) {
    int col = colHalf * 64 + nf2 * 16 + (lane & 15);
    float bv = b2[col];
    float mm = 0.f, rsig = 1.f;
    if (S1p) {
      mm = S1p[g * 128 + col] * (1.f / NPG);
      float var = S2p[g * 128 + col] * (1.f / NPG) - mm * mm;
      rsig = rsqrtf(var + EPSC);
    }
    #pragma unroll
    for (int m = 0; m < 2; ++m)
      #pragma unroll
      for (int j = 0; j < 4; ++j) {
        int r = rowHalf * 32 + m * 16 + (lane >> 4) * 4 + j;
        int n = n0 + r;
        float v = swishf(acc[m][nf2][j] + bv);
        float hc = hB[(size_t)n * 128 + col];
        hc = (hc - mm) * rsig;
        float hn = hc + v;
        hB[(size_t)n * 128 + col] = hn;
        s1l[nf2] += hn; s2l[nf2] += hn * hn;
      }
  }
  #pragma unroll
  for (int nf2 = 0; nf2 < 4; ++nf2) {
    float s1v = s1l[nf2], s2v = s2l[nf2];
    s1v += __shfl_xor(s1v, 16); s1v += __shfl_xor(s1v, 32);
    s2v += __shfl_xor(s2v, 16); s2v += __shfl_xor(s2v, 32);
    if ((lane >> 4) == 0) {
      int col = colHalf * 64 + nf2 * 16 + (lane & 15);
      atomicAdd(&S1n[g * 128 + col], s1v);
      atomicAdd(&S2n[g * 128 + col], s2v);
    }
  }
}

// ---------------------------------------------------------------------------
// Edge message + mean-aggregate -> Agg[n][128] bf16.
// ---------------------------------------------------------------------------
__global__ __launch_bounds__(256) void msg_kernel(
    const u16* __restrict__ AB, const int* __restrict__ srcIdx,
    const u16* __restrict__ Wf, const float* __restrict__ bm2,
    u16* __restrict__ Agg)
{
  __shared__ u16 Ms[64 * 128];
  __shared__ float aggS[8][132];
  int tid = threadIdx.x, lane = tid & 63, wid = tid >> 6;
  int e0 = blockIdx.x * 64;
  for (int c = tid; c < 1024; c += 256) {
    int i = c >> 4, kc = c & 15;
    int e = e0 + i;
    int nd = e >> 3;
    int ns = srcIdx[e];
    union { uint4 v; u16 s[8]; } va, vb, vo;
    va.v = *(const uint4*)(AB + (size_t)nd * 256 + kc * 8);
    vb.v = *(const uint4*)(AB + (size_t)ns * 256 + 128 + kc * 8);
    #pragma unroll
    for (int j = 0; j < 8; ++j) vo.s[j] = f2bf(swishf(bf2f(va.s[j]) + bf2f(vb.s[j])));
    int byte = i * 256 + kc * 16; byte ^= ((i & 7) << 4);
    *(uint4*)((char*)Ms + byte) = vo.v;
  }
  __syncthreads();
  int rowHalf = wid & 1, colHalf = wid >> 1;
  f32x4 acc[2][4];
  f32x4 zero = {0.f, 0.f, 0.f, 0.f};
  #pragma unroll
  for (int m = 0; m < 2; ++m)
    #pragma unroll
    for (int i = 0; i < 4; ++i) acc[m][i] = zero;
  int rowA = rowHalf * 32 + (lane & 15), kb = lane >> 4;
  #pragma unroll
  for (int ks = 0; ks < 4; ++ks) {
    int ab0 = rowA * 256 + ks * 64 + kb * 16; ab0 ^= ((rowA & 7) << 4);
    int rA1 = rowA + 16;
    int ab1 = rA1 * 256 + ks * 64 + kb * 16; ab1 ^= ((rA1 & 7) << 4);
    bf16x8 a0 = *(const bf16x8*)((const char*)Ms + ab0);
    bf16x8 a1 = *(const bf16x8*)((const char*)Ms + ab1);
    #pragma unroll
    for (int nf2 = 0; nf2 < 4; ++nf2) {
      bf16x8 b = *(const bf16x8*)(Wf + (((colHalf * 4 + nf2) * 4 + ks) * 64 + lane) * 8);
      acc[0][nf2] = __builtin_amdgcn_mfma_f32_16x16x32_bf16(a0, b, acc[0][nf2], 0, 0, 0);
      acc[1][nf2] = __builtin_amdgcn_mfma_f32_16x16x32_bf16(a1, b, acc[1][nf2], 0, 0, 0);
    }
  }
  #pragma unroll
  for (int m = 0; m < 2; ++m)
    #pragma unroll
    for (int nf2 = 0; nf2 < 4; ++nf2) {
      int col = colHalf * 64 + nf2 * 16 + (lane & 15);
      float bv = bm2[col];
      float s = 0.f;
      #pragma unroll
      for (int j = 0; j < 4; ++j) s += swishf(acc[m][nf2][j] + bv);
      s += __shfl_xor(s, 16);
      if ((lane & 31) < 16)
        aggS[rowHalf * 4 + m * 2 + (lane >> 5)][col] = s * 0.125f;
    }
  __syncthreads();
  {
    int node = tid >> 5;
    int c0 = (tid & 31) * 4;
    int n = (e0 >> 3) + node;
    ushort4 o;
    o.x = f2bf(aggS[node][c0 + 0]);
    o.y = f2bf(aggS[node][c0 + 1]);
    o.z = f2bf(aggS[node][c0 + 2]);
    o.w = f2bf(aggS[node][c0 + 3]);
    *(ushort4*)(Agg + (size_t)n * 128 + c0) = o;
  }
}

// ---------------------------------------------------------------------------
// Decoder: phase-split x layout (stride-3 conv -> contiguous windows),
// register-resident windows, contiguous t-chunks. 16 nodes/block.
// conv1: thread=(n,o,th): 19 t's, 6 (cc,p)-combos of reg windows.
// conv2: thread=(n,c,ts): 3-4 contiguous t's, per-ic reg windows.
// ---------------------------------------------------------------------------
__global__ __launch_bounds__(256) void dec_conv(
    const float* __restrict__ x2f, const float* __restrict__ u,
    const float* __restrict__ w1, const float* __restrict__ b1,
    const float* __restrict__ w2, const float* __restrict__ b2,
    float* __restrict__ outp)
{
  __shared__ float xs3[2][3][16][44];   // phase-split: x[n][cc*128+3t'+p] -> xs3[cc][p][n][t']
  __shared__ float ys[16][8][41];
  __shared__ float w1s[256], w2s[224];
  int tid = threadIdx.x;
  int n0 = blockIdx.x * 16;

  w1s[tid] = w1[tid];
  if (tid < 224) w2s[tid] = w2[tid];
  for (int i = tid; i < 16 * 64; i += 256) {
    int r = i >> 6, cq = i & 63;
    int cc = cq >> 5;
    int j4 = (cq & 31) * 4;
    float4 v = *(const float4*)(x2f + (size_t)(n0 + r) * 256 + cc * 128 + j4);
    float xe[4] = {v.x, v.y, v.z, v.w};
    #pragma unroll
    for (int e = 0; e < 4; ++e) {
      int j = j4 + e;
      xs3[cc][j % 3][r][j / 3] = xe[e];
    }
  }
  __syncthreads();

  {
    int n = tid >> 4, o = (tid >> 1) & 7, th = tid & 1;
    int t0 = th * 19;
    float y[19];
    float b1v = b1[o];
    #pragma unroll
    for (int t = 0; t < 19; ++t) y[t] = b1v;
    #pragma unroll
    for (int cc = 0; cc < 2; ++cc) {
      #pragma unroll
      for (int p = 0; p < 3; ++p) {
        const int KP = (p == 0) ? 6 : 5;
        float wr[6];
        #pragma unroll
        for (int k = 0; k < KP; ++k) wr[k] = w1s[o * 32 + cc * 16 + 3 * k + p];
        float win[24];
        #pragma unroll
        for (int q = 0; q < 18 + KP; ++q) win[q] = xs3[cc][p][n][t0 + q];
        #pragma unroll
        for (int t = 0; t < 19; ++t)
          #pragma unroll
          for (int k = 0; k < KP; ++k)
            y[t] += win[t + k] * wr[k];
      }
    }
    #pragma unroll
    for (int t = 0; t < 19; ++t) ys[n][o][t0 + t] = swishf(y[t]);
  }
  __syncthreads();

  {
    int n = tid >> 4, c = (tid >> 3) & 1, ts = tid & 7;
    int t0 = (ts == 0) ? 0 : ts * 3 + 1;   // chunks: 4,3,3,3,3,3,3,3 = 25
    int lim = (ts == 0) ? 4 : 3;
    float b2v = b2[c];
    float acc[4] = {b2v, b2v, b2v, b2v};
    #pragma unroll
    for (int ic = 0; ic < 8; ++ic) {
      float wr[14];
      #pragma unroll
      for (int k = 0; k < 14; ++k) wr[k] = w2s[c * 112 + ic * 14 + k];
      float win[17];
      #pragma unroll
      for (int q = 0; q < 17; ++q) win[q] = ys[n][ic][t0 + q];
      #pragma unroll
      for (int t = 0; t < 4; ++t)
        #pragma unroll
        for (int k = 0; k < 14; ++k)
          acc[t] += win[t + k] * wr[k];
    }
    #pragma unroll
    for (int t = 0; t < 4; ++t) {
      if (t < lim) {
        int tt = t0 + t;
        int gi = (n0 + n) * 50 + c * 25 + tt;
        outp[gi] = u[gi] + (DTC * (tt + 1)) * acc[t];
      }
    }
  }
}

extern "C" void kernel_launch(void* const* d_in, const int* in_sizes, int n_in,
                              void* d_out, int out_size, void* d_ws, size_t ws_size,
                              hipStream_t stream) {
  const float* u     = (const float*)d_in[0];
  const float* pos   = (const float*)d_in[1];
  const int*   eidx  = (const int*)d_in[2];
  const float* embW1 = (const float*)d_in[4];
  const float* embb1 = (const float*)d_in[5];
  const float* embW2 = (const float*)d_in[6];
  const float* embb2 = (const float*)d_in[7];
  const float* m1W   = (const float*)d_in[8];
  const float* m1b   = (const float*)d_in[9];
  const float* m2W   = (const float*)d_in[10];
  const float* m2b   = (const float*)d_in[11];
  const float* u1W   = (const float*)d_in[12];
  const float* u1b   = (const float*)d_in[13];
  const float* u2W   = (const float*)d_in[14];
  const float* u2b   = (const float*)d_in[15];
  const float* dblW  = (const float*)d_in[16];
  const float* dblb  = (const float*)d_in[17];
  const float* c1W   = (const float*)d_in[18];
  const float* c1b   = (const float*)d_in[19];
  const float* c2W   = (const float*)d_in[20];
  const float* c2b   = (const float*)d_in[21];
  float* outp = (float*)d_out;
  const int* srcI = eidx;   // edge_index[0] = src; dst(e) = e>>3 by construction

  char* ws = (char*)d_ws;
  size_t off = 0;
  auto alloc = [&](size_t bytes) -> char* {
    char* p = ws + off; off += (bytes + 255) & ~(size_t)255; return p;
  };
  u16* X0    = (u16*)alloc((size_t)N_NODES * 64 * 2);
  u16* ABbuf = (u16*)alloc((size_t)N_NODES * 256 * 2);
  u16* Agg   = (u16*)alloc((size_t)N_NODES * 128 * 2);
  float* hB  = (float*)alloc((size_t)N_NODES * 128 * 4);
  float* x2f = (float*)alloc((size_t)N_NODES * 256 * 4);
  float* stats = (float*)alloc((size_t)NL * 2 * 1024 * 4);
  u16* WembF1 = (u16*)alloc(64 * 128 * 2);
  u16* WembF2 = (u16*)alloc(128 * 128 * 2);
  u16* WABf   = (u16*)alloc((size_t)6 * 192 * 256 * 2);
  float* bABf = (float*)alloc(6 * 256 * 4);
  u16* Wm2f   = (u16*)alloc((size_t)6 * 128 * 128 * 2);
  u16* Wu1f   = (u16*)alloc((size_t)6 * 320 * 128 * 2);
  u16* Wu2f   = (u16*)alloc((size_t)6 * 128 * 128 * 2);
  u16* Wdblf  = (u16*)alloc((size_t)128 * 256 * 2);

  hipMemsetAsync(stats, 0, (size_t)NL * 2 * 1024 * 4, stream);

  prep_std<<<dim3(32, 1), 256, 0, stream>>>(embW1, WembF1, 52, 64, 128);
  prep_std<<<dim3(64, 1), 256, 0, stream>>>(embW2, WembF2, 128, 128, 128);
  prep_std<<<dim3(64, 6), 256, 0, stream>>>(m2W, Wm2f, 128, 128, 128);
  prep_std<<<dim3(160, 6), 256, 0, stream>>>(u1W, Wu1f, 257, 320, 128);
  prep_std<<<dim3(64, 6), 256, 0, stream>>>(u2W, Wu2f, 128, 128, 128);
  prep_std<<<dim3(128, 1), 256, 0, stream>>>(dblW, Wdblf, 128, 128, 256);
  prep_AB<<<dim3(192, 6), 256, 0, stream>>>(m1W, m1b, WABf, bABf);
  build_static<<<N_NODES * 64 / 256, 256, 0, stream>>>(u, pos, X0);

  enc_fused<<<512, 256, 0, stream>>>(X0, WembF1, embb1, WembF2, embb2, hB);

  for (int l = 0; l < NL; ++l) {
    const float* S1p = l ? stats + (size_t)(l - 1) * 2048 : nullptr;
    const float* S2p = l ? stats + (size_t)(l - 1) * 2048 + 1024 : nullptr;
    float* S1n = stats + (size_t)l * 2048;
    float* S2n = S1n + 1024;
    gemm2<192, 256, 0, 1, 0, 1><<<512, 256, 0, stream>>>(
        nullptr, 0, X0, hB, S1p, S2p, nullptr,
        WABf + (size_t)l * 192 * 256, bABf + l * 256, ABbuf, 256,
        nullptr, nullptr, nullptr);
    msg_kernel<<<N_EDGES / 64, 256, 0, stream>>>(
        ABbuf, srcI, Wm2f + (size_t)l * 128 * 128, m2b + l * 128, Agg);
    upd_fused<<<512, 256, 0, stream>>>(
        Agg, hB, S1p, S2p, pos,
        Wu1f + (size_t)l * 320 * 128, u1b + l * 128,
        Wu2f + (size_t)l * 128 * 128, u2b + l * 128,
        S1n, S2n);
  }

  gemm2<128, 256, 1, 1, 0, 0><<<512, 256, 0, stream>>>(
      nullptr, 0, nullptr, hB, stats + (size_t)5 * 2048, stats + (size_t)5 * 2048 + 1024,
      nullptr, Wdblf, dblb, nullptr, 0, x2f, nullptr, nullptr);
  dec_conv<<<N_NODES / 16, 256, 0, stream>>>(x2f, u, c1W, c1b, c2W, c2b, outp);
}